// Round 1
// baseline (6917.229 us; speedup 1.0000x reference)
//
#include <hip/hip_runtime.h>
#include <hip/hip_bf16.h>
#include <math.h>

// Problem constants (fixed by the reference)
#define NB   64     // batch
#define CIN  64     // input channels
#define DIMD 128    // q/k/e channels
#define TT   120    // time
#define VV   25     // joints
#define HH   8      // heads
#define DHD  16     // DIM/H
#define WW   3      // temporal window
#define UU   75     // W*V
#define TC   24     // t-chunk in attention kernel (120 = 5*24)

typedef __hip_bfloat16 bf16;

__device__ __forceinline__ float b2f(bf16 v)  { return __bfloat162float(v); }
__device__ __forceinline__ bf16  f2b(float v) { return __float2bfloat16(v); }

// ---------------------------------------------------------------------------
// Kernel A: y = x + PE(c,v) + sum_u x[c,u] * se_pe[dis[u][v]][c]   (bf16 out)
// grid = N*T blocks, 256 threads
// ---------------------------------------------------------------------------
__global__ __launch_bounds__(256) void k_build_y(
    const float* __restrict__ x, const float* __restrict__ se_pe,
    const int* __restrict__ dis, bf16* __restrict__ y)
{
  const int n = blockIdx.x / TT, t = blockIdx.x % TT;
  __shared__ float xl[CIN][VV];
  __shared__ float sp[5][CIN];
  __shared__ int   dm[VV][VV];
  const int tid = threadIdx.x;
  for (int i = tid; i < CIN * VV; i += 256)
    xl[i / VV][i % VV] = x[((size_t)(n * CIN + i / VV) * TT + t) * VV + i % VV];
  for (int i = tid; i < 5 * CIN; i += 256) sp[i / CIN][i % CIN] = se_pe[i];
  for (int i = tid; i < VV * VV; i += 256) dm[i / VV][i % VV] = dis[i];
  __syncthreads();
  for (int i = tid; i < CIN * VV; i += 256) {
    const int c = i / VV, v = i % VV;
    // div = exp(-(c&~1) * ln(10000)/64); even c -> sin(v*div), odd -> cos(v*div)
    const float dv = expf(-(float)(c & ~1) * (logf(10000.0f) / (float)CIN));
    const float pe = (c & 1) ? cosf((float)v * dv) : sinf((float)v * dv);
    float acc = xl[c][v] + pe;
    #pragma unroll
    for (int u = 0; u < VV; ++u) acc += xl[c][u] * sp[dm[u][v]][c];
    y[((size_t)(n * CIN + c) * TT + t) * VV + v] = f2b(acc);
  }
}

// ---------------------------------------------------------------------------
// Kernel B: qy = Wq*y + bq ; kk = (Wk*y + bk) + beta * ((We*y + be) @ G)
// grid = N*T blocks, 256 threads. Thread = (d = tid&127, v-range = 13 cols)
// ---------------------------------------------------------------------------
__global__ __launch_bounds__(256) void k_qke(
    const bf16* __restrict__ y,
    const float* __restrict__ Wq, const float* __restrict__ bq,
    const float* __restrict__ Wk, const float* __restrict__ bk,
    const float* __restrict__ We, const float* __restrict__ be,
    const float* __restrict__ G,  const float* __restrict__ beta,
    bf16* __restrict__ qy, bf16* __restrict__ kkp)
{
  const int n = blockIdx.x / TT, t = blockIdx.x % TT;
  __shared__ float yl[CIN][VV + 1];   // +1 pad: col 25 read (discarded) by v0=1,j=12
  __shared__ float el[DIMD][VV];
  __shared__ float Gl[VV][VV + 1];
  const int tid = threadIdx.x;
  for (int i = tid; i < CIN * VV; i += 256)
    yl[i / VV][i % VV] = b2f(y[((size_t)(n * CIN + i / VV) * TT + t) * VV + i % VV]);
  for (int i = tid; i < VV * VV; i += 256) Gl[i / VV][i % VV] = G[i];
  __syncthreads();
  const int d = tid & 127, v0 = tid >> 7;   // v = v0*13 + j, j<13 (v0=1: 12 valid)
  float qj[13], kj[13], ej[13];
  #pragma unroll
  for (int j = 0; j < 13; ++j) { qj[j] = bq[d]; kj[j] = bk[d]; ej[j] = be[d]; }
  for (int c = 0; c < CIN; ++c) {
    const float wq = Wq[d * CIN + c];
    const float wk = Wk[d * CIN + c];
    const float we = We[d * CIN + c];
    #pragma unroll
    for (int j = 0; j < 13; ++j) {
      const float yv = yl[c][v0 * 13 + j];
      qj[j] = fmaf(wq, yv, qj[j]);
      kj[j] = fmaf(wk, yv, kj[j]);
      ej[j] = fmaf(we, yv, ej[j]);
    }
  }
  #pragma unroll
  for (int j = 0; j < 13; ++j) {
    const int v = v0 * 13 + j;
    if (v < VV) {
      el[d][v] = ej[j];
      qy[((size_t)(n * DIMD + d) * TT + t) * VV + v] = f2b(qj[j]);
    }
  }
  __syncthreads();
  const float bet = beta[0];
  float eg[13];
  #pragma unroll
  for (int j = 0; j < 13; ++j) eg[j] = 0.f;
  for (int u = 0; u < VV; ++u) {
    const float ev = el[d][u];
    #pragma unroll
    for (int j = 0; j < 13; ++j)
      eg[j] = fmaf(ev, Gl[u][v0 * 13 + j], eg[j]);
  }
  #pragma unroll
  for (int j = 0; j < 13; ++j) {
    const int v = v0 * 13 + j;
    if (v < VV)
      kkp[((size_t)(n * DIMD + d) * TT + t) * VV + v] = f2b(kj[j] + bet * eg[j]);
  }
}

// ---------------------------------------------------------------------------
// Kernel C: att[n,h,u,v] = softmax_u( mask ? (sum_{dh,t} q*kk)/1920 : NEG )
//           * alpha + att0[h][u%V][v]
// q[.,t,wV+v'] = qy[.,t+w-1,v'] (bq at t-pad).  grid = N*H, 256 threads.
// Thread = (v = tid%25, g = tid/25); u = g + 10j, j<8.
// ---------------------------------------------------------------------------
__global__ __launch_bounds__(256) void k_att(
    const bf16* __restrict__ qy, const bf16* __restrict__ kkp,
    const float* __restrict__ bq, const float* __restrict__ disg,
    const float* __restrict__ att0, const float* __restrict__ alpha,
    bf16* __restrict__ att)
{
  const int n = blockIdx.x / HH, h = blockIdx.x % HH;
  __shared__ float qs[DHD][TC + 2][VV];   // t-local rows: global tq = t0 + row - 1
  __shared__ float ks[DHD][TC][VV];
  __shared__ float mxv[VV], smv[VV];
  const int tid = threadIdx.x;
  const int v = tid % VV;
  const int g = tid / VV;                 // g==10 -> inactive (6 threads)
  const bool act = (g < 10);
  int u_[8], w_[8], up_[8];
  #pragma unroll
  for (int j = 0; j < 8; ++j) {
    int u = g + 10 * j;
    u_[j] = u;
    if (u >= UU) u = 0;                   // clamp; results discarded
    w_[j] = u / VV; up_[j] = u % VV;
  }
  float acc[8] = {0.f, 0.f, 0.f, 0.f, 0.f, 0.f, 0.f, 0.f};

  for (int t0 = 0; t0 < TT; t0 += TC) {
    __syncthreads();
    for (int i = tid; i < DHD * (TC + 2) * VV; i += 256) {
      const int dh = i / ((TC + 2) * VV);
      const int r  = i % ((TC + 2) * VV);
      const int tt = r / VV, vv = r % VV;
      const int tq = t0 + tt - 1;
      const int dd = h * DHD + dh;
      qs[dh][tt][vv] = (tq >= 0 && tq < TT)
          ? b2f(qy[((size_t)(n * DIMD + dd) * TT + tq) * VV + vv]) : bq[dd];
    }
    for (int i = tid; i < DHD * TC * VV; i += 256) {
      const int dh = i / (TC * VV);
      const int r  = i % (TC * VV);
      const int tt = r / VV, vv = r % VV;
      ks[dh][tt][vv] =
          b2f(kkp[((size_t)(n * DIMD + h * DHD + dh) * TT + t0 + tt) * VV + vv]);
    }
    __syncthreads();
    if (act) {
      for (int dh = 0; dh < DHD; ++dh) {
        #pragma unroll 4
        for (int tt = 0; tt < TC; ++tt) {
          const float kv = ks[dh][tt][v];
          #pragma unroll
          for (int j = 0; j < 8; ++j)
            acc[j] = fmaf(qs[dh][tt + w_[j]][up_[j]], kv, acc[j]);
        }
      }
    }
  }
  __syncthreads();
  float* att_s = &qs[0][0][0];            // reuse qs: 75*25 f32
  const float inv = 1.0f / (float)(DHD * TT);
  if (act) {
    #pragma unroll
    for (int j = 0; j < 8; ++j) {
      if (u_[j] < UU) {
        const bool m = disg[(h * VV + up_[j]) * VV + v] > 0.f;
        att_s[u_[j] * VV + v] = m ? acc[j] * inv : -9e15f;
      }
    }
  }
  __syncthreads();
  if (tid < VV) {                          // column softmax stats over u (75)
    float mx = -INFINITY;
    for (int u = 0; u < UU; ++u) mx = fmaxf(mx, att_s[u * VV + tid]);
    float sm = 0.f;
    for (int u = 0; u < UU; ++u) sm += expf(att_s[u * VV + tid] - mx);
    mxv[tid] = mx; smv[tid] = sm;
  }
  __syncthreads();
  const float al = alpha[0];
  if (act) {
    #pragma unroll
    for (int j = 0; j < 8; ++j) {
      if (u_[j] < UU) {
        const float p = expf(att_s[u_[j] * VV + v] - mxv[v]) / smv[v];
        const float o = p * al + att0[(h * VV + up_[j]) * VV + v];
        att[((size_t)(n * HH + h) * UU + u_[j]) * VV + v] = f2b(o);
      }
    }
  }
}

// ---------------------------------------------------------------------------
// Kernel D: out = leaky( BN_o(Wo @ xs + b_o) + BN_d(Wd @ x + b_d), 0.1 )
//   xs[h*64+c, v] = sum_w sum_u' att[h, w*25+u', v] * x[n, c, t+w-1, u']
// grid = N*T, 256 threads. Never materializes xs globally.
// ---------------------------------------------------------------------------
__global__ __launch_bounds__(256) void k_out(
    const float* __restrict__ x, const bf16* __restrict__ att,
    const float* __restrict__ Wo, const float* __restrict__ b_o,
    const float* __restrict__ g_o, const float* __restrict__ be_o,
    const float* __restrict__ m_o, const float* __restrict__ v_o,
    const float* __restrict__ Wd, const float* __restrict__ b_d,
    const float* __restrict__ g_d, const float* __restrict__ be_d,
    const float* __restrict__ m_d, const float* __restrict__ v_d,
    float* __restrict__ out)
{
  const int n = blockIdx.x / TT, t = blockIdx.x % TT;
  __shared__ bf16  attb[HH][UU][VV];      // 30.0 KB
  __shared__ float x3[CIN][WW][VV];       // 19.2 KB
  __shared__ bf16  wl[CIN][DIMD];         // 16.0 KB  Wo_h transposed
  __shared__ float xsh[CIN][VV];          //  6.4 KB
  const int tid = threadIdx.x;
  bf16* ab = &attb[0][0][0];
  for (int i = tid; i < HH * UU * VV; i += 256)
    ab[i] = att[(size_t)n * (HH * UU * VV) + i];
  for (int i = tid; i < CIN * WW * VV; i += 256) {
    const int c = i / (WW * VV), r = i % (WW * VV);
    const int w = r / VV, vv = r % VV;
    const int ts = t + w - 1;
    x3[c][w][vv] = (ts >= 0 && ts < TT)
        ? x[((size_t)(n * CIN + c) * TT + ts) * VV + vv] : 0.f;
  }
  const int d = tid & 127, v0 = tid >> 7;  // out: v = v0*13 + j
  const int va = tid % VV, cg = tid / VV;  // xs phase: tid<200 active
  float oacc[13];
  #pragma unroll
  for (int j = 0; j < 13; ++j) oacc[j] = 0.f;

  for (int h = 0; h < HH; ++h) {
    __syncthreads();  // h=0: attb/x3 ready; h>0: prev Wo-phase reads done
    for (int i = tid; i < CIN * DIMD; i += 256) {
      const int c = i >> 7, dd = i & 127;
      wl[c][dd] = f2b(Wo[(size_t)dd * (HH * CIN) + h * CIN + c]);
    }
    if (cg < 8) {                           // xs tile: thread = (va, 8 c's)
      float xa[8];
      #pragma unroll
      for (int m = 0; m < 8; ++m) xa[m] = 0.f;
      for (int w = 0; w < WW; ++w)
        for (int up = 0; up < VV; ++up) {
          const float av = b2f(attb[h][w * VV + up][va]);
          #pragma unroll
          for (int m = 0; m < 8; ++m)
            xa[m] = fmaf(av, x3[cg * 8 + m][w][up], xa[m]);
        }
      #pragma unroll
      for (int m = 0; m < 8; ++m) xsh[cg * 8 + m][va] = xa[m];
    }
    __syncthreads();
    for (int c = 0; c < CIN; ++c) {         // out accumulate (broadcast reads)
      const float wv = b2f(wl[c][d]);
      #pragma unroll
      for (int j = 0; j < 13; ++j) {
        const int vv = v0 * 13 + j;
        if (vv < VV) oacc[j] = fmaf(wv, xsh[c][vv], oacc[j]);
      }
    }
  }
  // residual conv + BN + leaky relu
  float racc[13];
  #pragma unroll
  for (int j = 0; j < 13; ++j) racc[j] = 0.f;
  for (int c = 0; c < CIN; ++c) {
    const float wd = Wd[d * CIN + c];
    #pragma unroll
    for (int j = 0; j < 13; ++j) {
      const int vv = v0 * 13 + j;
      if (vv < VV) racc[j] = fmaf(wd, x3[c][1][vv], racc[j]);
    }
  }
  const float so = g_o[d] * rsqrtf(v_o[d] + 1e-5f);
  const float co = b_o[d] * so + be_o[d] - m_o[d] * so;
  const float sd = g_d[d] * rsqrtf(v_d[d] + 1e-5f);
  const float cd = b_d[d] * sd + be_d[d] - m_d[d] * sd;
  #pragma unroll
  for (int j = 0; j < 13; ++j) {
    const int vv = v0 * 13 + j;
    if (vv < VV) {
      const float z = (oacc[j] * so + co) + (racc[j] * sd + cd);
      out[((size_t)(n * DIMD + d) * TT + t) * VV + vv] = (z >= 0.f) ? z : 0.1f * z;
    }
  }
}

// ---------------------------------------------------------------------------
extern "C" void kernel_launch(void* const* d_in, const int* in_sizes, int n_in,
                              void* d_out, int out_size, void* d_ws, size_t ws_size,
                              hipStream_t stream)
{
  (void)in_sizes; (void)n_in; (void)out_size; (void)ws_size;
  const float* x     = (const float*)d_in[0];
  const float* Wq    = (const float*)d_in[1];
  const float* bq    = (const float*)d_in[2];
  const float* Wk    = (const float*)d_in[3];
  const float* bk    = (const float*)d_in[4];
  const float* We    = (const float*)d_in[5];
  const float* be    = (const float*)d_in[6];
  const float* G     = (const float*)d_in[7];
  const float* sepe  = (const float*)d_in[8];
  const float* att0  = (const float*)d_in[9];
  const float* alpha = (const float*)d_in[10];
  const float* beta  = (const float*)d_in[11];
  const float* Wo    = (const float*)d_in[12];
  const float* b_o   = (const float*)d_in[13];
  const float* g_o   = (const float*)d_in[14];
  const float* be_o  = (const float*)d_in[15];
  const float* m_o   = (const float*)d_in[16];
  const float* v_o   = (const float*)d_in[17];
  const float* Wd    = (const float*)d_in[18];
  const float* b_d   = (const float*)d_in[19];
  const float* g_d   = (const float*)d_in[20];
  const float* be_d  = (const float*)d_in[21];
  const float* m_d   = (const float*)d_in[22];
  const float* v_d   = (const float*)d_in[23];
  const int*   dism  = (const int*)d_in[24];
  const float* disg  = (const float*)d_in[25];

  // Workspace layout (bf16 intermediates), total 124,800,000 B:
  //   y   : 12,288,000 elems @ 0
  //   qy  : 24,576,000 elems @ 24,576,000
  //   kk  : 24,576,000 elems @ 73,728,000
  //   att :    960,000 elems @ 122,880,000
  char* ws = (char*)d_ws;
  bf16* y   = (bf16*)(ws);
  bf16* qy  = (bf16*)(ws + 24576000);
  bf16* kkp = (bf16*)(ws + 73728000);
  bf16* att = (bf16*)(ws + 122880000);

  k_build_y<<<NB * TT, 256, 0, stream>>>(x, sepe, dism, y);
  k_qke<<<NB * TT, 256, 0, stream>>>(y, Wq, bq, Wk, bk, We, be, G, beta, qy, kkp);
  k_att<<<NB * HH, 256, 0, stream>>>(qy, kkp, bq, disg, att0, alpha, att);
  k_out<<<NB * TT, 256, 0, stream>>>(x, att, Wo, b_o, g_o, be_o, m_o, v_o,
                                     Wd, b_d, g_d, be_d, m_d, v_d, (float*)d_out);
}

// Round 2
// 1532.337 us; speedup vs baseline: 4.5142x; 4.5142x over previous
//
#include <hip/hip_runtime.h>
#include <hip/hip_bf16.h>
#include <math.h>

// Problem constants (fixed by the reference)
#define NB   64     // batch
#define CIN  64     // input channels
#define DIMD 128    // q/k/e channels
#define TT   120    // time
#define VV   25     // joints
#define HH   8      // heads
#define DHD  16     // DIM/H
#define WW   3      // temporal window
#define UU   75     // W*V
#define TC   24     // t-chunk in attention kernel (120 = 5*24)
#define TCO  4      // t-chunk in output kernel (120 = 4*30)

typedef __hip_bfloat16 bf16;
typedef float        f32x4 __attribute__((ext_vector_type(4)));
typedef unsigned int u32x4 __attribute__((ext_vector_type(4)));
typedef unsigned int u32x2 __attribute__((ext_vector_type(2)));

__device__ __forceinline__ float b2f(bf16 v)  { return __bfloat162float(v); }
__device__ __forceinline__ bf16  f2b(float v) { return __float2bfloat16(v); }

__device__ __forceinline__ unsigned short f2bu(float f) {
  unsigned u = __builtin_bit_cast(unsigned, f);
  return (unsigned short)((u + 0x7fffu + ((u >> 16) & 1u)) >> 16);  // RNE
}
__device__ __forceinline__ unsigned pack2(float a, float b) {
  return ((unsigned)f2bu(b) << 16) | (unsigned)f2bu(a);
}

// D = A(16x32) * B(32x16) + D, bf16 inputs, f32 acc. A,B as 4-VGPR tuples.
__device__ __forceinline__ f32x4 mfma_bf16(u32x4 a, u32x4 b, f32x4 d) {
  asm("v_mfma_f32_16x16x32_bf16 %0, %1, %2, %0" : "+v"(d) : "v"(a), "v"(b));
  return d;
}

// ---------------------------------------------------------------------------
// Kernel A: y = x + PE(c,v) + sum_u x[c,u] * se_pe[dis[u][v]][c]   (bf16 out)
// ---------------------------------------------------------------------------
__global__ __launch_bounds__(256) void k_build_y(
    const float* __restrict__ x, const float* __restrict__ se_pe,
    const int* __restrict__ dis, bf16* __restrict__ y)
{
  const int n = blockIdx.x / TT, t = blockIdx.x % TT;
  __shared__ float xl[CIN][VV];
  __shared__ float sp[5][CIN];
  __shared__ int   dm[VV][VV];
  const int tid = threadIdx.x;
  for (int i = tid; i < CIN * VV; i += 256)
    xl[i / VV][i % VV] = x[((size_t)(n * CIN + i / VV) * TT + t) * VV + i % VV];
  for (int i = tid; i < 5 * CIN; i += 256) sp[i / CIN][i % CIN] = se_pe[i];
  for (int i = tid; i < VV * VV; i += 256) dm[i / VV][i % VV] = dis[i];
  __syncthreads();
  for (int i = tid; i < CIN * VV; i += 256) {
    const int c = i / VV, v = i % VV;
    const float dv = expf(-(float)(c & ~1) * (logf(10000.0f) / (float)CIN));
    const float pe = (c & 1) ? cosf((float)v * dv) : sinf((float)v * dv);
    float acc = xl[c][v] + pe;
    #pragma unroll
    for (int u = 0; u < VV; ++u) acc += xl[c][u] * sp[dm[u][v]][c];
    y[((size_t)(n * CIN + c) * TT + t) * VV + v] = f2b(acc);
  }
}

// ---------------------------------------------------------------------------
// Kernel B: qy = Wq*y + bq ; kk = (Wk*y + bk) + beta * ((We*y + be) @ G)
// ---------------------------------------------------------------------------
__global__ __launch_bounds__(256) void k_qke(
    const bf16* __restrict__ y,
    const float* __restrict__ Wq, const float* __restrict__ bq,
    const float* __restrict__ Wk, const float* __restrict__ bk,
    const float* __restrict__ We, const float* __restrict__ be,
    const float* __restrict__ G,  const float* __restrict__ beta,
    bf16* __restrict__ qy, bf16* __restrict__ kkp)
{
  const int n = blockIdx.x / TT, t = blockIdx.x % TT;
  __shared__ float yl[CIN][VV + 1];
  __shared__ float el[DIMD][VV];
  __shared__ float Gl[VV][VV + 1];
  const int tid = threadIdx.x;
  for (int i = tid; i < CIN * VV; i += 256)
    yl[i / VV][i % VV] = b2f(y[((size_t)(n * CIN + i / VV) * TT + t) * VV + i % VV]);
  for (int i = tid; i < VV * VV; i += 256) Gl[i / VV][i % VV] = G[i];
  __syncthreads();
  const int d = tid & 127, v0 = tid >> 7;
  float qj[13], kj[13], ej[13];
  #pragma unroll
  for (int j = 0; j < 13; ++j) { qj[j] = bq[d]; kj[j] = bk[d]; ej[j] = be[d]; }
  for (int c = 0; c < CIN; ++c) {
    const float wq = Wq[d * CIN + c];
    const float wk = Wk[d * CIN + c];
    const float we = We[d * CIN + c];
    #pragma unroll
    for (int j = 0; j < 13; ++j) {
      const float yv = yl[c][v0 * 13 + j];
      qj[j] = fmaf(wq, yv, qj[j]);
      kj[j] = fmaf(wk, yv, kj[j]);
      ej[j] = fmaf(we, yv, ej[j]);
    }
  }
  #pragma unroll
  for (int j = 0; j < 13; ++j) {
    const int v = v0 * 13 + j;
    if (v < VV) {
      el[d][v] = ej[j];
      qy[((size_t)(n * DIMD + d) * TT + t) * VV + v] = f2b(qj[j]);
    }
  }
  __syncthreads();
  const float bet = beta[0];
  float eg[13];
  #pragma unroll
  for (int j = 0; j < 13; ++j) eg[j] = 0.f;
  for (int u = 0; u < VV; ++u) {
    const float ev = el[d][u];
    #pragma unroll
    for (int j = 0; j < 13; ++j)
      eg[j] = fmaf(ev, Gl[u][v0 * 13 + j], eg[j]);
  }
  #pragma unroll
  for (int j = 0; j < 13; ++j) {
    const int v = v0 * 13 + j;
    if (v < VV)
      kkp[((size_t)(n * DIMD + d) * TT + t) * VV + v] = f2b(kj[j] + bet * eg[j]);
  }
}

// ---------------------------------------------------------------------------
// Kernel C: attT[n,h,v,u] = alpha*softmax_u(mask? qk/1920 : NEG) + att0
// (stores TRANSPOSED [v][u] so k_out can stage B-frags with coalesced-u reads)
// ---------------------------------------------------------------------------
__global__ __launch_bounds__(256) void k_att(
    const bf16* __restrict__ qy, const bf16* __restrict__ kkp,
    const float* __restrict__ bq, const float* __restrict__ disg,
    const float* __restrict__ att0, const float* __restrict__ alpha,
    bf16* __restrict__ attT)
{
  const int n = blockIdx.x / HH, h = blockIdx.x % HH;
  __shared__ float qs[DHD][TC + 2][VV];
  __shared__ float ks[DHD][TC][VV];
  __shared__ float mxv[VV], smv[VV];
  const int tid = threadIdx.x;
  const int v = tid % VV;
  const int g = tid / VV;
  const bool act = (g < 10);
  int u_[8], w_[8], up_[8];
  #pragma unroll
  for (int j = 0; j < 8; ++j) {
    int u = g + 10 * j;
    u_[j] = u;
    if (u >= UU) u = 0;
    w_[j] = u / VV; up_[j] = u % VV;
  }
  float acc[8] = {0.f, 0.f, 0.f, 0.f, 0.f, 0.f, 0.f, 0.f};

  for (int t0 = 0; t0 < TT; t0 += TC) {
    __syncthreads();
    for (int i = tid; i < DHD * (TC + 2) * VV; i += 256) {
      const int dh = i / ((TC + 2) * VV);
      const int r  = i % ((TC + 2) * VV);
      const int tt = r / VV, vv = r % VV;
      const int tq = t0 + tt - 1;
      const int dd = h * DHD + dh;
      qs[dh][tt][vv] = (tq >= 0 && tq < TT)
          ? b2f(qy[((size_t)(n * DIMD + dd) * TT + tq) * VV + vv]) : bq[dd];
    }
    for (int i = tid; i < DHD * TC * VV; i += 256) {
      const int dh = i / (TC * VV);
      const int r  = i % (TC * VV);
      const int tt = r / VV, vv = r % VV;
      ks[dh][tt][vv] =
          b2f(kkp[((size_t)(n * DIMD + h * DHD + dh) * TT + t0 + tt) * VV + vv]);
    }
    __syncthreads();
    if (act) {
      for (int dh = 0; dh < DHD; ++dh) {
        #pragma unroll 4
        for (int tt = 0; tt < TC; ++tt) {
          const float kv = ks[dh][tt][v];
          #pragma unroll
          for (int j = 0; j < 8; ++j)
            acc[j] = fmaf(qs[dh][tt + w_[j]][up_[j]], kv, acc[j]);
        }
      }
    }
  }
  __syncthreads();
  float* att_s = &qs[0][0][0];
  const float inv = 1.0f / (float)(DHD * TT);
  if (act) {
    #pragma unroll
    for (int j = 0; j < 8; ++j) {
      if (u_[j] < UU) {
        const bool m = disg[(h * VV + up_[j]) * VV + v] > 0.f;
        att_s[u_[j] * VV + v] = m ? acc[j] * inv : -9e15f;
      }
    }
  }
  __syncthreads();
  if (tid < VV) {
    float mx = -INFINITY;
    for (int u = 0; u < UU; ++u) mx = fmaxf(mx, att_s[u * VV + tid]);
    float sm = 0.f;
    for (int u = 0; u < UU; ++u) sm += expf(att_s[u * VV + tid] - mx);
    mxv[tid] = mx; smv[tid] = sm;
  }
  __syncthreads();
  const float al = alpha[0];
  for (int i = tid; i < UU * VV; i += 256) {
    const int u = i % UU, vc = i / UU;
    const float p = expf(att_s[u * VV + vc] - mxv[vc]) / smv[vc];
    const float o = p * al + att0[(h * VV + u % VV) * VV + vc];
    attT[((size_t)(n * HH + h) * VV + vc) * UU + u] = f2b(o);
  }
}

// ---------------------------------------------------------------------------
// Kernel D (MFMA): out = leaky( so*(Wo@xs) + co + sd*(Wd@x) + cd, 0.1 )
// block = (n, 4 t's); 4 waves. Per h: stage1 xs_h via mfma (per-wave one t),
// stage2 acc += Wo_h' @ xs_h. Residual = extra iteration h==8 (A=Wd', B=x^T).
// ---------------------------------------------------------------------------
__global__ __launch_bounds__(256) void k_out_mfma(
    const float* __restrict__ x, const bf16* __restrict__ attT,
    const float* __restrict__ Wo, const float* __restrict__ b_o,
    const float* __restrict__ g_o, const float* __restrict__ be_o,
    const float* __restrict__ m_o, const float* __restrict__ v_o,
    const float* __restrict__ Wd, const float* __restrict__ b_d,
    const float* __restrict__ g_d, const float* __restrict__ be_d,
    const float* __restrict__ m_d, const float* __restrict__ v_d,
    float* __restrict__ out)
{
  const int n = blockIdx.x / 30, t0 = (blockIdx.x % 30) * TCO;
  __shared__ alignas(16) unsigned short xu[TCO][64][96];   // 49152 B, u-pad 75..95 = 0
  __shared__ alignas(16) unsigned short attl[HH][32][96];  // 49152 B, v/u padded 0
  __shared__ alignas(16) unsigned short xsl[112][64];      // 14336 B, [tv][c], swz
  __shared__ alignas(16) unsigned short wol[128][64];      // 16384 B, [d][c], swz
  const int tid = threadIdx.x;

  // ---- build xu (bf16, zero-padded) ----
  for (int i = tid; i < TCO * 64 * 48; i += 256) {
    const int u0 = (i % 48) * 2, c = (i / 48) & 63, tr = i / (48 * 64);
    float f0 = 0.f, f1 = 0.f;
    if (u0 < UU) {
      const int w = u0 / VV, up = u0 % VV, ts = t0 + tr + w - 1;
      if (ts >= 0 && ts < TT) f0 = x[((n * 64 + c) * TT + ts) * VV + up];
    }
    if (u0 + 1 < UU) {
      const int u = u0 + 1, w = u / VV, up = u % VV, ts = t0 + tr + w - 1;
      if (ts >= 0 && ts < TT) f1 = x[((n * 64 + c) * TT + ts) * VV + up];
    }
    *(unsigned*)&xu[tr][c][u0] = pack2(f0, f1);
  }
  // ---- build attl [h][v][u] ----
  for (int i = tid; i < HH * 32 * 48; i += 256) {
    const int u0 = (i % 48) * 2, v = (i / 48) & 31, h = i / (48 * 32);
    float f0 = 0.f, f1 = 0.f;
    if (v < VV) {
      const bf16* src = attT + ((size_t)(n * HH + h) * VV + v) * UU;
      if (u0 < UU) f0 = b2f(src[u0]);
      if (u0 + 1 < UU) f1 = b2f(src[u0 + 1]);
    }
    *(unsigned*)&attl[h][v][u0] = pack2(f0, f1);
  }
  // zero xsl junk rows (tv 100..111) once; never rewritten
  for (int i = tid; i < 12 * 64; i += 256) xsl[100 + (i >> 6)][i & 63] = 0;
  __syncthreads();

  const int lane = tid & 63, wid = tid >> 6;
  const int m16 = lane & 15, kg = lane >> 4;

  // stage1 A-frags (xu for this wave's t), cached across all h
  u32x4 af[4][3];
  #pragma unroll
  for (int mt = 0; mt < 4; ++mt)
    #pragma unroll
    for (int ks = 0; ks < 3; ++ks)
      af[mt][ks] = *(const u32x4*)&xu[wid][mt * 16 + m16][ks * 32 + kg * 8];

  // per-thread Wo-loader coords + folded BN scales
  const int wd_d = tid >> 1, wd_c0 = (tid & 1) * 32;
  const float so_ = g_o[wd_d] * rsqrtf(v_o[wd_d] + 1e-5f);
  const float sd_ = g_d[wd_d] * rsqrtf(v_d[wd_d] + 1e-5f);

  f32x4 acc2[2][7];
  #pragma unroll
  for (int mt = 0; mt < 2; ++mt)
    #pragma unroll
    for (int nt = 0; nt < 7; ++nt) acc2[mt][nt] = (f32x4)0.f;

  for (int h = 0; h <= HH; ++h) {
    // issue weight loads early (latency hides under stage1 MFMAs)
    float4 wb[8];
    {
      const float* wsrc = (h < HH) ? (Wo + wd_d * 512 + h * 64 + wd_c0)
                                   : (Wd + wd_d * 64 + wd_c0);
      #pragma unroll
      for (int q = 0; q < 8; ++q) wb[q] = ((const float4*)wsrc)[q];
    }
    f32x4 a1[4][2];
    if (h < HH) {
      u32x4 bfr[2][3];
      #pragma unroll
      for (int nt = 0; nt < 2; ++nt)
        #pragma unroll
        for (int ks = 0; ks < 3; ++ks)
          bfr[nt][ks] = *(const u32x4*)&attl[h][nt * 16 + m16][ks * 32 + kg * 8];
      #pragma unroll
      for (int mt = 0; mt < 4; ++mt)
        #pragma unroll
        for (int nt = 0; nt < 2; ++nt) {
          a1[mt][nt] = (f32x4)0.f;
          #pragma unroll
          for (int ks = 0; ks < 3; ++ks)
            a1[mt][nt] = mfma_bf16(af[mt][ks], bfr[nt][ks], a1[mt][nt]);
        }
    }
    __syncthreads();  // prev stage2 done reading xsl/wol
    if (h < HH) {
      // write xs tile: D row = c = mt*16+kg*4+i, col v = nt*16+m16
      #pragma unroll
      for (int mt = 0; mt < 4; ++mt)
        #pragma unroll
        for (int nt = 0; nt < 2; ++nt) {
          const int v = nt * 16 + m16;
          if (v < VV) {
            const int tv = wid * VV + v;
            const int c0 = mt * 16 + kg * 4;
            u32x2 pk;
            pk[0] = pack2(a1[mt][nt][0], a1[mt][nt][1]);
            pk[1] = pack2(a1[mt][nt][2], a1[mt][nt][3]);
            char* p = (char*)xsl + tv * 128 + ((c0 * 2) ^ ((tv & 7) << 4));
            *(u32x2*)p = pk;
          }
        }
    } else {
      // residual: xsl <- x^T (bf16), from xu's w=1 slice
      for (int i = tid; i < 100 * 64; i += 256) {
        const int tv = i >> 6, c = i & 63;
        const unsigned short val = xu[tv / VV][c][VV + tv % VV];
        *(unsigned short*)((char*)xsl + tv * 128 + ((c * 2) ^ ((tv & 7) << 4))) = val;
      }
    }
    // write wol (scaled weights, swizzled by d&7)
    {
      const float sc = (h < HH) ? so_ : sd_;
      #pragma unroll
      for (int q = 0; q < 4; ++q) {
        const float4 p0 = wb[q * 2], p1 = wb[q * 2 + 1];
        u32x4 wv;
        wv[0] = pack2(p0.x * sc, p0.y * sc); wv[1] = pack2(p0.z * sc, p0.w * sc);
        wv[2] = pack2(p1.x * sc, p1.y * sc); wv[3] = pack2(p1.z * sc, p1.w * sc);
        char* p = (char*)wol + wd_d * 128 + ((wd_c0 * 2 + q * 16) ^ ((wd_d & 7) << 4));
        *(u32x4*)p = wv;
      }
    }
    __syncthreads();  // xsl/wol ready
    // stage2: acc2 += W' @ xs
    u32x4 a2[2][2];
    #pragma unroll
    for (int mt = 0; mt < 2; ++mt)
      #pragma unroll
      for (int ks = 0; ks < 2; ++ks) {
        const int d = wid * 32 + mt * 16 + m16;
        a2[mt][ks] = *(const u32x4*)((const char*)wol + d * 128 +
                      (((ks * 32 + kg * 8) * 2) ^ ((d & 7) << 4)));
      }
    #pragma unroll
    for (int nt = 0; nt < 7; ++nt) {
      const int tv = nt * 16 + m16;
      const u32x4 b0 = *(const u32x4*)((const char*)xsl + tv * 128 +
                        (((kg * 8) * 2) ^ ((tv & 7) << 4)));
      const u32x4 b1 = *(const u32x4*)((const char*)xsl + tv * 128 +
                        (((32 + kg * 8) * 2) ^ ((tv & 7) << 4)));
      #pragma unroll
      for (int mt = 0; mt < 2; ++mt) {
        acc2[mt][nt] = mfma_bf16(a2[mt][0], b0, acc2[mt][nt]);
        acc2[mt][nt] = mfma_bf16(a2[mt][1], b1, acc2[mt][nt]);
      }
    }
  }

  // epilogue: + (co + cd), leaky relu, store
  #pragma unroll
  for (int mt = 0; mt < 2; ++mt) {
    float cc[4];
    #pragma unroll
    for (int i = 0; i < 4; ++i) {
      const int d = wid * 32 + mt * 16 + kg * 4 + i;
      const float so2 = g_o[d] * rsqrtf(v_o[d] + 1e-5f);
      const float sd2 = g_d[d] * rsqrtf(v_d[d] + 1e-5f);
      cc[i] = b_o[d] * so2 + be_o[d] - m_o[d] * so2
            + b_d[d] * sd2 + be_d[d] - m_d[d] * sd2;
    }
    #pragma unroll
    for (int nt = 0; nt < 7; ++nt) {
      const int tv = nt * 16 + m16;
      if (tv < 100) {
        const int t = t0 + tv / VV, v = tv % VV;
        #pragma unroll
        for (int i = 0; i < 4; ++i) {
          const int d = wid * 32 + mt * 16 + kg * 4 + i;
          const float z = acc2[mt][nt][i] + cc[i];
          out[((n * DIMD + d) * TT + t) * VV + v] = (z >= 0.f) ? z : 0.1f * z;
        }
      }
    }
  }
}

// ---------------------------------------------------------------------------
extern "C" void kernel_launch(void* const* d_in, const int* in_sizes, int n_in,
                              void* d_out, int out_size, void* d_ws, size_t ws_size,
                              hipStream_t stream)
{
  (void)in_sizes; (void)n_in; (void)out_size; (void)ws_size;
  const float* x     = (const float*)d_in[0];
  const float* Wq    = (const float*)d_in[1];
  const float* bq    = (const float*)d_in[2];
  const float* Wk    = (const float*)d_in[3];
  const float* bk    = (const float*)d_in[4];
  const float* We    = (const float*)d_in[5];
  const float* be    = (const float*)d_in[6];
  const float* G     = (const float*)d_in[7];
  const float* sepe  = (const float*)d_in[8];
  const float* att0  = (const float*)d_in[9];
  const float* alpha = (const float*)d_in[10];
  const float* beta  = (const float*)d_in[11];
  const float* Wo    = (const float*)d_in[12];
  const float* b_o   = (const float*)d_in[13];
  const float* g_o   = (const float*)d_in[14];
  const float* be_o  = (const float*)d_in[15];
  const float* m_o   = (const float*)d_in[16];
  const float* v_o   = (const float*)d_in[17];
  const float* Wd    = (const float*)d_in[18];
  const float* b_d   = (const float*)d_in[19];
  const float* g_d   = (const float*)d_in[20];
  const float* be_d  = (const float*)d_in[21];
  const float* m_d   = (const float*)d_in[22];
  const float* v_d   = (const float*)d_in[23];
  const int*   dism  = (const int*)d_in[24];
  const float* disg  = (const float*)d_in[25];

  char* ws = (char*)d_ws;
  bf16* y    = (bf16*)(ws);
  bf16* qy   = (bf16*)(ws + 24576000);
  bf16* kkp  = (bf16*)(ws + 73728000);
  bf16* attT = (bf16*)(ws + 122880000);

  k_build_y<<<NB * TT, 256, 0, stream>>>(x, sepe, dism, y);
  k_qke<<<NB * TT, 256, 0, stream>>>(y, Wq, bq, Wk, bk, We, be, G, beta, qy, kkp);
  k_att<<<NB * HH, 256, 0, stream>>>(qy, kkp, bq, disg, att0, alpha, attT);
  k_out_mfma<<<NB * 30, 256, 0, stream>>>(x, attT, Wo, b_o, g_o, be_o, m_o, v_o,
                                          Wd, b_d, g_d, be_d, m_d, v_d, (float*)d_out);
}

// Round 5
// 1513.174 us; speedup vs baseline: 4.5713x; 1.0127x over previous
//
#include <hip/hip_runtime.h>
#include <hip/hip_bf16.h>
#include <math.h>

// Problem constants (fixed by the reference)
#define NB   64     // batch
#define CIN  64     // input channels
#define DIMD 128    // q/k/e channels
#define TT   120    // time
#define VV   25     // joints
#define HH   8      // heads
#define DHD  16     // DIM/H
#define WW   3      // temporal window
#define UU   75     // W*V
#define TC   24     // t-chunk in attention kernel (120 = 5*24)
#define TCO  4      // t-chunk in output kernel (120 = 4*30)

typedef __hip_bfloat16 bf16;
typedef float        f32x4 __attribute__((ext_vector_type(4)));
typedef unsigned int u32x4 __attribute__((ext_vector_type(4)));
typedef unsigned int u32x2 __attribute__((ext_vector_type(2)));

__device__ __forceinline__ float b2f(bf16 v)  { return __bfloat162float(v); }
__device__ __forceinline__ bf16  f2b(float v) { return __float2bfloat16(v); }

__device__ __forceinline__ unsigned short f2bu(float f) {
  unsigned u = __builtin_bit_cast(unsigned, f);
  return (unsigned short)((u + 0x7fffu + ((u >> 16) & 1u)) >> 16);  // RNE
}
__device__ __forceinline__ float bfu(unsigned short s) {
  unsigned u = ((unsigned)s) << 16;
  return __builtin_bit_cast(float, u);
}
__device__ __forceinline__ unsigned pack2(float a, float b) {
  return ((unsigned)f2bu(b) << 16) | (unsigned)f2bu(a);
}

// D = A(16x32) * B(32x16) + D, bf16 inputs, f32 acc. A,B as 4-VGPR tuples.
__device__ __forceinline__ f32x4 mfma_bf16(u32x4 a, u32x4 b, f32x4 d) {
  asm("v_mfma_f32_16x16x32_bf16 %0, %1, %2, %0" : "+v"(d) : "v"(a), "v"(b));
  return d;
}

// ---------------------------------------------------------------------------
// Fused A+B (bisect v3: round-2 verified SCALAR k_qke transplanted into the
// 4-t fused scaffold; only the scaffold is under test this round):
//   phase 0: stage x (f32), pe, se_pe, dis, G into LDS
//   phase 1 (scalar, round-0 verified): y = x + PE + struct-enc -> yl f32 LDS
//   per t in 0..3 (round-2 verified k_qke body, thread = (d, 13 v's)):
//     q,k,e scalar GEMM from global weights + yl; q->global; e->el LDS;
//     barrier; eg = e@G; kk = k + beta*eg -> global; barrier
// ---------------------------------------------------------------------------
__global__ __launch_bounds__(256) void k_qke_fused3(
    const float* __restrict__ x,
    const float* __restrict__ Wq, const float* __restrict__ bq,
    const float* __restrict__ Wk, const float* __restrict__ bk,
    const float* __restrict__ We, const float* __restrict__ be,
    const float* __restrict__ G,  const float* __restrict__ beta,
    const float* __restrict__ se_pe, const int* __restrict__ dis,
    bf16* __restrict__ qy, bf16* __restrict__ kkp)
{
  const int n = blockIdx.x / 30, t0 = (blockIdx.x % 30) * 4;
  __shared__ float xl[4][64][26];   // x[t][c][v] f32
  __shared__ float yl[4][64][26];   // y[t][c][v] f32 (col 25 = unused pad)
  __shared__ float pe[64][25];
  __shared__ float spl[5][64];
  __shared__ int   dml[25][25];
  __shared__ float Gl[25][26];      // G[u][v], col 25 = unused pad
  __shared__ float el[128][26];     // e[d][v] f32 per t (col 25 = pad)

  const int tid = threadIdx.x;
  // ---- phase 0: stage ----
  {
    const float* xb = x + (size_t)n * 192000 + t0 * 25;  // x[n][c][t0+t][v]
    for (int i = tid; i < 6400; i += 256) {
      const int c = i / 100, j = i % 100, t = j / 25, v = j % 25;
      xl[t][c][v] = xb[c * 3000 + j];
    }
  }
  for (int i = tid; i < 1600; i += 256) {
    const int c = i / 25, v = i % 25;
    const float dv = expf(-(float)(c & ~1) * (logf(10000.0f) / 64.0f));
    pe[c][v] = (c & 1) ? cosf((float)v * dv) : sinf((float)v * dv);
  }
  for (int i = tid; i < 320; i += 256) spl[i / 64][i % 64] = se_pe[i];
  for (int i = tid; i < 625; i += 256) dml[i / 25][i % 25] = dis[i];
  for (int i = tid; i < 625; i += 256) Gl[i / 25][i % 25] = G[i];
  __syncthreads();

  // ---- phase 1 (scalar, verified): yl = x + pe + struct-enc ----
  for (int idx = tid; idx < 6400; idx += 256) {
    const int c = idx & 63, tv = idx >> 6;
    const int t = tv / 25, v = tv % 25;
    float acc = xl[t][c][v] + pe[c][v];
    #pragma unroll
    for (int u = 0; u < 25; ++u)
      acc = fmaf(xl[t][c][u], spl[dml[u][v]][c], acc);
    yl[t][c][v] = acc;
  }
  __syncthreads();

  // ---- per-t round-2 scalar k_qke body ----
  const int d = tid & 127, v0 = tid >> 7;
  const float betav = beta[0];
  const float bqd = bq[d], bkd = bk[d], bed = be[d];
  bf16* qyb = qy  + (size_t)n * 384000 + t0 * 25;
  bf16* kkb = kkp + (size_t)n * 384000 + t0 * 25;

  for (int t = 0; t < 4; ++t) {
    float qj[13], kj[13], ej[13];
    #pragma unroll
    for (int j = 0; j < 13; ++j) { qj[j] = bqd; kj[j] = bkd; ej[j] = bed; }
    for (int c = 0; c < 64; ++c) {
      const float wq = Wq[d * 64 + c];
      const float wk = Wk[d * 64 + c];
      const float we = We[d * 64 + c];
      #pragma unroll
      for (int j = 0; j < 13; ++j) {
        const float yv = yl[t][c][v0 * 13 + j];
        qj[j] = fmaf(wq, yv, qj[j]);
        kj[j] = fmaf(wk, yv, kj[j]);
        ej[j] = fmaf(we, yv, ej[j]);
      }
    }
    #pragma unroll
    for (int j = 0; j < 13; ++j) {
      const int v = v0 * 13 + j;
      if (v < 25) {
        el[d][v] = ej[j];
        qyb[(size_t)d * 3000 + t * 25 + v] = f2b(qj[j]);
      }
    }
    __syncthreads();   // el ready
    float eg[13];
    #pragma unroll
    for (int j = 0; j < 13; ++j) eg[j] = 0.f;
    for (int u = 0; u < 25; ++u) {
      const float ev = el[d][u];
      #pragma unroll
      for (int j = 0; j < 13; ++j)
        eg[j] = fmaf(ev, Gl[u][v0 * 13 + j], eg[j]);
    }
    #pragma unroll
    for (int j = 0; j < 13; ++j) {
      const int v = v0 * 13 + j;
      if (v < 25)
        kkb[(size_t)d * 3000 + t * 25 + v] = f2b(kj[j] + betav * eg[j]);
    }
    __syncthreads();   // el reads done before next t overwrites
  }
}

// ---------------------------------------------------------------------------
// Kernel C: attT[n,h,v,u] = alpha*softmax_u(mask? qk/1920 : NEG) + att0
// (stores TRANSPOSED [v][u] so k_out can stage B-frags with coalesced-u reads)
// ---------------------------------------------------------------------------
__global__ __launch_bounds__(256) void k_att(
    const bf16* __restrict__ qy, const bf16* __restrict__ kkp,
    const float* __restrict__ bq, const float* __restrict__ disg,
    const float* __restrict__ att0, const float* __restrict__ alpha,
    bf16* __restrict__ attT)
{
  const int n = blockIdx.x / HH, h = blockIdx.x % HH;
  __shared__ float qs[DHD][TC + 2][VV];
  __shared__ float ks[DHD][TC][VV];
  __shared__ float mxv[VV], smv[VV];
  const int tid = threadIdx.x;
  const int v = tid % VV;
  const int g = tid / VV;
  const bool act = (g < 10);
  int u_[8], w_[8], up_[8];
  #pragma unroll
  for (int j = 0; j < 8; ++j) {
    int u = g + 10 * j;
    u_[j] = u;
    if (u >= UU) u = 0;
    w_[j] = u / VV; up_[j] = u % VV;
  }
  float acc[8] = {0.f, 0.f, 0.f, 0.f, 0.f, 0.f, 0.f, 0.f};

  for (int t0 = 0; t0 < TT; t0 += TC) {
    __syncthreads();
    for (int i = tid; i < DHD * (TC + 2) * VV; i += 256) {
      const int dh = i / ((TC + 2) * VV);
      const int r  = i % ((TC + 2) * VV);
      const int tt = r / VV, vv = r % VV;
      const int tq = t0 + tt - 1;
      const int dd = h * DHD + dh;
      qs[dh][tt][vv] = (tq >= 0 && tq < TT)
          ? b2f(qy[((size_t)(n * DIMD + dd) * TT + tq) * VV + vv]) : bq[dd];
    }
    for (int i = tid; i < DHD * TC * VV; i += 256) {
      const int dh = i / (TC * VV);
      const int r  = i % (TC * VV);
      const int tt = r / VV, vv = r % VV;
      ks[dh][tt][vv] =
          b2f(kkp[((size_t)(n * DIMD + h * DHD + dh) * TT + t0 + tt) * VV + vv]);
    }
    __syncthreads();
    if (act) {
      for (int dh = 0; dh < DHD; ++dh) {
        #pragma unroll 4
        for (int tt = 0; tt < TC; ++tt) {
          const float kv = ks[dh][tt][v];
          #pragma unroll
          for (int j = 0; j < 8; ++j)
            acc[j] = fmaf(qs[dh][tt + w_[j]][up_[j]], kv, acc[j]);
        }
      }
    }
  }
  __syncthreads();
  float* att_s = &qs[0][0][0];
  const float inv = 1.0f / (float)(DHD * TT);
  if (act) {
    #pragma unroll
    for (int j = 0; j < 8; ++j) {
      if (u_[j] < UU) {
        const bool m = disg[(h * VV + up_[j]) * VV + v] > 0.f;
        att_s[u_[j] * VV + v] = m ? acc[j] * inv : -9e15f;
      }
    }
  }
  __syncthreads();
  if (tid < VV) {
    float mx = -INFINITY;
    for (int u = 0; u < UU; ++u) mx = fmaxf(mx, att_s[u * VV + tid]);
    float sm = 0.f;
    for (int u = 0; u < UU; ++u) sm += expf(att_s[u * VV + tid] - mx);
    mxv[tid] = mx; smv[tid] = sm;
  }
  __syncthreads();
  const float al = alpha[0];
  for (int i = tid; i < UU * VV; i += 256) {
    const int u = i % UU, vc = i / UU;
    const float p = expf(att_s[u * VV + vc] - mxv[vc]) / smv[vc];
    const float o = p * al + att0[(h * VV + u % VV) * VV + vc];
    attT[((size_t)(n * HH + h) * VV + vc) * UU + u] = f2b(o);
  }
}

// ---------------------------------------------------------------------------
// Kernel D (MFMA): out = leaky( so*(Wo@xs) + co + sd*(Wd@x) + cd, 0.1 )
// ---------------------------------------------------------------------------
__global__ __launch_bounds__(256) void k_out_mfma(
    const float* __restrict__ x, const bf16* __restrict__ attT,
    const float* __restrict__ Wo, const float* __restrict__ b_o,
    const float* __restrict__ g_o, const float* __restrict__ be_o,
    const float* __restrict__ m_o, const float* __restrict__ v_o,
    const float* __restrict__ Wd, const float* __restrict__ b_d,
    const float* __restrict__ g_d, const float* __restrict__ be_d,
    const float* __restrict__ m_d, const float* __restrict__ v_d,
    float* __restrict__ out)
{
  const int n = blockIdx.x / 30, t0 = (blockIdx.x % 30) * TCO;
  __shared__ alignas(16) unsigned short xu[TCO][64][96];   // u-pad 75..95 = 0
  __shared__ alignas(16) unsigned short attl[HH][32][96];  // v/u padded 0
  __shared__ alignas(16) unsigned short xsl[112][64];      // [tv][c], swz
  __shared__ alignas(16) unsigned short wol[128][64];      // [d][c], swz
  const int tid = threadIdx.x;

  for (int i = tid; i < TCO * 64 * 48; i += 256) {
    const int u0 = (i % 48) * 2, c = (i / 48) & 63, tr = i / (48 * 64);
    float f0 = 0.f, f1 = 0.f;
    if (u0 < UU) {
      const int w = u0 / VV, up = u0 % VV, ts = t0 + tr + w - 1;
      if (ts >= 0 && ts < TT) f0 = x[((n * 64 + c) * TT + ts) * VV + up];
    }
    if (u0 + 1 < UU) {
      const int u = u0 + 1, w = u / VV, up = u % VV, ts = t0 + tr + w - 1;
      if (ts >= 0 && ts < TT) f1 = x[((n * 64 + c) * TT + ts) * VV + up];
    }
    *(unsigned*)&xu[tr][c][u0] = pack2(f0, f1);
  }
  for (int i = tid; i < HH * 32 * 48; i += 256) {
    const int u0 = (i % 48) * 2, v = (i / 48) & 31, h = i / (48 * 32);
    float f0 = 0.f, f1 = 0.f;
    if (v < VV) {
      const bf16* src = attT + ((size_t)(n * HH + h) * VV + v) * UU;
      if (u0 < UU) f0 = b2f(src[u0]);
      if (u0 + 1 < UU) f1 = b2f(src[u0 + 1]);
    }
    *(unsigned*)&attl[h][v][u0] = pack2(f0, f1);
  }
  for (int i = tid; i < 12 * 64; i += 256) xsl[100 + (i >> 6)][i & 63] = 0;
  __syncthreads();

  const int lane = tid & 63, wid = tid >> 6;
  const int m16 = lane & 15, kg = lane >> 4;

  u32x4 af[4][3];
  #pragma unroll
  for (int mt = 0; mt < 4; ++mt)
    #pragma unroll
    for (int ks = 0; ks < 3; ++ks)
      af[mt][ks] = *(const u32x4*)&xu[wid][mt * 16 + m16][ks * 32 + kg * 8];

  const int wd_d = tid >> 1, wd_c0 = (tid & 1) * 32;
  const float so_ = g_o[wd_d] * rsqrtf(v_o[wd_d] + 1e-5f);
  const float sd_ = g_d[wd_d] * rsqrtf(v_d[wd_d] + 1e-5f);

  f32x4 acc2[2][7];
  #pragma unroll
  for (int mt = 0; mt < 2; ++mt)
    #pragma unroll
    for (int nt = 0; nt < 7; ++nt) acc2[mt][nt] = (f32x4)0.f;

  for (int h = 0; h <= HH; ++h) {
    float4 wb[8];
    {
      const float* wsrc = (h < HH) ? (Wo + wd_d * 512 + h * 64 + wd_c0)
                                   : (Wd + wd_d * 64 + wd_c0);
      #pragma unroll
      for (int q = 0; q < 8; ++q) wb[q] = ((const float4*)wsrc)[q];
    }
    f32x4 a1[4][2];
    if (h < HH) {
      u32x4 bfr[2][3];
      #pragma unroll
      for (int nt = 0; nt < 2; ++nt)
        #pragma unroll
        for (int ks = 0; ks < 3; ++ks)
          bfr[nt][ks] = *(const u32x4*)&attl[h][nt * 16 + m16][ks * 32 + kg * 8];
      #pragma unroll
      for (int mt = 0; mt < 4; ++mt)
        #pragma unroll
        for (int nt = 0; nt < 2; ++nt) {
          a1[mt][nt] = (f32x4)0.f;
          #pragma unroll
          for (int ks = 0; ks < 3; ++ks)
            a1[mt][nt] = mfma_bf16(af[mt][ks], bfr[nt][ks], a1[mt][nt]);
        }
    }
    __syncthreads();
    if (h < HH) {
      #pragma unroll
      for (int mt = 0; mt < 4; ++mt)
        #pragma unroll
        for (int nt = 0; nt < 2; ++nt) {
          const int v = nt * 16 + m16;
          if (v < VV) {
            const int tv = wid * VV + v;
            const int c0 = mt * 16 + kg * 4;
            u32x2 pk;
            pk[0] = pack2(a1[mt][nt][0], a1[mt][nt][1]);
            pk[1] = pack2(a1[mt][nt][2], a1[mt][nt][3]);
            char* p = (char*)xsl + tv * 128 + ((c0 * 2) ^ ((tv & 7) << 4));
            *(u32x2*)p = pk;
          }
        }
    } else {
      for (int i = tid; i < 100 * 64; i += 256) {
        const int tv = i >> 6, c = i & 63;
        const unsigned short val = xu[tv / VV][c][VV + tv % VV];
        *(unsigned short*)((char*)xsl + tv * 128 + ((c * 2) ^ ((tv & 7) << 4))) = val;
      }
    }
    {
      const float sc = (h < HH) ? so_ : sd_;
      #pragma unroll
      for (int q = 0; q < 4; ++q) {
        const float4 p0 = wb[q * 2], p1 = wb[q * 2 + 1];
        u32x4 wv;
        wv[0] = pack2(p0.x * sc, p0.y * sc); wv[1] = pack2(p0.z * sc, p0.w * sc);
        wv[2] = pack2(p1.x * sc, p1.y * sc); wv[3] = pack2(p1.z * sc, p1.w * sc);
        char* p = (char*)wol + wd_d * 128 + ((wd_c0 * 2 + q * 16) ^ ((wd_d & 7) << 4));
        *(u32x4*)p = wv;
      }
    }
    __syncthreads();
    u32x4 a2[2][2];
    #pragma unroll
    for (int mt = 0; mt < 2; ++mt)
      #pragma unroll
      for (int ks = 0; ks < 2; ++ks) {
        const int d = wid * 32 + mt * 16 + m16;
        a2[mt][ks] = *(const u32x4*)((const char*)wol + d * 128 +
                      (((ks * 32 + kg * 8) * 2) ^ ((d & 7) << 4)));
      }
    #pragma unroll
    for (int nt = 0; nt < 7; ++nt) {
      const int tv = nt * 16 + m16;
      const u32x4 b0 = *(const u32x4*)((const char*)xsl + tv * 128 +
                        (((kg * 8) * 2) ^ ((tv & 7) << 4)));
      const u32x4 b1 = *(const u32x4*)((const char*)xsl + tv * 128 +
                        (((32 + kg * 8) * 2) ^ ((tv & 7) << 4)));
      #pragma unroll
      for (int mt = 0; mt < 2; ++mt) {
        acc2[mt][nt] = mfma_bf16(a2[mt][0], b0, acc2[mt][nt]);
        acc2[mt][nt] = mfma_bf16(a2[mt][1], b1, acc2[mt][nt]);
      }
    }
  }

  #pragma unroll
  for (int mt = 0; mt < 2; ++mt) {
    float cc[4];
    #pragma unroll
    for (int i = 0; i < 4; ++i) {
      const int d = wid * 32 + mt * 16 + kg * 4 + i;
      const float so2 = g_o[d] * rsqrtf(v_o[d] + 1e-5f);
      const float sd2 = g_d[d] * rsqrtf(v_d[d] + 1e-5f);
      cc[i] = b_o[d] * so2 + be_o[d] - m_o[d] * so2
            + b_d[d] * sd2 + be_d[d] - m_d[d] * sd2;
    }
    #pragma unroll
    for (int nt = 0; nt < 7; ++nt) {
      const int tv = nt * 16 + m16;
      if (tv < 100) {
        const int t = t0 + tv / VV, v = tv % VV;
        #pragma unroll
        for (int i = 0; i < 4; ++i) {
          const int d = wid * 32 + mt * 16 + kg * 4 + i;
          const float z = acc2[mt][nt][i] + cc[i];
          out[((n * DIMD + d) * TT + t) * VV + v] = (z >= 0.f) ? z : 0.1f * z;
        }
      }
    }
  }
}

// ---------------------------------------------------------------------------
extern "C" void kernel_launch(void* const* d_in, const int* in_sizes, int n_in,
                              void* d_out, int out_size, void* d_ws, size_t ws_size,
                              hipStream_t stream)
{
  (void)in_sizes; (void)n_in; (void)out_size; (void)ws_size;
  const float* x     = (const float*)d_in[0];
  const float* Wq    = (const float*)d_in[1];
  const float* bq    = (const float*)d_in[2];
  const float* Wk    = (const float*)d_in[3];
  const float* bk    = (const float*)d_in[4];
  const float* We    = (const float*)d_in[5];
  const float* be    = (const float*)d_in[6];
  const float* G     = (const float*)d_in[7];
  const float* sepe  = (const float*)d_in[8];
  const float* att0  = (const float*)d_in[9];
  const float* alpha = (const float*)d_in[10];
  const float* beta  = (const float*)d_in[11];
  const float* Wo    = (const float*)d_in[12];
  const float* b_o   = (const float*)d_in[13];
  const float* g_o   = (const float*)d_in[14];
  const float* be_o  = (const float*)d_in[15];
  const float* m_o   = (const float*)d_in[16];
  const float* v_o   = (const float*)d_in[17];
  const float* Wd    = (const float*)d_in[18];
  const float* b_d   = (const float*)d_in[19];
  const float* g_d   = (const float*)d_in[20];
  const float* be_d  = (const float*)d_in[21];
  const float* m_d   = (const float*)d_in[22];
  const float* v_d   = (const float*)d_in[23];
  const int*   dism  = (const int*)d_in[24];
  const float* disg  = (const float*)d_in[25];

  // Workspace (bf16): qy @0, kk @49,152,000, attT @98,304,000
  char* ws = (char*)d_ws;
  bf16* qy   = (bf16*)(ws);
  bf16* kkp  = (bf16*)(ws + 49152000);
  bf16* attT = (bf16*)(ws + 98304000);

  k_qke_fused3<<<NB * 30, 256, 0, stream>>>(x, Wq, bq, Wk, bk, We, be, G, beta,
                                            sepe, dism, qy, kkp);
  k_att<<<NB * HH, 256, 0, stream>>>(qy, kkp, bq, disg, att0, alpha, attT);
  k_out_mfma<<<NB * 30, 256, 0, stream>>>(x, attT, Wo, b_o, g_o, be_o, m_o, v_o,
                                          Wd, b_d, g_d, be_d, m_d, v_d, (float*)d_out);
}

// Round 8
// 1069.307 us; speedup vs baseline: 6.4689x; 1.4151x over previous
//
#include <hip/hip_runtime.h>
#include <hip/hip_bf16.h>
#include <math.h>

// Problem constants (fixed by the reference)
#define NB   64     // batch
#define CIN  64     // input channels
#define DIMD 128    // q/k/e channels
#define TT   120    // time
#define VV   25     // joints
#define HH   8      // heads
#define DHD  16     // DIM/H
#define WW   3      // temporal window
#define UU   75     // W*V
#define TC   24     // t-chunk in attention kernel (120 = 5*24)
#define TCO  4      // t-chunk in output kernel (120 = 4*30)

typedef __hip_bfloat16 bf16;
typedef float        f32x4 __attribute__((ext_vector_type(4)));
typedef unsigned int u32x4 __attribute__((ext_vector_type(4)));
typedef unsigned int u32x2 __attribute__((ext_vector_type(2)));

__device__ __forceinline__ float b2f(bf16 v)  { return __bfloat162float(v); }
__device__ __forceinline__ bf16  f2b(float v) { return __float2bfloat16(v); }

__device__ __forceinline__ unsigned short f2bu(float f) {
  unsigned u = __builtin_bit_cast(unsigned, f);
  return (unsigned short)((u + 0x7fffu + ((u >> 16) & 1u)) >> 16);  // RNE
}
__device__ __forceinline__ float bfu(unsigned short s) {
  unsigned u = ((unsigned)s) << 16;
  return __builtin_bit_cast(float, u);
}
__device__ __forceinline__ unsigned pack2(float a, float b) {
  return ((unsigned)f2bu(b) << 16) | (unsigned)f2bu(a);
}

// D = A(16x32) * B(32x16) + D, bf16 inputs, f32 acc. A,B as 4-VGPR tuples.
__device__ __forceinline__ f32x4 mfma_bf16(u32x4 a, u32x4 b, f32x4 d) {
  asm("v_mfma_f32_16x16x32_bf16 %0, %1, %2, %0" : "+v"(d) : "v"(a), "v"(b));
  return d;
}

// ---------------------------------------------------------------------------
// Fused A+B, MFMA, every line from a verified ancestor:
//   phase0 (R5): stage x f32 + tables
//   phase1 (R5 loop + R0 inline PE): y -> yT (R2 swz-u16 store)
//   GEMMs (R2 machinery, strict barriers): e -> el f32; q -> global;
//   eG (R5 logic, f32, in-place); k + bias + el -> kk global
// ---------------------------------------------------------------------------
__global__ __launch_bounds__(256) void k_qke_mfma3(
    const float* __restrict__ x,
    const float* __restrict__ Wq, const float* __restrict__ bq,
    const float* __restrict__ Wk, const float* __restrict__ bk,
    const float* __restrict__ We, const float* __restrict__ be,
    const float* __restrict__ G,  const float* __restrict__ beta,
    const float* __restrict__ se_pe, const int* __restrict__ dis,
    bf16* __restrict__ qy, bf16* __restrict__ kkp)
{
  const int n = blockIdx.x / 30, t0 = (blockIdx.x % 30) * 4;
  __shared__ alignas(16) float xl[4][64][26];            // 26,624  x f32
  __shared__ alignas(16) float spl[5][64];               //  1,280
  __shared__ alignas(16) int   dml[25][25];              //  2,500
  __shared__ alignas(16) float Gl[25][26];               //  2,600
  __shared__ alignas(16) float biasb[384];               //  1,536  bq|bk|be
  __shared__ alignas(16) unsigned short yT[112][64];     // 14,336  [tv][c] swz
  __shared__ alignas(16) unsigned short wl[128][64];     // 16,384  [d][c]  swz
  __shared__ alignas(16) float el[128][4][27];           // 55,296  e -> beta*(e@G), f32

  const int tid = threadIdx.x;
  // ---- phase 0: stage (R5-verbatim) ----
  {
    const float* xb = x + (size_t)n * 192000 + t0 * 25;  // x[n][c][t0+t][v]
    for (int i = tid; i < 6400; i += 256) {
      const int c = i / 100, j = i % 100, t = j / 25, v = j % 25;
      xl[t][c][v] = xb[c * 3000 + j];
    }
  }
  for (int i = tid; i < 320; i += 256) spl[i / 64][i % 64] = se_pe[i];
  for (int i = tid; i < 625; i += 256) dml[i / 25][i % 25] = dis[i];
  for (int i = tid; i < 625; i += 256) Gl[i / 25][i % 25] = G[i];
  for (int i = tid; i < 384; i += 256)
    biasb[i] = (i < 128) ? bq[i] : (i < 256 ? bk[i - 128] : be[i - 256]);
  for (int i = tid; i < 12 * 64; i += 256)               // yT junk rows -> 0
    yT[100 + (i >> 6)][i & 63] = 0;
  __syncthreads();

  const int lane = tid & 63, wid = tid >> 6;
  const int m16 = lane & 15, kg = lane >> 4;
  const int wd_d = tid >> 1, wd_c0 = (tid & 1) * 32;

  // verbatim round-2 wol staging pattern (W f32 -> wl bf16, d&7 XOR swizzle)
  #define STAGE_W(Wsrc)                                                        \
    {                                                                          \
      const float* wsrc = (Wsrc) + wd_d * 64 + wd_c0;                          \
      _Pragma("unroll")                                                        \
      for (int q2 = 0; q2 < 4; ++q2) {                                         \
        const float4 p0 = *(const float4*)(wsrc + q2 * 8);                     \
        const float4 p1 = *(const float4*)(wsrc + q2 * 8 + 4);                 \
        u32x4 wv;                                                              \
        wv[0] = pack2(p0.x, p0.y); wv[1] = pack2(p0.z, p0.w);                  \
        wv[2] = pack2(p1.x, p1.y); wv[3] = pack2(p1.z, p1.w);                  \
        char* p = (char*)wl + wd_d * 128 +                                     \
                  ((wd_c0 * 2 + q2 * 16) ^ ((wd_d & 7) << 4));                 \
        *(u32x4*)p = wv;                                                       \
      }                                                                        \
    }

  // verbatim round-2 a2 frag read (wl, swizzled)
  #define LOAD_AFRAGS(af)                                                      \
    _Pragma("unroll")                                                          \
    for (int mt = 0; mt < 2; ++mt) {                                           \
      _Pragma("unroll")                                                        \
      for (int ks = 0; ks < 2; ++ks) {                                         \
        const int d_ = wid * 32 + mt * 16 + m16;                               \
        af[mt][ks] = *(const u32x4*)((const char*)wl + d_ * 128 +              \
                      (((ks * 32 + kg * 8) * 2) ^ ((d_ & 7) << 4)));           \
      }                                                                        \
    }

  // ---- phase 1 (R5-verbatim loop, R0 inline PE, R2 swz-u16 store) ----
  for (int idx = tid; idx < 6400; idx += 256) {
    const int c = idx & 63, tv = idx >> 6;
    const int t = tv / 25, v = tv % 25;
    const float dv = expf(-(float)(c & ~1) * (logf(10000.0f) / 64.0f));
    float acc = xl[t][c][v] +
                ((c & 1) ? cosf((float)v * dv) : sinf((float)v * dv));
    #pragma unroll
    for (int u = 0; u < 25; ++u)
      acc = fmaf(xl[t][c][u], spl[dml[u][v]][c], acc);
    *(unsigned short*)((char*)yT + tv * 128 + ((c * 2) ^ ((tv & 7) << 4))) =
        f2bu(acc);
  }
  __syncthreads();   // yT ready

  bf16* qyb = qy  + (size_t)n * 384000 + t0 * 25;
  bf16* kkb = kkp + (size_t)n * 384000 + t0 * 25;

  // ---- stage We -> bar -> e-GEMM: el = We @ y + be (f32 store) ----
  STAGE_W(We);
  __syncthreads();   // wl = We ready
  {
    u32x4 ae[2][2];
    LOAD_AFRAGS(ae);
    for (int nt = 0; nt < 7; ++nt) {
      const int tv = nt * 16 + m16;
      const u32x4 b0 = *(const u32x4*)((const char*)yT + tv * 128 +
                        (((kg * 8) * 2) ^ ((tv & 7) << 4)));
      const u32x4 b1 = *(const u32x4*)((const char*)yT + tv * 128 +
                        (((32 + kg * 8) * 2) ^ ((tv & 7) << 4)));
      #pragma unroll
      for (int mt = 0; mt < 2; ++mt) {
        f32x4 acc = (f32x4)0.f;
        acc = mfma_bf16(ae[mt][0], b0, acc);
        acc = mfma_bf16(ae[mt][1], b1, acc);
        if (tv < 100) {
          const int t = tv / 25, uu = tv % 25;
          const int dr = wid * 32 + mt * 16 + kg * 4;
          #pragma unroll
          for (int i2 = 0; i2 < 4; ++i2)
            el[dr + i2][t][uu] = acc[i2] + biasb[256 + dr + i2];
        }
      }
    }
  }
  __syncthreads();   // el ready; all wl(We) reads drained

  // ---- eG (R5 logic, f32, in-place; thread owns rows (d,t)) ----
  {
    const float betav = beta[0];
    for (int pi = tid; pi < 512; pi += 256) {
      const int d = pi & 127, t = pi >> 7;
      float eg[25];
      #pragma unroll
      for (int v = 0; v < 25; ++v) eg[v] = 0.f;
      for (int u = 0; u < 25; ++u) {
        const float ev = el[d][t][u];
        #pragma unroll
        for (int v = 0; v < 25; ++v)
          eg[v] = fmaf(ev, Gl[u][v], eg[v]);
      }
      #pragma unroll
      for (int v = 0; v < 25; ++v)
        el[d][t][v] = betav * eg[v];   // el <- beta*(e@G), f32
    }
  }
  __syncthreads();   // el transformed

  // ---- stage Wq -> bar -> q-GEMM ----
  STAGE_W(Wq);
  __syncthreads();   // wl = Wq ready
  {
    u32x4 aq[2][2];
    LOAD_AFRAGS(aq);
    for (int nt = 0; nt < 7; ++nt) {
      const int tv = nt * 16 + m16;
      const u32x4 b0 = *(const u32x4*)((const char*)yT + tv * 128 +
                        (((kg * 8) * 2) ^ ((tv & 7) << 4)));
      const u32x4 b1 = *(const u32x4*)((const char*)yT + tv * 128 +
                        (((32 + kg * 8) * 2) ^ ((tv & 7) << 4)));
      #pragma unroll
      for (int mt = 0; mt < 2; ++mt) {
        f32x4 acc = (f32x4)0.f;
        acc = mfma_bf16(aq[mt][0], b0, acc);
        acc = mfma_bf16(aq[mt][1], b1, acc);
        if (tv < 100) {
          const int dr = wid * 32 + mt * 16 + kg * 4;
          #pragma unroll
          for (int i2 = 0; i2 < 4; ++i2)
            qyb[(size_t)(dr + i2) * 3000 + tv] = f2b(acc[i2] + biasb[dr + i2]);
        }
      }
    }
  }
  __syncthreads();   // all wl(Wq) reads drained

  // ---- stage Wk -> bar -> k-GEMM + kk epilogue ----
  STAGE_W(Wk);
  __syncthreads();   // wl = Wk ready
  {
    u32x4 ak[2][2];
    LOAD_AFRAGS(ak);
    for (int nt = 0; nt < 7; ++nt) {
      const int tv = nt * 16 + m16;
      const u32x4 b0 = *(const u32x4*)((const char*)yT + tv * 128 +
                        (((kg * 8) * 2) ^ ((tv & 7) << 4)));
      const u32x4 b1 = *(const u32x4*)((const char*)yT + tv * 128 +
                        (((32 + kg * 8) * 2) ^ ((tv & 7) << 4)));
      #pragma unroll
      for (int mt = 0; mt < 2; ++mt) {
        f32x4 acc = (f32x4)0.f;
        acc = mfma_bf16(ak[mt][0], b0, acc);
        acc = mfma_bf16(ak[mt][1], b1, acc);
        if (tv < 100) {
          const int t = tv / 25, uu = tv % 25;
          const int dr = wid * 32 + mt * 16 + kg * 4;
          #pragma unroll
          for (int i2 = 0; i2 < 4; ++i2)
            kkb[(size_t)(dr + i2) * 3000 + tv] =
                f2b(acc[i2] + biasb[128 + dr + i2] + el[dr + i2][t][uu]);
        }
      }
    }
  }
  #undef STAGE_W
  #undef LOAD_AFRAGS
}

// ---------------------------------------------------------------------------
// Kernel C: attT[n,h,v,u] = alpha*softmax_u(mask? qk/1920 : NEG) + att0
// ---------------------------------------------------------------------------
__global__ __launch_bounds__(256) void k_att(
    const bf16* __restrict__ qy, const bf16* __restrict__ kkp,
    const float* __restrict__ bq, const float* __restrict__ disg,
    const float* __restrict__ att0, const float* __restrict__ alpha,
    bf16* __restrict__ attT)
{
  const int n = blockIdx.x / HH, h = blockIdx.x % HH;
  __shared__ float qs[DHD][TC + 2][VV];
  __shared__ float ks[DHD][TC][VV];
  __shared__ float mxv[VV], smv[VV];
  const int tid = threadIdx.x;
  const int v = tid % VV;
  const int g = tid / VV;
  const bool act = (g < 10);
  int u_[8], w_[8], up_[8];
  #pragma unroll
  for (int j = 0; j < 8; ++j) {
    int u = g + 10 * j;
    u_[j] = u;
    if (u >= UU) u = 0;
    w_[j] = u / VV; up_[j] = u % VV;
  }
  float acc[8] = {0.f, 0.f, 0.f, 0.f, 0.f, 0.f, 0.f, 0.f};

  for (int t0 = 0; t0 < TT; t0 += TC) {
    __syncthreads();
    for (int i = tid; i < DHD * (TC + 2) * VV; i += 256) {
      const int dh = i / ((TC + 2) * VV);
      const int r  = i % ((TC + 2) * VV);
      const int tt = r / VV, vv = r % VV;
      const int tq = t0 + tt - 1;
      const int dd = h * DHD + dh;
      qs[dh][tt][vv] = (tq >= 0 && tq < TT)
          ? b2f(qy[((size_t)(n * DIMD + dd) * TT + tq) * VV + vv]) : bq[dd];
    }
    for (int i = tid; i < DHD * TC * VV; i += 256) {
      const int dh = i / (TC * VV);
      const int r  = i % (TC * VV);
      const int tt = r / VV, vv = r % VV;
      ks[dh][tt][vv] =
          b2f(kkp[((size_t)(n * DIMD + h * DHD + dh) * TT + t0 + tt) * VV + vv]);
    }
    __syncthreads();
    if (act) {
      for (int dh = 0; dh < DHD; ++dh) {
        #pragma unroll 4
        for (int tt = 0; tt < TC; ++tt) {
          const float kv = ks[dh][tt][v];
          #pragma unroll
          for (int j = 0; j < 8; ++j)
            acc[j] = fmaf(qs[dh][tt + w_[j]][up_[j]], kv, acc[j]);
        }
      }
    }
  }
  __syncthreads();
  float* att_s = &qs[0][0][0];
  const float inv = 1.0f / (float)(DHD * TT);
  if (act) {
    #pragma unroll
    for (int j = 0; j < 8; ++j) {
      if (u_[j] < UU) {
        const bool m = disg[(h * VV + up_[j]) * VV + v] > 0.f;
        att_s[u_[j] * VV + v] = m ? acc[j] * inv : -9e15f;
      }
    }
  }
  __syncthreads();
  if (tid < VV) {
    float mx = -INFINITY;
    for (int u = 0; u < UU; ++u) mx = fmaxf(mx, att_s[u * VV + tid]);
    float sm = 0.f;
    for (int u = 0; u < UU; ++u) sm += expf(att_s[u * VV + tid] - mx);
    mxv[tid] = mx; smv[tid] = sm;
  }
  __syncthreads();
  const float al = alpha[0];
  for (int i = tid; i < UU * VV; i += 256) {
    const int u = i % UU, vc = i / UU;
    const float p = expf(att_s[u * VV + vc] - mxv[vc]) / smv[vc];
    const float o = p * al + att0[(h * VV + u % VV) * VV + vc];
    attT[((size_t)(n * HH + h) * VV + vc) * UU + u] = f2b(o);
  }
}

// ---------------------------------------------------------------------------
// Kernel D (MFMA): out = leaky( so*(Wo@xs) + co + sd*(Wd@x) + cd, 0.1 )
// ---------------------------------------------------------------------------
__global__ __launch_bounds__(256) void k_out_mfma(
    const float* __restrict__ x, const bf16* __restrict__ attT,
    const float* __restrict__ Wo, const float* __restrict__ b_o,
    const float* __restrict__ g_o, const float* __restrict__ be_o,
    const float* __restrict__ m_o, const float* __restrict__ v_o,
    const float* __restrict__ Wd, const float* __restrict__ b_d,
    const float* __restrict__ g_d, const float* __restrict__ be_d,
    const float* __restrict__ m_d, const float* __restrict__ v_d,
    float* __restrict__ out)
{
  const int n = blockIdx.x / 30, t0 = (blockIdx.x % 30) * TCO;
  __shared__ alignas(16) unsigned short xu[TCO][64][96];   // u-pad 75..95 = 0
  __shared__ alignas(16) unsigned short attl[HH][32][96];  // v/u padded 0
  __shared__ alignas(16) unsigned short xsl[112][64];      // [tv][c], swz
  __shared__ alignas(16) unsigned short wol[128][64];      // [d][c], swz
  const int tid = threadIdx.x;

  for (int i = tid; i < TCO * 64 * 48; i += 256) {
    const int u0 = (i % 48) * 2, c = (i / 48) & 63, tr = i / (48 * 64);
    float f0 = 0.f, f1 = 0.f;
    if (u0 < UU) {
      const int w = u0 / VV, up = u0 % VV, ts = t0 + tr + w - 1;
      if (ts >= 0 && ts < TT) f0 = x[((n * 64 + c) * TT + ts) * VV + up];
    }
    if (u0 + 1 < UU) {
      const int u = u0 + 1, w = u / VV, up = u % VV, ts = t0 + tr + w - 1;
      if (ts >= 0 && ts < TT) f1 = x[((n * 64 + c) * TT + ts) * VV + up];
    }
    *(unsigned*)&xu[tr][c][u0] = pack2(f0, f1);
  }
  for (int i = tid; i < HH * 32 * 48; i += 256) {
    const int u0 = (i % 48) * 2, v = (i / 48) & 31, h = i / (48 * 32);
    float f0 = 0.f, f1 = 0.f;
    if (v < VV) {
      const bf16* src = attT + ((size_t)(n * HH + h) * VV + v) * UU;
      if (u0 < UU) f0 = b2f(src[u0]);
      if (u0 + 1 < UU) f1 = b2f(src[u0 + 1]);
    }
    *(unsigned*)&attl[h][v][u0] = pack2(f0, f1);
  }
  for (int i = tid; i < 12 * 64; i += 256) xsl[100 + (i >> 6)][i & 63] = 0;
  __syncthreads();

  const int lane = tid & 63, wid = tid >> 6;
  const int m16 = lane & 15, kg = lane >> 4;

  u32x4 af[4][3];
  #pragma unroll
  for (int mt = 0; mt < 4; ++mt)
    #pragma unroll
    for (int ks = 0; ks < 3; ++ks)
      af[mt][ks] = *(const u32x4*)&xu[wid][mt * 16 + m16][ks * 32 + kg * 8];

  const int wd_d = tid >> 1, wd_c0 = (tid & 1) * 32;
  const float so_ = g_o[wd_d] * rsqrtf(v_o[wd_d] + 1e-5f);
  const float sd_ = g_d[wd_d] * rsqrtf(v_d[wd_d] + 1e-5f);

  f32x4 acc2[2][7];
  #pragma unroll
  for (int mt = 0; mt < 2; ++mt)
    #pragma unroll
    for (int nt = 0; nt < 7; ++nt) acc2[mt][nt] = (f32x4)0.f;

  for (int h = 0; h <= HH; ++h) {
    float4 wb[8];
    {
      const float* wsrc = (h < HH) ? (Wo + wd_d * 512 + h * 64 + wd_c0)
                                   : (Wd + wd_d * 64 + wd_c0);
      #pragma unroll
      for (int q = 0; q < 8; ++q) wb[q] = ((const float4*)wsrc)[q];
    }
    f32x4 a1[4][2];
    if (h < HH) {
      u32x4 bfr[2][3];
      #pragma unroll
      for (int nt = 0; nt < 2; ++nt)
        #pragma unroll
        for (int ks = 0; ks < 3; ++ks)
          bfr[nt][ks] = *(const u32x4*)&attl[h][nt * 16 + m16][ks * 32 + kg * 8];
      #pragma unroll
      for (int mt = 0; mt < 4; ++mt)
        #pragma unroll
        for (int nt = 0; nt < 2; ++nt) {
          a1[mt][nt] = (f32x4)0.f;
          #pragma unroll
          for (int ks = 0; ks < 3; ++ks)
            a1[mt][nt] = mfma_bf16(af[mt][ks], bfr[nt][ks], a1[mt][nt]);
        }
    }
    __syncthreads();
    if (h < HH) {
      #pragma unroll
      for (int mt = 0; mt < 4; ++mt)
        #pragma unroll
        for (int nt = 0; nt < 2; ++nt) {
          const int v = nt * 16 + m16;
          if (v < VV) {
            const int tv = wid * VV + v;
            const int c0 = mt * 16 + kg * 4;
            u32x2 pk;
            pk[0] = pack2(a1[mt][nt][0], a1[mt][nt][1]);
            pk[1] = pack2(a1[mt][nt][2], a1[mt][nt][3]);
            char* p = (char*)xsl + tv * 128 + ((c0 * 2) ^ ((tv & 7) << 4));
            *(u32x2*)p = pk;
          }
        }
    } else {
      for (int i = tid; i < 100 * 64; i += 256) {
        const int tv = i >> 6, c = i & 63;
        const unsigned short val = xu[tv / VV][c][VV + tv % VV];
        *(unsigned short*)((char*)xsl + tv * 128 + ((c * 2) ^ ((tv & 7) << 4))) = val;
      }
    }
    {
      const float sc = (h < HH) ? so_ : sd_;
      #pragma unroll
      for (int q = 0; q < 4; ++q) {
        const float4 p0 = wb[q * 2], p1 = wb[q * 2 + 1];
        u32x4 wv;
        wv[0] = pack2(p0.x * sc, p0.y * sc); wv[1] = pack2(p0.z * sc, p0.w * sc);
        wv[2] = pack2(p1.x * sc, p1.y * sc); wv[3] = pack2(p1.z * sc, p1.w * sc);
        char* p = (char*)wol + wd_d * 128 + ((wd_c0 * 2 + q * 16) ^ ((wd_d & 7) << 4));
        *(u32x4*)p = wv;
      }
    }
    __syncthreads();
    u32x4 a2[2][2];
    #pragma unroll
    for (int mt = 0; mt < 2; ++mt)
      #pragma unroll
      for (int ks = 0; ks < 2; ++ks) {
        const int d = wid * 32 + mt * 16 + m16;
        a2[mt][ks] = *(const u32x4*)((const char*)wol + d * 128 +
                      (((ks * 32 + kg * 8) * 2) ^ ((d & 7) << 4)));
      }
    #pragma unroll
    for (int nt = 0; nt < 7; ++nt) {
      const int tv = nt * 16 + m16;
      const u32x4 b0 = *(const u32x4*)((const char*)xsl + tv * 128 +
                        (((kg * 8) * 2) ^ ((tv & 7) << 4)));
      const u32x4 b1 = *(const u32x4*)((const char*)xsl + tv * 128 +
                        (((32 + kg * 8) * 2) ^ ((tv & 7) << 4)));
      #pragma unroll
      for (int mt = 0; mt < 2; ++mt) {
        acc2[mt][nt] = mfma_bf16(a2[mt][0], b0, acc2[mt][nt]);
        acc2[mt][nt] = mfma_bf16(a2[mt][1], b1, acc2[mt][nt]);
      }
    }
  }

  #pragma unroll
  for (int mt = 0; mt < 2; ++mt) {
    float cc[4];
    #pragma unroll
    for (int i = 0; i < 4; ++i) {
      const int d = wid * 32 + mt * 16 + kg * 4 + i;
      const float so2 = g_o[d] * rsqrtf(v_o[d] + 1e-5f);
      const float sd2 = g_d[d] * rsqrtf(v_d[d] + 1e-5f);
      cc[i] = b_o[d] * so2 + be_o[d] - m_o[d] * so2
            + b_d[d] * sd2 + be_d[d] - m_d[d] * sd2;
    }
    #pragma unroll
    for (int nt = 0; nt < 7; ++nt) {
      const int tv = nt * 16 + m16;
      if (tv < 100) {
        const int t = t0 + tv / VV, v = tv % VV;
        #pragma unroll
        for (int i = 0; i < 4; ++i) {
          const int d = wid * 32 + mt * 16 + kg * 4 + i;
          const float z = acc2[mt][nt][i] + cc[i];
          out[((n * DIMD + d) * TT + t) * VV + v] = (z >= 0.f) ? z : 0.1f * z;
        }
      }
    }
  }
}

// ---------------------------------------------------------------------------
extern "C" void kernel_launch(void* const* d_in, const int* in_sizes, int n_in,
                              void* d_out, int out_size, void* d_ws, size_t ws_size,
                              hipStream_t stream)
{
  (void)in_sizes; (void)n_in; (void)out_size; (void)ws_size;
  const float* x     = (const float*)d_in[0];
  const float* Wq    = (const float*)d_in[1];
  const float* bq    = (const float*)d_in[2];
  const float* Wk    = (const float*)d_in[3];
  const float* bk    = (const float*)d_in[4];
  const float* We    = (const float*)d_in[5];
  const float* be    = (const float*)d_in[6];
  const float* G     = (const float*)d_in[7];
  const float* sepe  = (const float*)d_in[8];
  const float* att0  = (const float*)d_in[9];
  const float* alpha = (const float*)d_in[10];
  const float* beta  = (const float*)d_in[11];
  const float* Wo    = (const float*)d_in[12];
  const float* b_o   = (const float*)d_in[13];
  const float* g_o   = (const float*)d_in[14];
  const float* be_o  = (const float*)d_in[15];
  const float* m_o   = (const float*)d_in[16];
  const float* v_o   = (const float*)d_in[17];
  const float* Wd    = (const float*)d_in[18];
  const float* b_d   = (const float*)d_in[19];
  const float* g_d   = (const float*)d_in[20];
  const float* be_d  = (const float*)d_in[21];
  const float* m_d   = (const float*)d_in[22];
  const float* v_d   = (const float*)d_in[23];
  const int*   dism  = (const int*)d_in[24];
  const float* disg  = (const float*)d_in[25];

  // Workspace (bf16): qy @0, kk @49,152,000, attT @98,304,000
  char* ws = (char*)d_ws;
  bf16* qy   = (bf16*)(ws);
  bf16* kkp  = (bf16*)(ws + 49152000);
  bf16* attT = (bf16*)(ws + 98304000);

  k_qke_mfma3<<<NB * 30, 256, 0, stream>>>(x, Wq, bq, Wk, bk, We, be, G, beta,
                                           sepe, dism, qy, kkp);
  k_att<<<NB * HH, 256, 0, stream>>>(qy, kkp, bq, disg, att0, alpha, attT);
  k_out_mfma<<<NB * 30, 256, 0, stream>>>(x, attT, Wo, b_o, g_o, be_o, m_o, v_o,
                                          Wd, b_d, g_d, be_d, m_d, v_d, (float*)d_out);
}

// Round 9
// 895.064 us; speedup vs baseline: 7.7282x; 1.1947x over previous
//
#include <hip/hip_runtime.h>
#include <hip/hip_bf16.h>
#include <math.h>

// Problem constants (fixed by the reference)
#define NB   64     // batch
#define CIN  64     // input channels
#define DIMD 128    // q/k/e channels
#define TT   120    // time
#define VV   25     // joints
#define HH   8      // heads
#define DHD  16     // DIM/H
#define WW   3      // temporal window
#define UU   75     // W*V
#define TC   24     // t-chunk in attention kernel (120 = 5*24)
#define TCO  4      // t-chunk in output kernel (120 = 4*30)

typedef __hip_bfloat16 bf16;
typedef float        f32x4 __attribute__((ext_vector_type(4)));
typedef unsigned int u32x4 __attribute__((ext_vector_type(4)));
typedef unsigned int u32x2 __attribute__((ext_vector_type(2)));

__device__ __forceinline__ float b2f(bf16 v)  { return __bfloat162float(v); }
__device__ __forceinline__ bf16  f2b(float v) { return __float2bfloat16(v); }

__device__ __forceinline__ unsigned short f2bu(float f) {
  unsigned u = __builtin_bit_cast(unsigned, f);
  return (unsigned short)((u + 0x7fffu + ((u >> 16) & 1u)) >> 16);  // RNE
}
__device__ __forceinline__ float bfu(unsigned short s) {
  unsigned u = ((unsigned)s) << 16;
  return __builtin_bit_cast(float, u);
}
__device__ __forceinline__ unsigned pack2(float a, float b) {
  return ((unsigned)f2bu(b) << 16) | (unsigned)f2bu(a);
}

// D = A(16x32) * B(32x16) + D, bf16 inputs, f32 acc. A,B as 4-VGPR tuples.
__device__ __forceinline__ f32x4 mfma_bf16(u32x4 a, u32x4 b, f32x4 d) {
  asm("v_mfma_f32_16x16x32_bf16 %0, %1, %2, %0" : "+v"(d) : "v"(a), "v"(b));
  return d;
}

// ---------------------------------------------------------------------------
// Fused A+B (R8-verbatim, passing): y + PE + struct-enc -> yT; e/q/k MFMA
// GEMMs with strict barriers; eG scalar f32 in-place; q/kk -> global.
// ---------------------------------------------------------------------------
__global__ __launch_bounds__(256) void k_qke_mfma3(
    const float* __restrict__ x,
    const float* __restrict__ Wq, const float* __restrict__ bq,
    const float* __restrict__ Wk, const float* __restrict__ bk,
    const float* __restrict__ We, const float* __restrict__ be,
    const float* __restrict__ G,  const float* __restrict__ beta,
    const float* __restrict__ se_pe, const int* __restrict__ dis,
    bf16* __restrict__ qy, bf16* __restrict__ kkp)
{
  const int n = blockIdx.x / 30, t0 = (blockIdx.x % 30) * 4;
  __shared__ alignas(16) float xl[4][64][26];            // 26,624  x f32
  __shared__ alignas(16) float spl[5][64];               //  1,280
  __shared__ alignas(16) int   dml[25][25];              //  2,500
  __shared__ alignas(16) float Gl[25][26];               //  2,600
  __shared__ alignas(16) float biasb[384];               //  1,536  bq|bk|be
  __shared__ alignas(16) unsigned short yT[112][64];     // 14,336  [tv][c] swz
  __shared__ alignas(16) unsigned short wl[128][64];     // 16,384  [d][c]  swz
  __shared__ alignas(16) float el[128][4][27];           // 55,296  e -> beta*(e@G), f32

  const int tid = threadIdx.x;
  // ---- phase 0: stage ----
  {
    const float* xb = x + (size_t)n * 192000 + t0 * 25;  // x[n][c][t0+t][v]
    for (int i = tid; i < 6400; i += 256) {
      const int c = i / 100, j = i % 100, t = j / 25, v = j % 25;
      xl[t][c][v] = xb[c * 3000 + j];
    }
  }
  for (int i = tid; i < 320; i += 256) spl[i / 64][i % 64] = se_pe[i];
  for (int i = tid; i < 625; i += 256) dml[i / 25][i % 25] = dis[i];
  for (int i = tid; i < 625; i += 256) Gl[i / 25][i % 25] = G[i];
  for (int i = tid; i < 384; i += 256)
    biasb[i] = (i < 128) ? bq[i] : (i < 256 ? bk[i - 128] : be[i - 256]);
  for (int i = tid; i < 12 * 64; i += 256)               // yT junk rows -> 0
    yT[100 + (i >> 6)][i & 63] = 0;
  __syncthreads();

  const int lane = tid & 63, wid = tid >> 6;
  const int m16 = lane & 15, kg = lane >> 4;
  const int wd_d = tid >> 1, wd_c0 = (tid & 1) * 32;

  #define STAGE_W(Wsrc)                                                        \
    {                                                                          \
      const float* wsrc = (Wsrc) + wd_d * 64 + wd_c0;                          \
      _Pragma("unroll")                                                        \
      for (int q2 = 0; q2 < 4; ++q2) {                                         \
        const float4 p0 = *(const float4*)(wsrc + q2 * 8);                     \
        const float4 p1 = *(const float4*)(wsrc + q2 * 8 + 4);                 \
        u32x4 wv;                                                              \
        wv[0] = pack2(p0.x, p0.y); wv[1] = pack2(p0.z, p0.w);                  \
        wv[2] = pack2(p1.x, p1.y); wv[3] = pack2(p1.z, p1.w);                  \
        char* p = (char*)wl + wd_d * 128 +                                     \
                  ((wd_c0 * 2 + q2 * 16) ^ ((wd_d & 7) << 4));                 \
        *(u32x4*)p = wv;                                                       \
      }                                                                        \
    }

  #define LOAD_AFRAGS(af)                                                      \
    _Pragma("unroll")                                                          \
    for (int mt = 0; mt < 2; ++mt) {                                           \
      _Pragma("unroll")                                                        \
      for (int ks = 0; ks < 2; ++ks) {                                         \
        const int d_ = wid * 32 + mt * 16 + m16;                               \
        af[mt][ks] = *(const u32x4*)((const char*)wl + d_ * 128 +              \
                      (((ks * 32 + kg * 8) * 2) ^ ((d_ & 7) << 4)));           \
      }                                                                        \
    }

  // ---- phase 1 ----
  for (int idx = tid; idx < 6400; idx += 256) {
    const int c = idx & 63, tv = idx >> 6;
    const int t = tv / 25, v = tv % 25;
    const float dv = expf(-(float)(c & ~1) * (logf(10000.0f) / 64.0f));
    float acc = xl[t][c][v] +
                ((c & 1) ? cosf((float)v * dv) : sinf((float)v * dv));
    #pragma unroll
    for (int u = 0; u < 25; ++u)
      acc = fmaf(xl[t][c][u], spl[dml[u][v]][c], acc);
    *(unsigned short*)((char*)yT + tv * 128 + ((c * 2) ^ ((tv & 7) << 4))) =
        f2bu(acc);
  }
  __syncthreads();   // yT ready

  bf16* qyb = qy  + (size_t)n * 384000 + t0 * 25;
  bf16* kkb = kkp + (size_t)n * 384000 + t0 * 25;

  // ---- stage We -> bar -> e-GEMM ----
  STAGE_W(We);
  __syncthreads();
  {
    u32x4 ae[2][2];
    LOAD_AFRAGS(ae);
    for (int nt = 0; nt < 7; ++nt) {
      const int tv = nt * 16 + m16;
      const u32x4 b0 = *(const u32x4*)((const char*)yT + tv * 128 +
                        (((kg * 8) * 2) ^ ((tv & 7) << 4)));
      const u32x4 b1 = *(const u32x4*)((const char*)yT + tv * 128 +
                        (((32 + kg * 8) * 2) ^ ((tv & 7) << 4)));
      #pragma unroll
      for (int mt = 0; mt < 2; ++mt) {
        f32x4 acc = (f32x4)0.f;
        acc = mfma_bf16(ae[mt][0], b0, acc);
        acc = mfma_bf16(ae[mt][1], b1, acc);
        if (tv < 100) {
          const int t = tv / 25, uu = tv % 25;
          const int dr = wid * 32 + mt * 16 + kg * 4;
          #pragma unroll
          for (int i2 = 0; i2 < 4; ++i2)
            el[dr + i2][t][uu] = acc[i2] + biasb[256 + dr + i2];
        }
      }
    }
  }
  __syncthreads();

  // ---- eG (f32, in-place) ----
  {
    const float betav = beta[0];
    for (int pi = tid; pi < 512; pi += 256) {
      const int d = pi & 127, t = pi >> 7;
      float eg[25];
      #pragma unroll
      for (int v = 0; v < 25; ++v) eg[v] = 0.f;
      for (int u = 0; u < 25; ++u) {
        const float ev = el[d][t][u];
        #pragma unroll
        for (int v = 0; v < 25; ++v)
          eg[v] = fmaf(ev, Gl[u][v], eg[v]);
      }
      #pragma unroll
      for (int v = 0; v < 25; ++v)
        el[d][t][v] = betav * eg[v];
    }
  }
  __syncthreads();

  // ---- stage Wq -> bar -> q-GEMM ----
  STAGE_W(Wq);
  __syncthreads();
  {
    u32x4 aq[2][2];
    LOAD_AFRAGS(aq);
    for (int nt = 0; nt < 7; ++nt) {
      const int tv = nt * 16 + m16;
      const u32x4 b0 = *(const u32x4*)((const char*)yT + tv * 128 +
                        (((kg * 8) * 2) ^ ((tv & 7) << 4)));
      const u32x4 b1 = *(const u32x4*)((const char*)yT + tv * 128 +
                        (((32 + kg * 8) * 2) ^ ((tv & 7) << 4)));
      #pragma unroll
      for (int mt = 0; mt < 2; ++mt) {
        f32x4 acc = (f32x4)0.f;
        acc = mfma_bf16(aq[mt][0], b0, acc);
        acc = mfma_bf16(aq[mt][1], b1, acc);
        if (tv < 100) {
          const int dr = wid * 32 + mt * 16 + kg * 4;
          #pragma unroll
          for (int i2 = 0; i2 < 4; ++i2)
            qyb[(size_t)(dr + i2) * 3000 + tv] = f2b(acc[i2] + biasb[dr + i2]);
        }
      }
    }
  }
  __syncthreads();

  // ---- stage Wk -> bar -> k-GEMM + kk epilogue ----
  STAGE_W(Wk);
  __syncthreads();
  {
    u32x4 ak[2][2];
    LOAD_AFRAGS(ak);
    for (int nt = 0; nt < 7; ++nt) {
      const int tv = nt * 16 + m16;
      const u32x4 b0 = *(const u32x4*)((const char*)yT + tv * 128 +
                        (((kg * 8) * 2) ^ ((tv & 7) << 4)));
      const u32x4 b1 = *(const u32x4*)((const char*)yT + tv * 128 +
                        (((32 + kg * 8) * 2) ^ ((tv & 7) << 4)));
      #pragma unroll
      for (int mt = 0; mt < 2; ++mt) {
        f32x4 acc = (f32x4)0.f;
        acc = mfma_bf16(ak[mt][0], b0, acc);
        acc = mfma_bf16(ak[mt][1], b1, acc);
        if (tv < 100) {
          const int t = tv / 25, uu = tv % 25;
          const int dr = wid * 32 + mt * 16 + kg * 4;
          #pragma unroll
          for (int i2 = 0; i2 < 4; ++i2)
            kkb[(size_t)(dr + i2) * 3000 + tv] =
                f2b(acc[i2] + biasb[128 + dr + i2] + el[dr + i2][t][uu]);
        }
      }
    }
  }
  #undef STAGE_W
  #undef LOAD_AFRAGS
}

// ---------------------------------------------------------------------------
// Kernel C (R8-verbatim): attT[n,h,v,u]
// ---------------------------------------------------------------------------
__global__ __launch_bounds__(256) void k_att(
    const bf16* __restrict__ qy, const bf16* __restrict__ kkp,
    const float* __restrict__ bq, const float* __restrict__ disg,
    const float* __restrict__ att0, const float* __restrict__ alpha,
    bf16* __restrict__ attT)
{
  const int n = blockIdx.x / HH, h = blockIdx.x % HH;
  __shared__ float qs[DHD][TC + 2][VV];
  __shared__ float ks[DHD][TC][VV];
  __shared__ float mxv[VV], smv[VV];
  const int tid = threadIdx.x;
  const int v = tid % VV;
  const int g = tid / VV;
  const bool act = (g < 10);
  int u_[8], w_[8], up_[8];
  #pragma unroll
  for (int j = 0; j < 8; ++j) {
    int u = g + 10 * j;
    u_[j] = u;
    if (u >= UU) u = 0;
    w_[j] = u / VV; up_[j] = u % VV;
  }
  float acc[8] = {0.f, 0.f, 0.f, 0.f, 0.f, 0.f, 0.f, 0.f};

  for (int t0 = 0; t0 < TT; t0 += TC) {
    __syncthreads();
    for (int i = tid; i < DHD * (TC + 2) * VV; i += 256) {
      const int dh = i / ((TC + 2) * VV);
      const int r  = i % ((TC + 2) * VV);
      const int tt = r / VV, vv = r % VV;
      const int tq = t0 + tt - 1;
      const int dd = h * DHD + dh;
      qs[dh][tt][vv] = (tq >= 0 && tq < TT)
          ? b2f(qy[((size_t)(n * DIMD + dd) * TT + tq) * VV + vv]) : bq[dd];
    }
    for (int i = tid; i < DHD * TC * VV; i += 256) {
      const int dh = i / (TC * VV);
      const int r  = i % (TC * VV);
      const int tt = r / VV, vv = r % VV;
      ks[dh][tt][vv] =
          b2f(kkp[((size_t)(n * DIMD + h * DHD + dh) * TT + t0 + tt) * VV + vv]);
    }
    __syncthreads();
    if (act) {
      for (int dh = 0; dh < DHD; ++dh) {
        #pragma unroll 4
        for (int tt = 0; tt < TC; ++tt) {
          const float kv = ks[dh][tt][v];
          #pragma unroll
          for (int j = 0; j < 8; ++j)
            acc[j] = fmaf(qs[dh][tt + w_[j]][up_[j]], kv, acc[j]);
        }
      }
    }
  }
  __syncthreads();
  float* att_s = &qs[0][0][0];
  const float inv = 1.0f / (float)(DHD * TT);
  if (act) {
    #pragma unroll
    for (int j = 0; j < 8; ++j) {
      if (u_[j] < UU) {
        const bool m = disg[(h * VV + up_[j]) * VV + v] > 0.f;
        att_s[u_[j] * VV + v] = m ? acc[j] * inv : -9e15f;
      }
    }
  }
  __syncthreads();
  if (tid < VV) {
    float mx = -INFINITY;
    for (int u = 0; u < UU; ++u) mx = fmaxf(mx, att_s[u * VV + tid]);
    float sm = 0.f;
    for (int u = 0; u < UU; ++u) sm += expf(att_s[u * VV + tid] - mx);
    mxv[tid] = mx; smv[tid] = sm;
  }
  __syncthreads();
  const float al = alpha[0];
  for (int i = tid; i < UU * VV; i += 256) {
    const int u = i % UU, vc = i / UU;
    const float p = expf(att_s[u * VV + vc] - mxv[vc]) / smv[vc];
    const float o = p * al + att0[(h * VV + u % VV) * VV + vc];
    attT[((size_t)(n * HH + h) * VV + vc) * UU + u] = f2b(o);
  }
}

// ---------------------------------------------------------------------------
// Kernel D v2: 2 blocks/CU (69 KB LDS) + conflict-free pitch-104 tiles.
//   xu staged in two 2-t chunks (A-frags cached in regs); attB double-buffered
//   per-h; residual re-read from global at h==8.
// ---------------------------------------------------------------------------
__global__ __launch_bounds__(256) void k_out_mfma2(
    const float* __restrict__ x, const bf16* __restrict__ attT,
    const float* __restrict__ Wo, const float* __restrict__ b_o,
    const float* __restrict__ g_o, const float* __restrict__ be_o,
    const float* __restrict__ m_o, const float* __restrict__ v_o,
    const float* __restrict__ Wd, const float* __restrict__ b_d,
    const float* __restrict__ g_d, const float* __restrict__ be_d,
    const float* __restrict__ m_d, const float* __restrict__ v_d,
    float* __restrict__ out)
{
  const int n = blockIdx.x / 30, t0 = (blockIdx.x % 30) * TCO;
  __shared__ alignas(16) unsigned short xu2[2][64][104];   // 26,624 B (2 t's)
  __shared__ alignas(16) unsigned short attB[2][32][104];  // 13,312 B dbuf
  __shared__ alignas(16) unsigned short xsl[112][64];      // 14,336 B swz
  __shared__ alignas(16) unsigned short wol[128][64];      // 16,384 B swz
  const int tid = threadIdx.x;
  const int lane = tid & 63, wid = tid >> 6;
  const int m16 = lane & 15, kg = lane >> 4;

  // stage x-unfold for (t0+tb, t0+tb+1); cols 75..95 zeroed, 96..103 unused
  #define STAGE_XU(tb)                                                         \
    for (int i = tid; i < 2 * 64 * 48; i += 256) {                             \
      const int u0 = (i % 48) * 2, c = (i / 48) & 63, tr = i / (48 * 64);      \
      float f0 = 0.f, f1 = 0.f;                                                \
      if (u0 < UU) {                                                           \
        const int w = u0 / VV, up = u0 % VV, ts = t0 + (tb) + tr + w - 1;      \
        if (ts >= 0 && ts < TT) f0 = x[((n * 64 + c) * TT + ts) * VV + up];    \
      }                                                                        \
      if (u0 + 1 < UU) {                                                       \
        const int u = u0 + 1, w = u / VV, up = u % VV;                         \
        const int ts = t0 + (tb) + tr + w - 1;                                 \
        if (ts >= 0 && ts < TT) f1 = x[((n * 64 + c) * TT + ts) * VV + up];    \
      }                                                                        \
      *(unsigned*)&xu2[tr][c][u0] = pack2(f0, f1);                             \
    }

  #define STAGE_ATT(hh, buf)                                                   \
    for (int i = tid; i < 32 * 48; i += 256) {                                 \
      const int u0 = (i % 48) * 2, v = i / 48;                                 \
      float f0 = 0.f, f1 = 0.f;                                                \
      if (v < VV) {                                                            \
        const bf16* src = attT + ((size_t)(n * HH + (hh)) * VV + v) * UU;      \
        if (u0 < UU) f0 = b2f(src[u0]);                                        \
        if (u0 + 1 < UU) f1 = b2f(src[u0 + 1]);                                \
      }                                                                        \
      *(unsigned*)&attB[buf][v][u0] = pack2(f0, f1);                           \
    }

  // ---- phase 0a: chunk 1 (t = 0,1) + xsl junk rows ----
  STAGE_XU(0);
  for (int i = tid; i < 12 * 64; i += 256) xsl[100 + (i >> 6)][i & 63] = 0;
  __syncthreads();
  u32x4 af[4][3];
  if (wid < 2) {
    #pragma unroll
    for (int mt = 0; mt < 4; ++mt)
      #pragma unroll
      for (int ks = 0; ks < 3; ++ks)
        af[mt][ks] = *(const u32x4*)&xu2[wid][mt * 16 + m16][ks * 32 + kg * 8];
  }
  __syncthreads();   // chunk-1 frag reads drained before overwrite
  // ---- phase 0b: chunk 2 (t = 2,3) + attB[0] ----
  STAGE_XU(2);
  STAGE_ATT(0, 0);
  __syncthreads();
  if (wid >= 2) {
    #pragma unroll
    for (int mt = 0; mt < 4; ++mt)
      #pragma unroll
      for (int ks = 0; ks < 3; ++ks)
        af[mt][ks] = *(const u32x4*)&xu2[wid - 2][mt * 16 + m16][ks * 32 + kg * 8];
  }
  // xu2 never written again; attB[1] first written inside h=0 below.

  const int wd_d = tid >> 1, wd_c0 = (tid & 1) * 32;
  const float so_ = g_o[wd_d] * rsqrtf(v_o[wd_d] + 1e-5f);
  const float sd_ = g_d[wd_d] * rsqrtf(v_d[wd_d] + 1e-5f);

  f32x4 acc2[2][7];
  #pragma unroll
  for (int mt = 0; mt < 2; ++mt)
    #pragma unroll
    for (int nt = 0; nt < 7; ++nt) acc2[mt][nt] = (f32x4)0.f;

  for (int h = 0; h <= HH; ++h) {
    float4 wb[8];
    {
      const float* wsrc = (h < HH) ? (Wo + wd_d * 512 + h * 64 + wd_c0)
                                   : (Wd + wd_d * 64 + wd_c0);
      #pragma unroll
      for (int q = 0; q < 8; ++q) wb[q] = ((const float4*)wsrc)[q];
    }
    // prefetch next head's att tile (buffer parity: written here, read at
    // h+1's stage1 — separated by this iteration's two barriers)
    if (h + 1 < HH) { STAGE_ATT(h + 1, (h + 1) & 1); }
    f32x4 a1[4][2];
    if (h < HH) {
      u32x4 bfr[2][3];
      #pragma unroll
      for (int nt = 0; nt < 2; ++nt)
        #pragma unroll
        for (int ks = 0; ks < 3; ++ks)
          bfr[nt][ks] =
              *(const u32x4*)&attB[h & 1][nt * 16 + m16][ks * 32 + kg * 8];
      #pragma unroll
      for (int mt = 0; mt < 4; ++mt)
        #pragma unroll
        for (int nt = 0; nt < 2; ++nt) {
          a1[mt][nt] = (f32x4)0.f;
          #pragma unroll
          for (int ks = 0; ks < 3; ++ks)
            a1[mt][nt] = mfma_bf16(af[mt][ks], bfr[nt][ks], a1[mt][nt]);
        }
    }
    __syncthreads();
    if (h < HH) {
      #pragma unroll
      for (int mt = 0; mt < 4; ++mt)
        #pragma unroll
        for (int nt = 0; nt < 2; ++nt) {
          const int v = nt * 16 + m16;
          if (v < VV) {
            const int tv = wid * VV + v;
            const int c0 = mt * 16 + kg * 4;
            u32x2 pk;
            pk[0] = pack2(a1[mt][nt][0], a1[mt][nt][1]);
            pk[1] = pack2(a1[mt][nt][2], a1[mt][nt][3]);
            char* p = (char*)xsl + tv * 128 + ((c0 * 2) ^ ((tv & 7) << 4));
            *(u32x2*)p = pk;
          }
        }
    } else {
      // residual: re-read x (coalesced: contiguous 100 floats per c)
      for (int i = tid; i < 6400; i += 256) {
        const int c = i / 100, j = i % 100;   // j = tl*25 + v
        const float f = x[((size_t)(n * 64 + c) * TT + t0) * VV + j];
        *(unsigned short*)((char*)xsl + j * 128 + ((c * 2) ^ ((j & 7) << 4))) =
            f2bu(f);
      }
    }
    {
      const float sc = (h < HH) ? so_ : sd_;
      #pragma unroll
      for (int q = 0; q < 4; ++q) {
        const float4 p0 = wb[q * 2], p1 = wb[q * 2 + 1];
        u32x4 wv;
        wv[0] = pack2(p0.x * sc, p0.y * sc); wv[1] = pack2(p0.z * sc, p0.w * sc);
        wv[2] = pack2(p1.x * sc, p1.y * sc); wv[3] = pack2(p1.z * sc, p1.w * sc);
        char* p = (char*)wol + wd_d * 128 + ((wd_c0 * 2 + q * 16) ^ ((wd_d & 7) << 4));
        *(u32x4*)p = wv;
      }
    }
    __syncthreads();
    u32x4 a2[2][2];
    #pragma unroll
    for (int mt = 0; mt < 2; ++mt)
      #pragma unroll
      for (int ks = 0; ks < 2; ++ks) {
        const int d = wid * 32 + mt * 16 + m16;
        a2[mt][ks] = *(const u32x4*)((const char*)wol + d * 128 +
                      (((ks * 32 + kg * 8) * 2) ^ ((d & 7) << 4)));
      }
    #pragma unroll
    for (int nt = 0; nt < 7; ++nt) {
      const int tv = nt * 16 + m16;
      const u32x4 b0 = *(const u32x4*)((const char*)xsl + tv * 128 +
                        (((kg * 8) * 2) ^ ((tv & 7) << 4)));
      const u32x4 b1 = *(const u32x4*)((const char*)xsl + tv * 128 +
                        (((32 + kg * 8) * 2) ^ ((tv & 7) << 4)));
      #pragma unroll
      for (int mt = 0; mt < 2; ++mt) {
        acc2[mt][nt] = mfma_bf16(a2[mt][0], b0, acc2[mt][nt]);
        acc2[mt][nt] = mfma_bf16(a2[mt][1], b1, acc2[mt][nt]);
      }
    }
  }

  #pragma unroll
  for (int mt = 0; mt < 2; ++mt) {
    float cc[4];
    #pragma unroll
    for (int i = 0; i < 4; ++i) {
      const int d = wid * 32 + mt * 16 + kg * 4 + i;
      const float so2 = g_o[d] * rsqrtf(v_o[d] + 1e-5f);
      const float sd2 = g_d[d] * rsqrtf(v_d[d] + 1e-5f);
      cc[i] = b_o[d] * so2 + be_o[d] - m_o[d] * so2
            + b_d[d] * sd2 + be_d[d] - m_d[d] * sd2;
    }
    #pragma unroll
    for (int nt = 0; nt < 7; ++nt) {
      const int tv = nt * 16 + m16;
      if (tv < 100) {
        const int t = t0 + tv / VV, v = tv % VV;
        #pragma unroll
        for (int i = 0; i < 4; ++i) {
          const int d = wid * 32 + mt * 16 + kg * 4 + i;
          const float z = acc2[mt][nt][i] + cc[i];
          out[((n * DIMD + d) * TT + t) * VV + v] = (z >= 0.f) ? z : 0.1f * z;
        }
      }
    }
  }
  #undef STAGE_XU
  #undef STAGE_ATT
}

// ---------------------------------------------------------------------------
extern "C" void kernel_launch(void* const* d_in, const int* in_sizes, int n_in,
                              void* d_out, int out_size, void* d_ws, size_t ws_size,
                              hipStream_t stream)
{
  (void)in_sizes; (void)n_in; (void)out_size; (void)ws_size;
  const float* x     = (const float*)d_in[0];
  const float* Wq    = (const float*)d_in[1];
  const float* bq    = (const float*)d_in[2];
  const float* Wk    = (const float*)d_in[3];
  const float* bk    = (const float*)d_in[4];
  const float* We    = (const float*)d_in[5];
  const float* be    = (const float*)d_in[6];
  const float* G     = (const float*)d_in[7];
  const float* sepe  = (const float*)d_in[8];
  const float* att0  = (const float*)d_in[9];
  const float* alpha = (const float*)d_in[10];
  const float* beta  = (const float*)d_in[11];
  const float* Wo    = (const float*)d_in[12];
  const float* b_o   = (const float*)d_in[13];
  const float* g_o   = (const float*)d_in[14];
  const float* be_o  = (const float*)d_in[15];
  const float* m_o   = (const float*)d_in[16];
  const float* v_o   = (const float*)d_in[17];
  const float* Wd    = (const float*)d_in[18];
  const float* b_d   = (const float*)d_in[19];
  const float* g_d   = (const float*)d_in[20];
  const float* be_d  = (const float*)d_in[21];
  const float* m_d   = (const float*)d_in[22];
  const float* v_d   = (const float*)d_in[23];
  const int*   dism  = (const int*)d_in[24];
  const float* disg  = (const float*)d_in[25];

  // Workspace (bf16): qy @0, kk @49,152,000, attT @98,304,000
  char* ws = (char*)d_ws;
  bf16* qy   = (bf16*)(ws);
  bf16* kkp  = (bf16*)(ws + 49152000);
  bf16* attT = (bf16*)(ws + 98304000);

  k_qke_mfma3<<<NB * 30, 256, 0, stream>>>(x, Wq, bq, Wk, bk, We, be, G, beta,
                                           sepe, dism, qy, kkp);
  k_att<<<NB * HH, 256, 0, stream>>>(qy, kkp, bq, disg, att0, alpha, attT);
  k_out_mfma2<<<NB * 30, 256, 0, stream>>>(x, attT, Wo, b_o, g_o, be_o, m_o, v_o,
                                           Wd, b_d, g_d, be_d, m_d, v_d, (float*)d_out);
}

// Round 11
// 763.480 us; speedup vs baseline: 9.0601x; 1.1723x over previous
//
#include <hip/hip_runtime.h>
#include <hip/hip_bf16.h>
#include <math.h>

// Problem constants (fixed by the reference)
#define NB   64     // batch
#define CIN  64     // input channels
#define DIMD 128    // q/k/e channels
#define TT   120    // time
#define VV   25     // joints
#define HH   8      // heads
#define DHD  16     // DIM/H
#define WW   3      // temporal window
#define UU   75     // W*V
#define TC   24     // t-chunk in attention kernel (120 = 5*24)
#define TCO  4      // t-chunk in output kernel (120 = 4*30)

typedef __hip_bfloat16 bf16;
typedef float        f32x4  __attribute__((ext_vector_type(4)));
typedef unsigned int u32x4  __attribute__((ext_vector_type(4)));
typedef unsigned int u32x2  __attribute__((ext_vector_type(2)));
typedef __bf16       bf16x8 __attribute__((ext_vector_type(8)));

__device__ __forceinline__ float b2f(bf16 v)  { return __bfloat162float(v); }
__device__ __forceinline__ bf16  f2b(float v) { return __float2bfloat16(v); }

__device__ __forceinline__ unsigned short f2bu(float f) {
  unsigned u = __builtin_bit_cast(unsigned, f);
  return (unsigned short)((u + 0x7fffu + ((u >> 16) & 1u)) >> 16);  // RNE
}
__device__ __forceinline__ float bfu(unsigned short s) {
  unsigned u = ((unsigned)s) << 16;
  return __builtin_bit_cast(float, u);
}
__device__ __forceinline__ unsigned pack2(float a, float b) {
  return ((unsigned)f2bu(b) << 16) | (unsigned)f2bu(a);
}

// D = A(16x32) * B(32x16) + D, bf16 inputs, f32 acc.
// BUILTIN (not inline asm): the GCN hazard recognizer only inserts the
// required MFMA->VALU wait-states for instructions it can see as MAI;
// an asm block is opaque -> silent accumulator corruption (R6/R7/R10).
__device__ __forceinline__ f32x4 mfma_bf16(u32x4 a, u32x4 b, f32x4 d) {
  return __builtin_amdgcn_mfma_f32_16x16x32_bf16(
      __builtin_bit_cast(bf16x8, a), __builtin_bit_cast(bf16x8, b), d, 0, 0, 0);
}

// ---------------------------------------------------------------------------
// Fused A+B v4: el buffer eliminated via kk = Wk@y + beta*We@(y@G) + bias.
//   phase1  : y -> yT (R8-verified)
//   phase1b : yTG[c][t,v] = sum_u y[c][t,u]*G[u][v]  (scalar, swz store)
//   q-GEMM(yT) -> global; k-GEMM(yT) -> kacc regs; e-GEMM(beta*We, yTG)
//   accumulates into kacc; epilogue adds bk + beta*be*gsum[v] -> kk.
// LDS ~79.7 KB -> 2 blocks/CU.
// ---------------------------------------------------------------------------
__global__ __launch_bounds__(256) void k_qke_mfma4(
    const float* __restrict__ x,
    const float* __restrict__ Wq, const float* __restrict__ bq,
    const float* __restrict__ Wk, const float* __restrict__ bk,
    const float* __restrict__ We, const float* __restrict__ be,
    const float* __restrict__ G,  const float* __restrict__ beta,
    const float* __restrict__ se_pe, const int* __restrict__ dis,
    bf16* __restrict__ qy, bf16* __restrict__ kkp)
{
  const int n = blockIdx.x / 30, t0 = (blockIdx.x % 30) * 4;
  __shared__ alignas(16) float xl[4][64][26];            // 26,624  x f32
  __shared__ alignas(16) float spl[5][64];               //  1,280
  __shared__ alignas(16) int   dml[25][25];              //  2,500
  __shared__ alignas(16) float Gl[25][26];               //  2,600
  __shared__ alignas(16) float gsum[32];                 //    128  sum_u G[u][v]
  __shared__ alignas(16) float biasb[384];               //  1,536  bq|bk|be
  __shared__ alignas(16) unsigned short yT[112][64];     // 14,336  [tv][c] swz
  __shared__ alignas(16) unsigned short yTG[112][64];    // 14,336  [tv][c] swz
  __shared__ alignas(16) unsigned short wl[128][64];     // 16,384  [d][c]  swz

  const int tid = threadIdx.x;
  // ---- phase 0: stage ----
  {
    const float* xb = x + (size_t)n * 192000 + t0 * 25;  // x[n][c][t0+t][v]
    for (int i = tid; i < 6400; i += 256) {
      const int c = i / 100, j = i % 100, t = j / 25, v = j % 25;
      xl[t][c][v] = xb[c * 3000 + j];
    }
  }
  for (int i = tid; i < 320; i += 256) spl[i / 64][i % 64] = se_pe[i];
  for (int i = tid; i < 625; i += 256) dml[i / 25][i % 25] = dis[i];
  for (int i = tid; i < 625; i += 256) Gl[i / 25][i % 25] = G[i];
  if (tid < 25) {                                        // gsum[v] = sum_u G[u][v]
    float s = 0.f;
    for (int u = 0; u < 25; ++u) s += G[u * 25 + tid];
    gsum[tid] = s;
  }
  for (int i = tid; i < 384; i += 256)
    biasb[i] = (i < 128) ? bq[i] : (i < 256 ? bk[i - 128] : be[i - 256]);
  for (int i = tid; i < 12 * 64; i += 256) {             // junk rows -> 0
    yT[100 + (i >> 6)][i & 63] = 0;
    yTG[100 + (i >> 6)][i & 63] = 0;
  }
  __syncthreads();

  const int lane = tid & 63, wid = tid >> 6;
  const int m16 = lane & 15, kg = lane >> 4;
  const int wd_d = tid >> 1, wd_c0 = (tid & 1) * 32;

  // R2-verified wol staging (f32 -> bf16, d&7 XOR swizzle), with scale
  #define STAGE_WS(Wsrc, SC)                                                   \
    {                                                                          \
      const float* wsrc = (Wsrc) + wd_d * 64 + wd_c0;                          \
      const float sc_ = (SC);                                                  \
      _Pragma("unroll")                                                        \
      for (int q2 = 0; q2 < 4; ++q2) {                                         \
        const float4 p0 = *(const float4*)(wsrc + q2 * 8);                     \
        const float4 p1 = *(const float4*)(wsrc + q2 * 8 + 4);                 \
        u32x4 wv;                                                              \
        wv[0] = pack2(p0.x * sc_, p0.y * sc_);                                 \
        wv[1] = pack2(p0.z * sc_, p0.w * sc_);                                 \
        wv[2] = pack2(p1.x * sc_, p1.y * sc_);                                 \
        wv[3] = pack2(p1.z * sc_, p1.w * sc_);                                 \
        char* p = (char*)wl + wd_d * 128 +                                     \
                  ((wd_c0 * 2 + q2 * 16) ^ ((wd_d & 7) << 4));                 \
        *(u32x4*)p = wv;                                                       \
      }                                                                        \
    }

  #define LOAD_AFRAGS(af)                                                      \
    _Pragma("unroll")                                                          \
    for (int mt = 0; mt < 2; ++mt) {                                           \
      _Pragma("unroll")                                                        \
      for (int ks = 0; ks < 2; ++ks) {                                         \
        const int d_ = wid * 32 + mt * 16 + m16;                               \
        af[mt][ks] = *(const u32x4*)((const char*)wl + d_ * 128 +              \
                      (((ks * 32 + kg * 8) * 2) ^ ((d_ & 7) << 4)));           \
      }                                                                        \
    }

  // ---- phase 1 (R8-verified): yT = x + pe + struct-enc ----
  for (int idx = tid; idx < 6400; idx += 256) {
    const int c = idx & 63, tv = idx >> 6;
    const int t = tv / 25, v = tv % 25;
    const float dv = expf(-(float)(c & ~1) * (logf(10000.0f) / 64.0f));
    float acc = xl[t][c][v] +
                ((c & 1) ? cosf((float)v * dv) : sinf((float)v * dv));
    #pragma unroll
    for (int u = 0; u < 25; ++u)
      acc = fmaf(xl[t][c][u], spl[dml[u][v]][c], acc);
    *(unsigned short*)((char*)yT + tv * 128 + ((c * 2) ^ ((tv & 7) << 4))) =
        f2bu(acc);
  }
  __syncthreads();   // yT ready

  // ---- phase 1b: yTG[c][t,v] = sum_u y[c][t,u] * G[u][v] ----
  for (int idx = tid; idx < 6400; idx += 256) {
    const int c = idx & 63, tv = idx >> 6;
    const int t = tv / 25, v = tv % 25;
    float acc = 0.f;
    #pragma unroll
    for (int u = 0; u < 25; ++u) {
      const int ru = t * 25 + u;
      const float yv = bfu(*(const unsigned short*)((const char*)yT + ru * 128 +
                            ((c * 2) ^ ((ru & 7) << 4))));
      acc = fmaf(yv, Gl[u][v], acc);
    }
    *(unsigned short*)((char*)yTG + tv * 128 + ((c * 2) ^ ((tv & 7) << 4))) =
        f2bu(acc);
  }
  __syncthreads();   // yTG ready

  bf16* qyb = qy  + (size_t)n * 384000 + t0 * 25;
  bf16* kkb = kkp + (size_t)n * 384000 + t0 * 25;
  const float betav = beta[0];

  // ---- stage Wq -> bar -> q-GEMM ----
  STAGE_WS(Wq, 1.0f);
  __syncthreads();
  {
    u32x4 aq[2][2];
    LOAD_AFRAGS(aq);
    for (int nt = 0; nt < 7; ++nt) {
      const int tv = nt * 16 + m16;
      const u32x4 b0 = *(const u32x4*)((const char*)yT + tv * 128 +
                        (((kg * 8) * 2) ^ ((tv & 7) << 4)));
      const u32x4 b1 = *(const u32x4*)((const char*)yT + tv * 128 +
                        (((32 + kg * 8) * 2) ^ ((tv & 7) << 4)));
      #pragma unroll
      for (int mt = 0; mt < 2; ++mt) {
        f32x4 acc = (f32x4)0.f;
        acc = mfma_bf16(aq[mt][0], b0, acc);
        acc = mfma_bf16(aq[mt][1], b1, acc);
        if (tv < 100) {
          const int dr = wid * 32 + mt * 16 + kg * 4;
          #pragma unroll
          for (int i2 = 0; i2 < 4; ++i2)
            qyb[(size_t)(dr + i2) * 3000 + tv] = f2b(acc[i2] + biasb[dr + i2]);
        }
      }
    }
  }
  __syncthreads();   // wl(Wq) reads drained

  // ---- stage Wk -> bar -> k-GEMM into persistent kacc ----
  f32x4 kacc[2][7];
  #pragma unroll
  for (int mt = 0; mt < 2; ++mt)
    #pragma unroll
    for (int nt = 0; nt < 7; ++nt) kacc[mt][nt] = (f32x4)0.f;

  STAGE_WS(Wk, 1.0f);
  __syncthreads();
  {
    u32x4 ak[2][2];
    LOAD_AFRAGS(ak);
    for (int nt = 0; nt < 7; ++nt) {
      const int tv = nt * 16 + m16;
      const u32x4 b0 = *(const u32x4*)((const char*)yT + tv * 128 +
                        (((kg * 8) * 2) ^ ((tv & 7) << 4)));
      const u32x4 b1 = *(const u32x4*)((const char*)yT + tv * 128 +
                        (((32 + kg * 8) * 2) ^ ((tv & 7) << 4)));
      #pragma unroll
      for (int mt = 0; mt < 2; ++mt) {
        kacc[mt][nt] = mfma_bf16(ak[mt][0], b0, kacc[mt][nt]);
        kacc[mt][nt] = mfma_bf16(ak[mt][1], b1, kacc[mt][nt]);
      }
    }
  }
  __syncthreads();   // wl(Wk) reads drained

  // ---- stage beta*We -> bar -> e-GEMM on yTG, accumulate, store kk ----
  STAGE_WS(We, betav);
  __syncthreads();
  {
    u32x4 ae[2][2];
    LOAD_AFRAGS(ae);
    for (int nt = 0; nt < 7; ++nt) {
      const int tv = nt * 16 + m16;
      const u32x4 b0 = *(const u32x4*)((const char*)yTG + tv * 128 +
                        (((kg * 8) * 2) ^ ((tv & 7) << 4)));
      const u32x4 b1 = *(const u32x4*)((const char*)yTG + tv * 128 +
                        (((32 + kg * 8) * 2) ^ ((tv & 7) << 4)));
      #pragma unroll
      for (int mt = 0; mt < 2; ++mt) {
        kacc[mt][nt] = mfma_bf16(ae[mt][0], b0, kacc[mt][nt]);
        kacc[mt][nt] = mfma_bf16(ae[mt][1], b1, kacc[mt][nt]);
        if (tv < 100) {
          const int vv = tv % 25;
          const int dr = wid * 32 + mt * 16 + kg * 4;
          #pragma unroll
          for (int i2 = 0; i2 < 4; ++i2)
            kkb[(size_t)(dr + i2) * 3000 + tv] =
                f2b(kacc[mt][nt][i2] + biasb[128 + dr + i2] +
                    betav * biasb[256 + dr + i2] * gsum[vv]);
        }
      }
    }
  }
  #undef STAGE_WS
  #undef LOAD_AFRAGS
}

// ---------------------------------------------------------------------------
// Kernel C (R8-verbatim): attT[n,h,v,u]
// ---------------------------------------------------------------------------
__global__ __launch_bounds__(256) void k_att(
    const bf16* __restrict__ qy, const bf16* __restrict__ kkp,
    const float* __restrict__ bq, const float* __restrict__ disg,
    const float* __restrict__ att0, const float* __restrict__ alpha,
    bf16* __restrict__ attT)
{
  const int n = blockIdx.x / HH, h = blockIdx.x % HH;
  __shared__ float qs[DHD][TC + 2][VV];
  __shared__ float ks[DHD][TC][VV];
  __shared__ float mxv[VV], smv[VV];
  const int tid = threadIdx.x;
  const int v = tid % VV;
  const int g = tid / VV;
  const bool act = (g < 10);
  int u_[8], w_[8], up_[8];
  #pragma unroll
  for (int j = 0; j < 8; ++j) {
    int u = g + 10 * j;
    u_[j] = u;
    if (u >= UU) u = 0;
    w_[j] = u / VV; up_[j] = u % VV;
  }
  float acc[8] = {0.f, 0.f, 0.f, 0.f, 0.f, 0.f, 0.f, 0.f};

  for (int t0 = 0; t0 < TT; t0 += TC) {
    __syncthreads();
    for (int i = tid; i < DHD * (TC + 2) * VV; i += 256) {
      const int dh = i / ((TC + 2) * VV);
      const int r  = i % ((TC + 2) * VV);
      const int tt = r / VV, vv = r % VV;
      const int tq = t0 + tt - 1;
      const int dd = h * DHD + dh;
      qs[dh][tt][vv] = (tq >= 0 && tq < TT)
          ? b2f(qy[((size_t)(n * DIMD + dd) * TT + tq) * VV + vv]) : bq[dd];
    }
    for (int i = tid; i < DHD * TC * VV; i += 256) {
      const int dh = i / (TC * VV);
      const int r  = i % (TC * VV);
      const int tt = r / VV, vv = r % VV;
      ks[dh][tt][vv] =
          b2f(kkp[((size_t)(n * DIMD + h * DHD + dh) * TT + t0 + tt) * VV + vv]);
    }
    __syncthreads();
    if (act) {
      for (int dh = 0; dh < DHD; ++dh) {
        #pragma unroll 4
        for (int tt = 0; tt < TC; ++tt) {
          const float kv = ks[dh][tt][v];
          #pragma unroll
          for (int j = 0; j < 8; ++j)
            acc[j] = fmaf(qs[dh][tt + w_[j]][up_[j]], kv, acc[j]);
        }
      }
    }
  }
  __syncthreads();
  float* att_s = &qs[0][0][0];
  const float inv = 1.0f / (float)(DHD * TT);
  if (act) {
    #pragma unroll
    for (int j = 0; j < 8; ++j) {
      if (u_[j] < UU) {
        const bool m = disg[(h * VV + up_[j]) * VV + v] > 0.f;
        att_s[u_[j] * VV + v] = m ? acc[j] * inv : -9e15f;
      }
    }
  }
  __syncthreads();
  if (tid < VV) {
    float mx = -INFINITY;
    for (int u = 0; u < UU; ++u) mx = fmaxf(mx, att_s[u * VV + tid]);
    float sm = 0.f;
    for (int u = 0; u < UU; ++u) sm += expf(att_s[u * VV + tid] - mx);
    mxv[tid] = mx; smv[tid] = sm;
  }
  __syncthreads();
  const float al = alpha[0];
  for (int i = tid; i < UU * VV; i += 256) {
    const int u = i % UU, vc = i / UU;
    const float p = expf(att_s[u * VV + vc] - mxv[vc]) / smv[vc];
    const float o = p * al + att0[(h * VV + u % VV) * VV + vc];
    attT[((size_t)(n * HH + h) * VV + vc) * UU + u] = f2b(o);
  }
}

// ---------------------------------------------------------------------------
// Kernel D v2 (R9-verbatim structure, builtin MFMA): 2 blocks/CU.
// ---------------------------------------------------------------------------
__global__ __launch_bounds__(256) void k_out_mfma2(
    const float* __restrict__ x, const bf16* __restrict__ attT,
    const float* __restrict__ Wo, const float* __restrict__ b_o,
    const float* __restrict__ g_o, const float* __restrict__ be_o,
    const float* __restrict__ m_o, const float* __restrict__ v_o,
    const float* __restrict__ Wd, const float* __restrict__ b_d,
    const float* __restrict__ g_d, const float* __restrict__ be_d,
    const float* __restrict__ m_d, const float* __restrict__ v_d,
    float* __restrict__ out)
{
  const int n = blockIdx.x / 30, t0 = (blockIdx.x % 30) * TCO;
  __shared__ alignas(16) unsigned short xu2[2][64][104];   // 26,624 B (2 t's)
  __shared__ alignas(16) unsigned short attB[2][32][104];  // 13,312 B dbuf
  __shared__ alignas(16) unsigned short xsl[112][64];      // 14,336 B swz
  __shared__ alignas(16) unsigned short wol[128][64];      // 16,384 B swz
  const int tid = threadIdx.x;
  const int lane = tid & 63, wid = tid >> 6;
  const int m16 = lane & 15, kg = lane >> 4;

  #define STAGE_XU(tb)                                                         \
    for (int i = tid; i < 2 * 64 * 48; i += 256) {                             \
      const int u0 = (i % 48) * 2, c = (i / 48) & 63, tr = i / (48 * 64);      \
      float f0 = 0.f, f1 = 0.f;                                                \
      if (u0 < UU) {                                                           \
        const int w = u0 / VV, up = u0 % VV, ts = t0 + (tb) + tr + w - 1;      \
        if (ts >= 0 && ts < TT) f0 = x[((n * 64 + c) * TT + ts) * VV + up];    \
      }                                                                        \
      if (u0 + 1 < UU) {                                                       \
        const int u = u0 + 1, w = u / VV, up = u % VV;                         \
        const int ts = t0 + (tb) + tr + w - 1;                                 \
        if (ts >= 0 && ts < TT) f1 = x[((n * 64 + c) * TT + ts) * VV + up];    \
      }                                                                        \
      *(unsigned*)&xu2[tr][c][u0] = pack2(f0, f1);                             \
    }

  #define STAGE_ATT(hh, buf)                                                   \
    for (int i = tid; i < 32 * 48; i += 256) {                                 \
      const int u0 = (i % 48) * 2, v = i / 48;                                 \
      float f0 = 0.f, f1 = 0.f;                                                \
      if (v < VV) {                                                            \
        const bf16* src = attT + ((size_t)(n * HH + (hh)) * VV + v) * UU;      \
        if (u0 < UU) f0 = b2f(src[u0]);                                        \
        if (u0 + 1 < UU) f1 = b2f(src[u0 + 1]);                                \
      }                                                                        \
      *(unsigned*)&attB[buf][v][u0] = pack2(f0, f1);                           \
    }

  STAGE_XU(0);
  for (int i = tid; i < 12 * 64; i += 256) xsl[100 + (i >> 6)][i & 63] = 0;
  __syncthreads();
  u32x4 af[4][3];
  if (wid < 2) {
    #pragma unroll
    for (int mt = 0; mt < 4; ++mt)
      #pragma unroll
      for (int ks = 0; ks < 3; ++ks)
        af[mt][ks] = *(const u32x4*)&xu2[wid][mt * 16 + m16][ks * 32 + kg * 8];
  }
  __syncthreads();
  STAGE_XU(2);
  STAGE_ATT(0, 0);
  __syncthreads();
  if (wid >= 2) {
    #pragma unroll
    for (int mt = 0; mt < 4; ++mt)
      #pragma unroll
      for (int ks = 0; ks < 3; ++ks)
        af[mt][ks] = *(const u32x4*)&xu2[wid - 2][mt * 16 + m16][ks * 32 + kg * 8];
  }

  const int wd_d = tid >> 1, wd_c0 = (tid & 1) * 32;
  const float so_ = g_o[wd_d] * rsqrtf(v_o[wd_d] + 1e-5f);
  const float sd_ = g_d[wd_d] * rsqrtf(v_d[wd_d] + 1e-5f);

  f32x4 acc2[2][7];
  #pragma unroll
  for (int mt = 0; mt < 2; ++mt)
    #pragma unroll
    for (int nt = 0; nt < 7; ++nt) acc2[mt][nt] = (f32x4)0.f;

  for (int h = 0; h <= HH; ++h) {
    float4 wb[8];
    {
      const float* wsrc = (h < HH) ? (Wo + wd_d * 512 + h * 64 + wd_c0)
                                   : (Wd + wd_d * 64 + wd_c0);
      #pragma unroll
      for (int q = 0; q < 8; ++q) wb[q] = ((const float4*)wsrc)[q];
    }
    if (h + 1 < HH) { STAGE_ATT(h + 1, (h + 1) & 1); }
    f32x4 a1[4][2];
    if (h < HH) {
      u32x4 bfr[2][3];
      #pragma unroll
      for (int nt = 0; nt < 2; ++nt)
        #pragma unroll
        for (int ks = 0; ks < 3; ++ks)
          bfr[nt][ks] =
              *(const u32x4*)&attB[h & 1][nt * 16 + m16][ks * 32 + kg * 8];
      #pragma unroll
      for (int mt = 0; mt < 4; ++mt)
        #pragma unroll
        for (int nt = 0; nt < 2; ++nt) {
          a1[mt][nt] = (f32x4)0.f;
          #pragma unroll
          for (int ks = 0; ks < 3; ++ks)
            a1[mt][nt] = mfma_bf16(af[mt][ks], bfr[nt][ks], a1[mt][nt]);
        }
    }
    __syncthreads();
    if (h < HH) {
      #pragma unroll
      for (int mt = 0; mt < 4; ++mt)
        #pragma unroll
        for (int nt = 0; nt < 2; ++nt) {
          const int v = nt * 16 + m16;
          if (v < VV) {
            const int tv = wid * VV + v;
            const int c0 = mt * 16 + kg * 4;
            u32x2 pk;
            pk[0] = pack2(a1[mt][nt][0], a1[mt][nt][1]);
            pk[1] = pack2(a1[mt][nt][2], a1[mt][nt][3]);
            char* p = (char*)xsl + tv * 128 + ((c0 * 2) ^ ((tv & 7) << 4));
            *(u32x2*)p = pk;
          }
        }
    } else {
      for (int i = tid; i < 6400; i += 256) {
        const int c = i / 100, j = i % 100;
        const float f = x[((size_t)(n * 64 + c) * TT + t0) * VV + j];
        *(unsigned short*)((char*)xsl + j * 128 + ((c * 2) ^ ((j & 7) << 4))) =
            f2bu(f);
      }
    }
    {
      const float sc = (h < HH) ? so_ : sd_;
      #pragma unroll
      for (int q = 0; q < 4; ++q) {
        const float4 p0 = wb[q * 2], p1 = wb[q * 2 + 1];
        u32x4 wv;
        wv[0] = pack2(p0.x * sc, p0.y * sc); wv[1] = pack2(p0.z * sc, p0.w * sc);
        wv[2] = pack2(p1.x * sc, p1.y * sc); wv[3] = pack2(p1.z * sc, p1.w * sc);
        char* p = (char*)wol + wd_d * 128 + ((wd_c0 * 2 + q * 16) ^ ((wd_d & 7) << 4));
        *(u32x4*)p = wv;
      }
    }
    __syncthreads();
    u32x4 a2[2][2];
    #pragma unroll
    for (int mt = 0; mt < 2; ++mt)
      #pragma unroll
      for (int ks = 0; ks < 2; ++ks) {
        const int d = wid * 32 + mt * 16 + m16;
        a2[mt][ks] = *(const u32x4*)((const char*)wol + d * 128 +
                      (((ks * 32 + kg * 8) * 2) ^ ((d & 7) << 4)));
      }
    #pragma unroll
    for (int nt = 0; nt < 7; ++nt) {
      const int tv = nt * 16 + m16;
      const u32x4 b0 = *(const u32x4*)((const char*)xsl + tv * 128 +
                        (((kg * 8) * 2) ^ ((tv & 7) << 4)));
      const u32x4 b1 = *(const u32x4*)((const char*)xsl + tv * 128 +
                        (((32 + kg * 8) * 2) ^ ((tv & 7) << 4)));
      #pragma unroll
      for (int mt = 0; mt < 2; ++mt) {
        acc2[mt][nt] = mfma_bf16(a2[mt][0], b0, acc2[mt][nt]);
        acc2[mt][nt] = mfma_bf16(a2[mt][1], b1, acc2[mt][nt]);
      }
    }
  }

  #pragma unroll
  for (int mt = 0; mt < 2; ++mt) {
    float cc[4];
    #pragma unroll
    for (int i = 0; i < 4; ++i) {
      const int d = wid * 32 + mt * 16 + kg * 4 + i;
      const float so2 = g_o[d] * rsqrtf(v_o[d] + 1e-5f);
      const float sd2 = g_d[d] * rsqrtf(v_d[d] + 1e-5f);
      cc[i] = b_o[d] * so2 + be_o[d] - m_o[d] * so2
            + b_d[d] * sd2 + be_d[d] - m_d[d] * sd2;
    }
    #pragma unroll
    for (int nt = 0; nt < 7; ++nt) {
      const int tv = nt * 16 + m16;
      if (tv < 100) {
        const int t = t0 + tv / VV, v = tv % VV;
        #pragma unroll
        for (int i = 0; i < 4; ++i) {
          const int d = wid * 32 + mt * 16 + kg * 4 + i;
          const float z = acc2[mt][nt][i] + cc[i];
          out[((n * DIMD + d) * TT + t) * VV + v] = (z >= 0.f) ? z : 0.1f * z;
        }
      }
    }
  }
  #undef STAGE_XU
  #undef STAGE_ATT
}

// ---------------------------------------------------------------------------
extern "C" void kernel_launch(void* const* d_in, const int* in_sizes, int n_in,
                              void* d_out, int out_size, void* d_ws, size_t ws_size,
                              hipStream_t stream)
{
  (void)in_sizes; (void)n_in; (void)out_size; (void)ws_size;
  const float* x     = (const float*)d_in[0];
  const float* Wq    = (const float*)d_in[1];
  const float* bq    = (const float*)d_in[2];
  const float* Wk    = (const float*)d_in[3];
  const float* bk    = (const float*)d_in[4];
  const float* We    = (const float*)d_in[5];
  const float* be    = (const float*)d_in[6];
  const float* G     = (const float*)d_in[7];
  const float* sepe  = (const float*)d_in[8];
  const float* att0  = (const float*)d_in[9];
  const float* alpha = (const float*)d_in[10];
  const float* beta  = (const float*)d_in[11];
  const float* Wo    = (const float*)d_in[12];
  const float* b_o   = (const float*)d_in[13];
  const float* g_o   = (const float*)d_in[14];
  const float* be_o  = (const float*)d_in[15];
  const float* m_o   = (const float*)d_in[16];
  const float* v_o   = (const float*)d_in[17];
  const float* Wd    = (const float*)d_in[18];
  const float* b_d   = (const float*)d_in[19];
  const float* g_d   = (const float*)d_in[20];
  const float* be_d  = (const float*)d_in[21];
  const float* m_d   = (const float*)d_in[22];
  const float* v_d   = (const float*)d_in[23];
  const int*   dism  = (const int*)d_in[24];
  const float* disg  = (const float*)d_in[25];

  // Workspace (bf16): qy @0, kk @49,152,000, attT @98,304,000
  char* ws = (char*)d_ws;
  bf16* qy   = (bf16*)(ws);
  bf16* kkp  = (bf16*)(ws + 49152000);
  bf16* attT = (bf16*)(ws + 98304000);

  k_qke_mfma4<<<NB * 30, 256, 0, stream>>>(x, Wq, bq, Wk, bk, We, be, G, beta,
                                           sepe, dism, qy, kkp);
  k_att<<<NB * HH, 256, 0, stream>>>(qy, kkp, bq, disg, att0, alpha, attT);
  k_out_mfma2<<<NB * 30, 256, 0, stream>>>(x, attT, Wo, b_o, g_o, be_o, m_o, v_o,
                                           Wd, b_d, g_d, be_d, m_d, v_d, (float*)d_out);
}

// Round 12
// 717.979 us; speedup vs baseline: 9.6343x; 1.0634x over previous
//
#include <hip/hip_runtime.h>
#include <hip/hip_bf16.h>
#include <math.h>

// Problem constants (fixed by the reference)
#define NB   64     // batch
#define CIN  64     // input channels
#define DIMD 128    // q/k/e channels
#define TT   120    // time
#define VV   25     // joints
#define HH   8      // heads
#define DHD  16     // DIM/H
#define WW   3      // temporal window
#define UU   75     // W*V
#define TC   24     // t-chunk in attention kernel (120 = 5*24)
#define TCO  4      // t-chunk in output kernel (120 = 4*30)

typedef __hip_bfloat16 bf16;
typedef float        f32x4  __attribute__((ext_vector_type(4)));
typedef unsigned int u32x4  __attribute__((ext_vector_type(4)));
typedef unsigned int u32x2  __attribute__((ext_vector_type(2)));
typedef __bf16       bf16x8 __attribute__((ext_vector_type(8)));

__device__ __forceinline__ float b2f(bf16 v)  { return __bfloat162float(v); }
__device__ __forceinline__ bf16  f2b(float v) { return __float2bfloat16(v); }

__device__ __forceinline__ unsigned short f2bu(float f) {
  unsigned u = __builtin_bit_cast(unsigned, f);
  return (unsigned short)((u + 0x7fffu + ((u >> 16) & 1u)) >> 16);  // RNE
}
__device__ __forceinline__ float bfu(unsigned short s) {
  unsigned u = ((unsigned)s) << 16;
  return __builtin_bit_cast(float, u);
}
__device__ __forceinline__ unsigned pack2(float a, float b) {
  return ((unsigned)f2bu(b) << 16) | (unsigned)f2bu(a);
}

// BUILTIN MFMA (R11 lesson: asm-wrapped MFMA is invisible to the GCN hazard
// recognizer -> missing MFMA->VALU wait-states -> silent corruption).
__device__ __forceinline__ f32x4 mfma_bf16(u32x4 a, u32x4 b, f32x4 d) {
  return __builtin_amdgcn_mfma_f32_16x16x32_bf16(
      __builtin_bit_cast(bf16x8, a), __builtin_bit_cast(bf16x8, b), d, 0, 0, 0);
}

// ---------------------------------------------------------------------------
// Fused A+B v5 (= v4 + LDS aliasing for 3 blocks/CU):
//   union uA: phase0/1 xl (26.6 KB f32)  <->  main yTG(14.3)+wl(16.4)
//   kk = Wk@y + beta*We@(y@G) + bk + beta*be*gsum
// ---------------------------------------------------------------------------
__global__ __launch_bounds__(256, 3) void k_qke_mfma5(
    const float* __restrict__ x,
    const float* __restrict__ Wq, const float* __restrict__ bq,
    const float* __restrict__ Wk, const float* __restrict__ bk,
    const float* __restrict__ We, const float* __restrict__ be,
    const float* __restrict__ G,  const float* __restrict__ beta,
    const float* __restrict__ se_pe, const int* __restrict__ dis,
    bf16* __restrict__ qy, bf16* __restrict__ kkp)
{
  const int n = blockIdx.x / 30, t0 = (blockIdx.x % 30) * 4;
  __shared__ alignas(16) char uA[30720];                 // xl | yTG+wl
  __shared__ alignas(16) unsigned short yT[112][64];     // 14,336 [tv][c] swz
  __shared__ alignas(16) float spl[5][64];
  __shared__ alignas(16) int   dml[25][25];
  __shared__ alignas(16) float Gl[25][26];
  __shared__ alignas(16) float gsum[32];
  __shared__ alignas(16) float biasb[384];               // bq|bk|be

  float* xl  = (float*)uA;                               // [4][64][26] f32
  char*  yTG = uA;                                       // [112] rows x 128B swz
  char*  wlb = uA + 14336;                               // [128] rows x 128B swz
  #define XL(t, c, v) xl[(((t) * 64 + (c)) * 26) + (v)]

  const int tid = threadIdx.x;
  // ---- phase 0: stage (xl + tables; NO writes to yTG/wl region beyond xl) --
  {
    const float* xb = x + (size_t)n * 192000 + t0 * 25;  // x[n][c][t0+t][v]
    for (int i = tid; i < 6400; i += 256) {
      const int c = i / 100, j = i % 100, t = j / 25, v = j % 25;
      XL(t, c, v) = xb[c * 3000 + j];
    }
  }
  for (int i = tid; i < 320; i += 256) spl[i / 64][i % 64] = se_pe[i];
  for (int i = tid; i < 625; i += 256) dml[i / 25][i % 25] = dis[i];
  for (int i = tid; i < 625; i += 256) Gl[i / 25][i % 25] = G[i];
  if (tid < 25) {
    float s = 0.f;
    for (int u = 0; u < 25; ++u) s += G[u * 25 + tid];
    gsum[tid] = s;
  }
  for (int i = tid; i < 384; i += 256)
    biasb[i] = (i < 128) ? bq[i] : (i < 256 ? bk[i - 128] : be[i - 256]);
  for (int i = tid; i < 12 * 64; i += 256)               // yT junk rows -> 0
    yT[100 + (i >> 6)][i & 63] = 0;
  __syncthreads();

  const int lane = tid & 63, wid = tid >> 6;
  const int m16 = lane & 15, kg = lane >> 4;
  const int wd_d = tid >> 1, wd_c0 = (tid & 1) * 32;

  #define STAGE_WS(Wsrc, SC)                                                   \
    {                                                                          \
      const float* wsrc = (Wsrc) + wd_d * 64 + wd_c0;                          \
      const float sc_ = (SC);                                                  \
      _Pragma("unroll")                                                        \
      for (int q2 = 0; q2 < 4; ++q2) {                                         \
        const float4 p0 = *(const float4*)(wsrc + q2 * 8);                     \
        const float4 p1 = *(const float4*)(wsrc + q2 * 8 + 4);                 \
        u32x4 wv;                                                              \
        wv[0] = pack2(p0.x * sc_, p0.y * sc_);                                 \
        wv[1] = pack2(p0.z * sc_, p0.w * sc_);                                 \
        wv[2] = pack2(p1.x * sc_, p1.y * sc_);                                 \
        wv[3] = pack2(p1.z * sc_, p1.w * sc_);                                 \
        char* p = wlb + wd_d * 128 +                                           \
                  ((wd_c0 * 2 + q2 * 16) ^ ((wd_d & 7) << 4));                 \
        *(u32x4*)p = wv;                                                       \
      }                                                                        \
    }

  #define LOAD_AFRAGS(af)                                                      \
    _Pragma("unroll")                                                          \
    for (int mt = 0; mt < 2; ++mt) {                                           \
      _Pragma("unroll")                                                        \
      for (int ks = 0; ks < 2; ++ks) {                                         \
        const int d_ = wid * 32 + mt * 16 + m16;                               \
        af[mt][ks] = *(const u32x4*)(wlb + d_ * 128 +                          \
                      (((ks * 32 + kg * 8) * 2) ^ ((d_ & 7) << 4)));           \
      }                                                                        \
    }

  // ---- phase 1: yT = x + pe + struct-enc (reads xl; writes yT only) ----
  for (int idx = tid; idx < 6400; idx += 256) {
    const int c = idx & 63, tv = idx >> 6;
    const int t = tv / 25, v = tv % 25;
    const float dv = expf(-(float)(c & ~1) * (logf(10000.0f) / 64.0f));
    float acc = XL(t, c, v) +
                ((c & 1) ? cosf((float)v * dv) : sinf((float)v * dv));
    #pragma unroll
    for (int u = 0; u < 25; ++u)
      acc = fmaf(XL(t, c, u), spl[dml[u][v]][c], acc);
    *(unsigned short*)((char*)yT + tv * 128 + ((c * 2) ^ ((tv & 7) << 4))) =
        f2bu(acc);
  }
  __syncthreads();   // yT ready; xl DEAD from here (uA becomes yTG+wl)

  // ---- phase 1b: yTG = y @ G (reads yT, writes yTG; zero junk rows too) ----
  for (int i = tid; i < 12 * 64; i += 256)
    *(unsigned short*)(yTG + (100 + (i >> 6)) * 128 + ((i & 63) * 2)) = 0;
  for (int idx = tid; idx < 6400; idx += 256) {
    const int c = idx & 63, tv = idx >> 6;
    const int t = tv / 25, v = tv % 25;
    float acc = 0.f;
    #pragma unroll
    for (int u = 0; u < 25; ++u) {
      const int ru = t * 25 + u;
      const float yv = bfu(*(const unsigned short*)((const char*)yT + ru * 128 +
                            ((c * 2) ^ ((ru & 7) << 4))));
      acc = fmaf(yv, Gl[u][v], acc);
    }
    *(unsigned short*)(yTG + tv * 128 + ((c * 2) ^ ((tv & 7) << 4))) =
        f2bu(acc);
  }
  __syncthreads();   // yTG ready

  bf16* qyb = qy  + (size_t)n * 384000 + t0 * 25;
  bf16* kkb = kkp + (size_t)n * 384000 + t0 * 25;
  const float betav = beta[0];

  // ---- stage Wq -> bar -> q-GEMM ----
  STAGE_WS(Wq, 1.0f);
  __syncthreads();
  {
    u32x4 aq[2][2];
    LOAD_AFRAGS(aq);
    for (int nt = 0; nt < 7; ++nt) {
      const int tv = nt * 16 + m16;
      const u32x4 b0 = *(const u32x4*)((const char*)yT + tv * 128 +
                        (((kg * 8) * 2) ^ ((tv & 7) << 4)));
      const u32x4 b1 = *(const u32x4*)((const char*)yT + tv * 128 +
                        (((32 + kg * 8) * 2) ^ ((tv & 7) << 4)));
      #pragma unroll
      for (int mt = 0; mt < 2; ++mt) {
        f32x4 acc = (f32x4)0.f;
        acc = mfma_bf16(aq[mt][0], b0, acc);
        acc = mfma_bf16(aq[mt][1], b1, acc);
        if (tv < 100) {
          const int dr = wid * 32 + mt * 16 + kg * 4;
          #pragma unroll
          for (int i2 = 0; i2 < 4; ++i2)
            qyb[(size_t)(dr + i2) * 3000 + tv] = f2b(acc[i2] + biasb[dr + i2]);
        }
      }
    }
  }
  __syncthreads();   // wl(Wq) reads drained

  // ---- stage Wk -> bar -> k-GEMM into persistent kacc ----
  f32x4 kacc[2][7];
  #pragma unroll
  for (int mt = 0; mt < 2; ++mt)
    #pragma unroll
    for (int nt = 0; nt < 7; ++nt) kacc[mt][nt] = (f32x4)0.f;

  STAGE_WS(Wk, 1.0f);
  __syncthreads();
  {
    u32x4 ak[2][2];
    LOAD_AFRAGS(ak);
    for (int nt = 0; nt < 7; ++nt) {
      const int tv = nt * 16 + m16;
      const u32x4 b0 = *(const u32x4*)((const char*)yT + tv * 128 +
                        (((kg * 8) * 2) ^ ((tv & 7) << 4)));
      const u32x4 b1 = *(const u32x4*)((const char*)yT + tv * 128 +
                        (((32 + kg * 8) * 2) ^ ((tv & 7) << 4)));
      #pragma unroll
      for (int mt = 0; mt < 2; ++mt) {
        kacc[mt][nt] = mfma_bf16(ak[mt][0], b0, kacc[mt][nt]);
        kacc[mt][nt] = mfma_bf16(ak[mt][1], b1, kacc[mt][nt]);
      }
    }
  }
  __syncthreads();   // wl(Wk) reads drained

  // ---- stage beta*We -> bar -> e-GEMM on yTG, accumulate, store kk ----
  STAGE_WS(We, betav);
  __syncthreads();
  {
    u32x4 ae[2][2];
    LOAD_AFRAGS(ae);
    for (int nt = 0; nt < 7; ++nt) {
      const int tv = nt * 16 + m16;
      const u32x4 b0 = *(const u32x4*)(yTG + tv * 128 +
                        (((kg * 8) * 2) ^ ((tv & 7) << 4)));
      const u32x4 b1 = *(const u32x4*)(yTG + tv * 128 +
                        (((32 + kg * 8) * 2) ^ ((tv & 7) << 4)));
      #pragma unroll
      for (int mt = 0; mt < 2; ++mt) {
        kacc[mt][nt] = mfma_bf16(ae[mt][0], b0, kacc[mt][nt]);
        kacc[mt][nt] = mfma_bf16(ae[mt][1], b1, kacc[mt][nt]);
        if (tv < 100) {
          const int vv = tv % 25;
          const int dr = wid * 32 + mt * 16 + kg * 4;
          #pragma unroll
          for (int i2 = 0; i2 < 4; ++i2)
            kkb[(size_t)(dr + i2) * 3000 + tv] =
                f2b(kacc[mt][nt][i2] + biasb[128 + dr + i2] +
                    betav * biasb[256 + dr + i2] * gsum[vv]);
        }
      }
    }
  }
  #undef STAGE_WS
  #undef LOAD_AFRAGS
  #undef XL
}

// ---------------------------------------------------------------------------
// Kernel C (R8-verbatim): attT[n,h,v,u]
// ---------------------------------------------------------------------------
__global__ __launch_bounds__(256) void k_att(
    const bf16* __restrict__ qy, const bf16* __restrict__ kkp,
    const float* __restrict__ bq, const float* __restrict__ disg,
    const float* __restrict__ att0, const float* __restrict__ alpha,
    bf16* __restrict__ attT)
{
  const int n = blockIdx.x / HH, h = blockIdx.x % HH;
  __shared__ float qs[DHD][TC + 2][VV];
  __shared__ float ks[DHD][TC][VV];
  __shared__ float mxv[VV], smv[VV];
  const int tid = threadIdx.x;
  const int v = tid % VV;
  const int g = tid / VV;
  const bool act = (g < 10);
  int u_[8], w_[8], up_[8];
  #pragma unroll
  for (int j = 0; j < 8; ++j) {
    int u = g + 10 * j;
    u_[j] = u;
    if (u >= UU) u = 0;
    w_[j] = u / VV; up_[j] = u % VV;
  }
  float acc[8] = {0.f, 0.f, 0.f, 0.f, 0.f, 0.f, 0.f, 0.f};

  for (int t0 = 0; t0 < TT; t0 += TC) {
    __syncthreads();
    for (int i = tid; i < DHD * (TC + 2) * VV; i += 256) {
      const int dh = i / ((TC + 2) * VV);
      const int r  = i % ((TC + 2) * VV);
      const int tt = r / VV, vv = r % VV;
      const int tq = t0 + tt - 1;
      const int dd = h * DHD + dh;
      qs[dh][tt][vv] = (tq >= 0 && tq < TT)
          ? b2f(qy[((size_t)(n * DIMD + dd) * TT + tq) * VV + vv]) : bq[dd];
    }
    for (int i = tid; i < DHD * TC * VV; i += 256) {
      const int dh = i / (TC * VV);
      const int r  = i % (TC * VV);
      const int tt = r / VV, vv = r % VV;
      ks[dh][tt][vv] =
          b2f(kkp[((size_t)(n * DIMD + h * DHD + dh) * TT + t0 + tt) * VV + vv]);
    }
    __syncthreads();
    if (act) {
      for (int dh = 0; dh < DHD; ++dh) {
        #pragma unroll 4
        for (int tt = 0; tt < TC; ++tt) {
          const float kv = ks[dh][tt][v];
          #pragma unroll
          for (int j = 0; j < 8; ++j)
            acc[j] = fmaf(qs[dh][tt + w_[j]][up_[j]], kv, acc[j]);
        }
      }
    }
  }
  __syncthreads();
  float* att_s = &qs[0][0][0];
  const float inv = 1.0f / (float)(DHD * TT);
  if (act) {
    #pragma unroll
    for (int j = 0; j < 8; ++j) {
      if (u_[j] < UU) {
        const bool m = disg[(h * VV + up_[j]) * VV + v] > 0.f;
        att_s[u_[j] * VV + v] = m ? acc[j] * inv : -9e15f;
      }
    }
  }
  __syncthreads();
  if (tid < VV) {
    float mx = -INFINITY;
    for (int u = 0; u < UU; ++u) mx = fmaxf(mx, att_s[u * VV + tid]);
    float sm = 0.f;
    for (int u = 0; u < UU; ++u) sm += expf(att_s[u * VV + tid] - mx);
    mxv[tid] = mx; smv[tid] = sm;
  }
  __syncthreads();
  const float al = alpha[0];
  for (int i = tid; i < UU * VV; i += 256) {
    const int u = i % UU, vc = i / UU;
    const float p = expf(att_s[u * VV + vc] - mxv[vc]) / smv[vc];
    const float o = p * al + att0[(h * VV + u % VV) * VV + vc];
    attT[((size_t)(n * HH + h) * VV + vc) * UU + u] = f2b(o);
  }
}

// ---------------------------------------------------------------------------
// Kernel D v3 (= v2 + LDS aliasing for 3 blocks/CU):
//   union uB: prologue xu2 (26.6 KB)  <->  main xsl(14.3)+wol(16.4)
//   Explicit fence barrier after last xu2 read; xsl junk-zero after fence.
// ---------------------------------------------------------------------------
__global__ __launch_bounds__(256) void k_out_mfma3(
    const float* __restrict__ x, const bf16* __restrict__ attT,
    const float* __restrict__ Wo, const float* __restrict__ b_o,
    const float* __restrict__ g_o, const float* __restrict__ be_o,
    const float* __restrict__ m_o, const float* __restrict__ v_o,
    const float* __restrict__ Wd, const float* __restrict__ b_d,
    const float* __restrict__ g_d, const float* __restrict__ be_d,
    const float* __restrict__ m_d, const float* __restrict__ v_d,
    float* __restrict__ out)
{
  const int n = blockIdx.x / 30, t0 = (blockIdx.x % 30) * TCO;
  __shared__ alignas(16) char uB[30720];                   // xu2 | xsl+wol
  __shared__ alignas(16) unsigned short attB[2][32][104];  // 13,312 B dbuf
  unsigned short* xu2 = (unsigned short*)uB;               // [(tr*64+c)*104+u]
  char* xslb = uB;                                         // [112] x 128B swz
  char* wolb = uB + 14336;                                 // [128] x 128B swz
  const int tid = threadIdx.x;
  const int lane = tid & 63, wid = tid >> 6;
  const int m16 = lane & 15, kg = lane >> 4;

  #define STAGE_XU(tb)                                                         \
    for (int i = tid; i < 2 * 64 * 48; i += 256) {                             \
      const int u0 = (i % 48) * 2, c = (i / 48) & 63, tr = i / (48 * 64);      \
      float f0 = 0.f, f1 = 0.f;                                                \
      if (u0 < UU) {                                                           \
        const int w = u0 / VV, up = u0 % VV, ts = t0 + (tb) + tr + w - 1;      \
        if (ts >= 0 && ts < TT) f0 = x[((n * 64 + c) * TT + ts) * VV + up];    \
      }                                                                        \
      if (u0 + 1 < UU) {                                                       \
        const int u = u0 + 1, w = u / VV, up = u % VV;                         \
        const int ts = t0 + (tb) + tr + w - 1;                                 \
        if (ts >= 0 && ts < TT) f1 = x[((n * 64 + c) * TT + ts) * VV + up];    \
      }                                                                        \
      *(unsigned*)(xu2 + (tr * 64 + c) * 104 + u0) = pack2(f0, f1);            \
    }

  #define STAGE_ATT(hh, buf)                                                   \
    for (int i = tid; i < 32 * 48; i += 256) {                                 \
      const int u0 = (i % 48) * 2, v = i / 48;                                 \
      float f0 = 0.f, f1 = 0.f;                                                \
      if (v < VV) {                                                            \
        const bf16* src = attT + ((size_t)(n * HH + (hh)) * VV + v) * UU;      \
        if (u0 < UU) f0 = b2f(src[u0]);                                        \
        if (u0 + 1 < UU) f1 = b2f(src[u0 + 1]);                                \
      }                                                                        \
      *(unsigned*)&attB[buf][v][u0] = pack2(f0, f1);                           \
    }

  // ---- prologue: A-frags from xu2 in two 2-t chunks ----
  STAGE_XU(0);
  __syncthreads();
  u32x4 af[4][3];
  if (wid < 2) {
    #pragma unroll
    for (int mt = 0; mt < 4; ++mt)
      #pragma unroll
      for (int ks = 0; ks < 3; ++ks)
        af[mt][ks] = *(const u32x4*)(xu2 + (wid * 64 + mt * 16 + m16) * 104 +
                                     ks * 32 + kg * 8);
  }
  __syncthreads();   // chunk-1 reads drained before overwrite
  STAGE_XU(2);
  STAGE_ATT(0, 0);
  __syncthreads();
  if (wid >= 2) {
    #pragma unroll
    for (int mt = 0; mt < 4; ++mt)
      #pragma unroll
      for (int ks = 0; ks < 3; ++ks)
        af[mt][ks] = *(const u32x4*)(xu2 + ((wid - 2) * 64 + mt * 16 + m16) * 104 +
                                     ks * 32 + kg * 8);
  }
  __syncthreads();   // FENCE: all xu2 reads drained; uB becomes xsl+wol
  // xsl junk rows (tv 100..111) -> 0 (first write into aliased region)
  for (int i = tid; i < 12 * 64; i += 256)
    *(unsigned short*)(xslb + (100 + (i >> 6)) * 128 + ((i & 63) * 2)) = 0;

  const int wd_d = tid >> 1, wd_c0 = (tid & 1) * 32;
  const float so_ = g_o[wd_d] * rsqrtf(v_o[wd_d] + 1e-5f);
  const float sd_ = g_d[wd_d] * rsqrtf(v_d[wd_d] + 1e-5f);

  f32x4 acc2[2][7];
  #pragma unroll
  for (int mt = 0; mt < 2; ++mt)
    #pragma unroll
    for (int nt = 0; nt < 7; ++nt) acc2[mt][nt] = (f32x4)0.f;

  for (int h = 0; h <= HH; ++h) {
    float4 wb[8];
    {
      const float* wsrc = (h < HH) ? (Wo + wd_d * 512 + h * 64 + wd_c0)
                                   : (Wd + wd_d * 64 + wd_c0);
      #pragma unroll
      for (int q = 0; q < 8; ++q) wb[q] = ((const float4*)wsrc)[q];
    }
    if (h + 1 < HH) { STAGE_ATT(h + 1, (h + 1) & 1); }
    f32x4 a1[4][2];
    if (h < HH) {
      u32x4 bfr[2][3];
      #pragma unroll
      for (int nt = 0; nt < 2; ++nt)
        #pragma unroll
        for (int ks = 0; ks < 3; ++ks)
          bfr[nt][ks] =
              *(const u32x4*)&attB[h & 1][nt * 16 + m16][ks * 32 + kg * 8];
      #pragma unroll
      for (int mt = 0; mt < 4; ++mt)
        #pragma unroll
        for (int nt = 0; nt < 2; ++nt) {
          a1[mt][nt] = (f32x4)0.f;
          #pragma unroll
          for (int ks = 0; ks < 3; ++ks)
            a1[mt][nt] = mfma_bf16(af[mt][ks], bfr[nt][ks], a1[mt][nt]);
        }
    }
    __syncthreads();
    if (h < HH) {
      #pragma unroll
      for (int mt = 0; mt < 4; ++mt)
        #pragma unroll
        for (int nt = 0; nt < 2; ++nt) {
          const int v = nt * 16 + m16;
          if (v < VV) {
            const int tv = wid * VV + v;
            const int c0 = mt * 16 + kg * 4;
            u32x2 pk;
            pk[0] = pack2(a1[mt][nt][0], a1[mt][nt][1]);
            pk[1] = pack2(a1[mt][nt][2], a1[mt][nt][3]);
            char* p = xslb + tv * 128 + ((c0 * 2) ^ ((tv & 7) << 4));
            *(u32x2*)p = pk;
          }
        }
    } else {
      for (int i = tid; i < 6400; i += 256) {
        const int c = i / 100, j = i % 100;
        const float f = x[((size_t)(n * 64 + c) * TT + t0) * VV + j];
        *(unsigned short*)(xslb + j * 128 + ((c * 2) ^ ((j & 7) << 4))) =
            f2bu(f);
      }
    }
    {
      const float sc = (h < HH) ? so_ : sd_;
      #pragma unroll
      for (int q = 0; q < 4; ++q) {
        const float4 p0 = wb[q * 2], p1 = wb[q * 2 + 1];
        u32x4 wv;
        wv[0] = pack2(p0.x * sc, p0.y * sc); wv[1] = pack2(p0.z * sc, p0.w * sc);
        wv[2] = pack2(p1.x * sc, p1.y * sc); wv[3] = pack2(p1.z * sc, p1.w * sc);
        char* p = wolb + wd_d * 128 + ((wd_c0 * 2 + q * 16) ^ ((wd_d & 7) << 4));
        *(u32x4*)p = wv;
      }
    }
    __syncthreads();
    u32x4 a2[2][2];
    #pragma unroll
    for (int mt = 0; mt < 2; ++mt)
      #pragma unroll
      for (int ks = 0; ks < 2; ++ks) {
        const int d = wid * 32 + mt * 16 + m16;
        a2[mt][ks] = *(const u32x4*)(wolb + d * 128 +
                      (((ks * 32 + kg * 8) * 2) ^ ((d & 7) << 4)));
      }
    #pragma unroll
    for (int nt = 0; nt < 7; ++nt) {
      const int tv = nt * 16 + m16;
      const u32x4 b0 = *(const u32x4*)(xslb + tv * 128 +
                        (((kg * 8) * 2) ^ ((tv & 7) << 4)));
      const u32x4 b1 = *(const u32x4*)(xslb + tv * 128 +
                        (((32 + kg * 8) * 2) ^ ((tv & 7) << 4)));
      #pragma unroll
      for (int mt = 0; mt < 2; ++mt) {
        acc2[mt][nt] = mfma_bf16(a2[mt][0], b0, acc2[mt][nt]);
        acc2[mt][nt] = mfma_bf16(a2[mt][1], b1, acc2[mt][nt]);
      }
    }
  }

  #pragma unroll
  for (int mt = 0; mt < 2; ++mt) {
    float cc[4];
    #pragma unroll
    for (int i = 0; i < 4; ++i) {
      const int d = wid * 32 + mt * 16 + kg * 4 + i;
      const float so2 = g_o[d] * rsqrtf(v_o[d] + 1e-5f);
      const float sd2 = g_d[d] * rsqrtf(v_d[d] + 1e-5f);
      cc[i] = b_o[d] * so2 + be_o[d] - m_o[d] * so2
            + b_d[d] * sd2 + be_d[d] - m_d[d] * sd2;
    }
    #pragma unroll
    for (int nt = 0; nt < 7; ++nt) {
      const int tv = nt * 16 + m16;
      if (tv < 100) {
        const int t = t0 + tv / VV, v = tv % VV;
        #pragma unroll
        for (int i = 0; i < 4; ++i) {
          const int d = wid * 32 + mt * 16 + kg * 4 + i;
          const float z = acc2[mt][nt][i] + cc[i];
          out[((n * DIMD + d) * TT + t) * VV + v] = (z >= 0.f) ? z : 0.1f * z;
        }
      }
    }
  }
  #undef STAGE_XU
  #undef STAGE_ATT
}

// ---------------------------------------------------------------------------
extern "C" void kernel_launch(void* const* d_in, const int* in_sizes, int n_in,
                              void* d_out, int out_size, void* d_ws, size_t ws_size,
                              hipStream_t stream)
{
  (void)in_sizes; (void)n_in; (void)out_size; (void)ws_size;
  const float* x     = (const float*)d_in[0];
  const float* Wq    = (const float*)d_in[1];
  const float* bq    = (const float*)d_in[2];
  const float* Wk    = (const float*)d_in[3];
  const float* bk    = (const float*)d_in[4];
  const float* We    = (const float*)d_in[5];
  const float* be    = (const float*)d_in[6];
  const float* G     = (const float*)d_in[7];
  const float* sepe  = (const float*)d_in[8];
  const float* att0  = (const float*)d_in[9];
  const float* alpha = (const float*)d_in[10];
  const float* beta  = (const float*)d_in[11];
  const float* Wo    = (const float*)d_in[12];
  const float* b_o   = (const float*)d_in[13];
  const float* g_o   = (const float*)d_in[14];
  const float* be_o  = (const float*)d_in[15];
  const float* m_o   = (const float*)d_in[16];
  const float* v_o   = (const float*)d_in[17];
  const float* Wd    = (const float*)d_in[18];
  const float* b_d   = (const float*)d_in[19];
  const float* g_d   = (const float*)d_in[20];
  const float* be_d  = (const float*)d_in[21];
  const float* m_d   = (const float*)d_in[22];
  const float* v_d   = (const float*)d_in[23];
  const int*   dism  = (const int*)d_in[24];
  const float* disg  = (const float*)d_in[25];

  // Workspace (bf16): qy @0, kk @49,152,000, attT @98,304,000
  char* ws = (char*)d_ws;
  bf16* qy   = (bf16*)(ws);
  bf16* kkp  = (bf16*)(ws + 49152000);
  bf16* attT = (bf16*)(ws + 98304000);

  k_qke_mfma5<<<NB * 30, 256, 0, stream>>>(x, Wq, bq, Wk, bk, We, be, G, beta,
                                           sepe, dism, qy, kkp);
  k_att<<<NB * HH, 256, 0, stream>>>(qy, kkp, bq, disg, att0, alpha, attT);
  k_out_mfma3<<<NB * 30, 256, 0, stream>>>(x, attT, Wo, b_o, g_o, be_o, m_o, v_o,
                                           Wd, b_d, g_d, be_d, m_d, v_d, (float*)d_out);
}

// Round 13
// 664.185 us; speedup vs baseline: 10.4146x; 1.0810x over previous
//
#include <hip/hip_runtime.h>
#include <hip/hip_bf16.h>
#include <math.h>

// Problem constants (fixed by the reference)
#define NB   64     // batch
#define CIN  64     // input channels
#define DIMD 128    // q/k/e channels
#define TT   120    // time
#define VV   25     // joints
#define HH   8      // heads
#define DHD  16     // DIM/H
#define WW   3      // temporal window
#define UU   75     // W*V
#define TC   24     // t-chunk in attention kernel (120 = 5*24)
#define TCO  4      // t-chunk in output kernel (120 = 4*30)

typedef __hip_bfloat16 bf16;
typedef float        f32x4  __attribute__((ext_vector_type(4)));
typedef unsigned int u32x4  __attribute__((ext_vector_type(4)));
typedef unsigned int u32x2  __attribute__((ext_vector_type(2)));
typedef __bf16       bf16x8 __attribute__((ext_vector_type(8)));

__device__ __forceinline__ float b2f(bf16 v)  { return __bfloat162float(v); }
__device__ __forceinline__ bf16  f2b(float v) { return __float2bfloat16(v); }

__device__ __forceinline__ unsigned short f2bu(float f) {
  unsigned u = __builtin_bit_cast(unsigned, f);
  return (unsigned short)((u + 0x7fffu + ((u >> 16) & 1u)) >> 16);  // RNE
}
__device__ __forceinline__ float bfu(unsigned short s) {
  unsigned u = ((unsigned)s) << 16;
  return __builtin_bit_cast(float, u);
}
__device__ __forceinline__ unsigned pack2(float a, float b) {
  return ((unsigned)f2bu(b) << 16) | (unsigned)f2bu(a);
}

// BUILTIN MFMA (R11 lesson: asm-wrapped MFMA is invisible to the GCN hazard
// recognizer -> missing MFMA->VALU wait-states -> silent corruption).
__device__ __forceinline__ f32x4 mfma_bf16(u32x4 a, u32x4 b, f32x4 d) {
  return __builtin_amdgcn_mfma_f32_16x16x32_bf16(
      __builtin_bit_cast(bf16x8, a), __builtin_bit_cast(bf16x8, b), d, 0, 0, 0);
}

// ---------------------------------------------------------------------------
// Fused A+B v5 (R12-verbatim, passing): kk = Wk@y + beta*We@(y@G) + bias;
// xl aliased with yTG+wl for 3 blocks/CU.
// ---------------------------------------------------------------------------
__global__ __launch_bounds__(256, 3) void k_qke_mfma5(
    const float* __restrict__ x,
    const float* __restrict__ Wq, const float* __restrict__ bq,
    const float* __restrict__ Wk, const float* __restrict__ bk,
    const float* __restrict__ We, const float* __restrict__ be,
    const float* __restrict__ G,  const float* __restrict__ beta,
    const float* __restrict__ se_pe, const int* __restrict__ dis,
    bf16* __restrict__ qy, bf16* __restrict__ kkp)
{
  const int n = blockIdx.x / 30, t0 = (blockIdx.x % 30) * 4;
  __shared__ alignas(16) char uA[30720];                 // xl | yTG+wl
  __shared__ alignas(16) unsigned short yT[112][64];     // [tv][c] swz
  __shared__ alignas(16) float spl[5][64];
  __shared__ alignas(16) int   dml[25][25];
  __shared__ alignas(16) float Gl[25][26];
  __shared__ alignas(16) float gsum[32];
  __shared__ alignas(16) float biasb[384];               // bq|bk|be

  float* xl  = (float*)uA;                               // [4][64][26] f32
  char*  yTG = uA;                                       // [112] x 128B swz
  char*  wlb = uA + 14336;                               // [128] x 128B swz
  #define XL(t, c, v) xl[(((t) * 64 + (c)) * 26) + (v)]

  const int tid = threadIdx.x;
  {
    const float* xb = x + (size_t)n * 192000 + t0 * 25;  // x[n][c][t0+t][v]
    for (int i = tid; i < 6400; i += 256) {
      const int c = i / 100, j = i % 100, t = j / 25, v = j % 25;
      XL(t, c, v) = xb[c * 3000 + j];
    }
  }
  for (int i = tid; i < 320; i += 256) spl[i / 64][i % 64] = se_pe[i];
  for (int i = tid; i < 625; i += 256) dml[i / 25][i % 25] = dis[i];
  for (int i = tid; i < 625; i += 256) Gl[i / 25][i % 25] = G[i];
  if (tid < 25) {
    float s = 0.f;
    for (int u = 0; u < 25; ++u) s += G[u * 25 + tid];
    gsum[tid] = s;
  }
  for (int i = tid; i < 384; i += 256)
    biasb[i] = (i < 128) ? bq[i] : (i < 256 ? bk[i - 128] : be[i - 256]);
  for (int i = tid; i < 12 * 64; i += 256)               // yT junk rows -> 0
    yT[100 + (i >> 6)][i & 63] = 0;
  __syncthreads();

  const int lane = tid & 63, wid = tid >> 6;
  const int m16 = lane & 15, kg = lane >> 4;
  const int wd_d = tid >> 1, wd_c0 = (tid & 1) * 32;

  #define STAGE_WS(Wsrc, SC)                                                   \
    {                                                                          \
      const float* wsrc = (Wsrc) + wd_d * 64 + wd_c0;                          \
      const float sc_ = (SC);                                                  \
      _Pragma("unroll")                                                        \
      for (int q2 = 0; q2 < 4; ++q2) {                                         \
        const float4 p0 = *(const float4*)(wsrc + q2 * 8);                     \
        const float4 p1 = *(const float4*)(wsrc + q2 * 8 + 4);                 \
        u32x4 wv;                                                              \
        wv[0] = pack2(p0.x * sc_, p0.y * sc_);                                 \
        wv[1] = pack2(p0.z * sc_, p0.w * sc_);                                 \
        wv[2] = pack2(p1.x * sc_, p1.y * sc_);                                 \
        wv[3] = pack2(p1.z * sc_, p1.w * sc_);                                 \
        char* p = wlb + wd_d * 128 +                                           \
                  ((wd_c0 * 2 + q2 * 16) ^ ((wd_d & 7) << 4));                 \
        *(u32x4*)p = wv;                                                       \
      }                                                                        \
    }

  #define LOAD_AFRAGS(af)                                                      \
    _Pragma("unroll")                                                          \
    for (int mt = 0; mt < 2; ++mt) {                                           \
      _Pragma("unroll")                                                        \
      for (int ks = 0; ks < 2; ++ks) {                                         \
        const int d_ = wid * 32 + mt * 16 + m16;                               \
        af[mt][ks] = *(const u32x4*)(wlb + d_ * 128 +                          \
                      (((ks * 32 + kg * 8) * 2) ^ ((d_ & 7) << 4)));           \
      }                                                                        \
    }

  // ---- phase 1: yT = x + pe + struct-enc ----
  for (int idx = tid; idx < 6400; idx += 256) {
    const int c = idx & 63, tv = idx >> 6;
    const int t = tv / 25, v = tv % 25;
    const float dv = expf(-(float)(c & ~1) * (logf(10000.0f) / 64.0f));
    float acc = XL(t, c, v) +
                ((c & 1) ? cosf((float)v * dv) : sinf((float)v * dv));
    #pragma unroll
    for (int u = 0; u < 25; ++u)
      acc = fmaf(XL(t, c, u), spl[dml[u][v]][c], acc);
    *(unsigned short*)((char*)yT + tv * 128 + ((c * 2) ^ ((tv & 7) << 4))) =
        f2bu(acc);
  }
  __syncthreads();   // yT ready; xl DEAD (uA becomes yTG+wl)

  // ---- phase 1b: yTG = y @ G ----
  for (int i = tid; i < 12 * 64; i += 256)
    *(unsigned short*)(yTG + (100 + (i >> 6)) * 128 + ((i & 63) * 2)) = 0;
  for (int idx = tid; idx < 6400; idx += 256) {
    const int c = idx & 63, tv = idx >> 6;
    const int t = tv / 25, v = tv % 25;
    float acc = 0.f;
    #pragma unroll
    for (int u = 0; u < 25; ++u) {
      const int ru = t * 25 + u;
      const float yv = bfu(*(const unsigned short*)((const char*)yT + ru * 128 +
                            ((c * 2) ^ ((ru & 7) << 4))));
      acc = fmaf(yv, Gl[u][v], acc);
    }
    *(unsigned short*)(yTG + tv * 128 + ((c * 2) ^ ((tv & 7) << 4))) =
        f2bu(acc);
  }
  __syncthreads();   // yTG ready

  bf16* qyb = qy  + (size_t)n * 384000 + t0 * 25;
  bf16* kkb = kkp + (size_t)n * 384000 + t0 * 25;
  const float betav = beta[0];

  // ---- stage Wq -> bar -> q-GEMM ----
  STAGE_WS(Wq, 1.0f);
  __syncthreads();
  {
    u32x4 aq[2][2];
    LOAD_AFRAGS(aq);
    for (int nt = 0; nt < 7; ++nt) {
      const int tv = nt * 16 + m16;
      const u32x4 b0 = *(const u32x4*)((const char*)yT + tv * 128 +
                        (((kg * 8) * 2) ^ ((tv & 7) << 4)));
      const u32x4 b1 = *(const u32x4*)((const char*)yT + tv * 128 +
                        (((32 + kg * 8) * 2) ^ ((tv & 7) << 4)));
      #pragma unroll
      for (int mt = 0; mt < 2; ++mt) {
        f32x4 acc = (f32x4)0.f;
        acc = mfma_bf16(aq[mt][0], b0, acc);
        acc = mfma_bf16(aq[mt][1], b1, acc);
        if (tv < 100) {
          const int dr = wid * 32 + mt * 16 + kg * 4;
          #pragma unroll
          for (int i2 = 0; i2 < 4; ++i2)
            qyb[(size_t)(dr + i2) * 3000 + tv] = f2b(acc[i2] + biasb[dr + i2]);
        }
      }
    }
  }
  __syncthreads();

  // ---- stage Wk -> bar -> k-GEMM into persistent kacc ----
  f32x4 kacc[2][7];
  #pragma unroll
  for (int mt = 0; mt < 2; ++mt)
    #pragma unroll
    for (int nt = 0; nt < 7; ++nt) kacc[mt][nt] = (f32x4)0.f;

  STAGE_WS(Wk, 1.0f);
  __syncthreads();
  {
    u32x4 ak[2][2];
    LOAD_AFRAGS(ak);
    for (int nt = 0; nt < 7; ++nt) {
      const int tv = nt * 16 + m16;
      const u32x4 b0 = *(const u32x4*)((const char*)yT + tv * 128 +
                        (((kg * 8) * 2) ^ ((tv & 7) << 4)));
      const u32x4 b1 = *(const u32x4*)((const char*)yT + tv * 128 +
                        (((32 + kg * 8) * 2) ^ ((tv & 7) << 4)));
      #pragma unroll
      for (int mt = 0; mt < 2; ++mt) {
        kacc[mt][nt] = mfma_bf16(ak[mt][0], b0, kacc[mt][nt]);
        kacc[mt][nt] = mfma_bf16(ak[mt][1], b1, kacc[mt][nt]);
      }
    }
  }
  __syncthreads();

  // ---- stage beta*We -> bar -> e-GEMM on yTG, accumulate, store kk ----
  STAGE_WS(We, betav);
  __syncthreads();
  {
    u32x4 ae[2][2];
    LOAD_AFRAGS(ae);
    for (int nt = 0; nt < 7; ++nt) {
      const int tv = nt * 16 + m16;
      const u32x4 b0 = *(const u32x4*)(yTG + tv * 128 +
                        (((kg * 8) * 2) ^ ((tv & 7) << 4)));
      const u32x4 b1 = *(const u32x4*)(yTG + tv * 128 +
                        (((32 + kg * 8) * 2) ^ ((tv & 7) << 4)));
      #pragma unroll
      for (int mt = 0; mt < 2; ++mt) {
        kacc[mt][nt] = mfma_bf16(ae[mt][0], b0, kacc[mt][nt]);
        kacc[mt][nt] = mfma_bf16(ae[mt][1], b1, kacc[mt][nt]);
        if (tv < 100) {
          const int vv = tv % 25;
          const int dr = wid * 32 + mt * 16 + kg * 4;
          #pragma unroll
          for (int i2 = 0; i2 < 4; ++i2)
            kkb[(size_t)(dr + i2) * 3000 + tv] =
                f2b(kacc[mt][nt][i2] + biasb[128 + dr + i2] +
                    betav * biasb[256 + dr + i2] * gsum[vv]);
        }
      }
    }
  }
  #undef STAGE_WS
  #undef LOAD_AFRAGS
  #undef XL
}

// ---------------------------------------------------------------------------
// Kernel C: same compute as R8; epilogue now writes PADDED attP[n][h][32][104]
// (zero pad) so k_out can stage it with raw u32x4 copies.
// ---------------------------------------------------------------------------
__global__ __launch_bounds__(256) void k_att(
    const bf16* __restrict__ qy, const bf16* __restrict__ kkp,
    const float* __restrict__ bq, const float* __restrict__ disg,
    const float* __restrict__ att0, const float* __restrict__ alpha,
    unsigned short* __restrict__ attP)
{
  const int n = blockIdx.x / HH, h = blockIdx.x % HH;
  __shared__ float qs[DHD][TC + 2][VV];
  __shared__ float ks[DHD][TC][VV];
  __shared__ float mxv[VV], smv[VV];
  const int tid = threadIdx.x;
  const int v = tid % VV;
  const int g = tid / VV;
  const bool act = (g < 10);
  int u_[8], w_[8], up_[8];
  #pragma unroll
  for (int j = 0; j < 8; ++j) {
    int u = g + 10 * j;
    u_[j] = u;
    if (u >= UU) u = 0;
    w_[j] = u / VV; up_[j] = u % VV;
  }
  float acc[8] = {0.f, 0.f, 0.f, 0.f, 0.f, 0.f, 0.f, 0.f};

  for (int t0 = 0; t0 < TT; t0 += TC) {
    __syncthreads();
    for (int i = tid; i < DHD * (TC + 2) * VV; i += 256) {
      const int dh = i / ((TC + 2) * VV);
      const int r  = i % ((TC + 2) * VV);
      const int tt = r / VV, vv = r % VV;
      const int tq = t0 + tt - 1;
      const int dd = h * DHD + dh;
      qs[dh][tt][vv] = (tq >= 0 && tq < TT)
          ? b2f(qy[((size_t)(n * DIMD + dd) * TT + tq) * VV + vv]) : bq[dd];
    }
    for (int i = tid; i < DHD * TC * VV; i += 256) {
      const int dh = i / (TC * VV);
      const int r  = i % (TC * VV);
      const int tt = r / VV, vv = r % VV;
      ks[dh][tt][vv] =
          b2f(kkp[((size_t)(n * DIMD + h * DHD + dh) * TT + t0 + tt) * VV + vv]);
    }
    __syncthreads();
    if (act) {
      for (int dh = 0; dh < DHD; ++dh) {
        #pragma unroll 4
        for (int tt = 0; tt < TC; ++tt) {
          const float kv = ks[dh][tt][v];
          #pragma unroll
          for (int j = 0; j < 8; ++j)
            acc[j] = fmaf(qs[dh][tt + w_[j]][up_[j]], kv, acc[j]);
        }
      }
    }
  }
  __syncthreads();
  float* att_s = &qs[0][0][0];
  const float inv = 1.0f / (float)(DHD * TT);
  if (act) {
    #pragma unroll
    for (int j = 0; j < 8; ++j) {
      if (u_[j] < UU) {
        const bool m = disg[(h * VV + up_[j]) * VV + v] > 0.f;
        att_s[u_[j] * VV + v] = m ? acc[j] * inv : -9e15f;
      }
    }
  }
  __syncthreads();
  if (tid < VV) {
    float mx = -INFINITY;
    for (int u = 0; u < UU; ++u) mx = fmaxf(mx, att_s[u * VV + tid]);
    float sm = 0.f;
    for (int u = 0; u < UU; ++u) sm += expf(att_s[u * VV + tid] - mx);
    mxv[tid] = mx; smv[tid] = sm;
  }
  __syncthreads();
  const float al = alpha[0];
  unsigned* dst = (unsigned*)(attP + ((size_t)(n * HH + h) * 32) * 104);
  for (int i = tid; i < 1664; i += 256) {     // 32 x 52 u32 (= 104 u16)
    const int vc = i / 52, u0 = (i % 52) * 2;
    unsigned val = 0u;
    if (vc < VV) {
      float f0 = 0.f, f1 = 0.f;
      if (u0 < UU)
        f0 = expf(att_s[u0 * VV + vc] - mxv[vc]) / smv[vc] * al
             + att0[(h * VV + u0 % VV) * VV + vc];
      if (u0 + 1 < UU)
        f1 = expf(att_s[(u0 + 1) * VV + vc] - mxv[vc]) / smv[vc] * al
             + att0[(h * VV + (u0 + 1) % VV) * VV + vc];
      val = pack2(f0, f1);
    }
    dst[i] = val;
  }
}

// ---------------------------------------------------------------------------
// Kernel D v4: double-buffered xsl/wol (1 barrier per h) + raw-copy att stage.
//   union uB: prologue xu2 (26.6 KB)  <->  main xsl2[2](28.7)+wol2[2](32.8)
//   attB[2] staged via u32x4 copies from padded attP.
// ---------------------------------------------------------------------------
__global__ __launch_bounds__(256) void k_out_mfma4(
    const float* __restrict__ x, const unsigned short* __restrict__ attP,
    const float* __restrict__ Wo, const float* __restrict__ b_o,
    const float* __restrict__ g_o, const float* __restrict__ be_o,
    const float* __restrict__ m_o, const float* __restrict__ v_o,
    const float* __restrict__ Wd, const float* __restrict__ b_d,
    const float* __restrict__ g_d, const float* __restrict__ be_d,
    const float* __restrict__ m_d, const float* __restrict__ v_d,
    float* __restrict__ out)
{
  const int n = blockIdx.x / 30, t0 = (blockIdx.x % 30) * TCO;
  __shared__ alignas(16) char uB[61440];                   // xu2 | xsl2+wol2
  __shared__ alignas(16) unsigned short attB[2][32][104];  // 13,312 B dbuf
  unsigned short* xu2 = (unsigned short*)uB;               // [(tr*64+c)*104+u]
  const int tid = threadIdx.x;
  const int lane = tid & 63, wid = tid >> 6;
  const int m16 = lane & 15, kg = lane >> 4;

  #define XSLB(b) (uB + (b) * 14336)            // [112] rows x 128B swz
  #define WOLB(b) (uB + 28672 + (b) * 16384)    // [128] rows x 128B swz

  #define STAGE_XU(tb)                                                         \
    for (int i = tid; i < 2 * 64 * 48; i += 256) {                             \
      const int u0 = (i % 48) * 2, c = (i / 48) & 63, tr = i / (48 * 64);      \
      float f0 = 0.f, f1 = 0.f;                                                \
      if (u0 < UU) {                                                           \
        const int w = u0 / VV, up = u0 % VV, ts = t0 + (tb) + tr + w - 1;      \
        if (ts >= 0 && ts < TT) f0 = x[((n * 64 + c) * TT + ts) * VV + up];    \
      }                                                                        \
      if (u0 + 1 < UU) {                                                       \
        const int u = u0 + 1, w = u / VV, up = u % VV;                         \
        const int ts = t0 + (tb) + tr + w - 1;                                 \
        if (ts >= 0 && ts < TT) f1 = x[((n * 64 + c) * TT + ts) * VV + up];    \
      }                                                                        \
      *(unsigned*)(xu2 + (tr * 64 + c) * 104 + u0) = pack2(f0, f1);            \
    }

  // raw vector copy: attP[n][hh] (padded, bit-exact layout) -> attB[buf]
  #define STAGE_ATT(hh, buf)                                                   \
    {                                                                          \
      const u32x4* srcv =                                                      \
          (const u32x4*)(attP + ((size_t)(n * HH + (hh)) * 32) * 104);         \
      u32x4* dstv = (u32x4*)&attB[buf][0][0];                                  \
      for (int i = tid; i < 416; i += 256) dstv[i] = srcv[i];                  \
    }

  // ---- prologue: A-frags from xu2 in two 2-t chunks ----
  STAGE_XU(0);
  __syncthreads();
  u32x4 af[4][3];
  if (wid < 2) {
    #pragma unroll
    for (int mt = 0; mt < 4; ++mt)
      #pragma unroll
      for (int ks = 0; ks < 3; ++ks)
        af[mt][ks] = *(const u32x4*)(xu2 + (wid * 64 + mt * 16 + m16) * 104 +
                                     ks * 32 + kg * 8);
  }
  __syncthreads();   // chunk-1 reads drained before overwrite
  STAGE_XU(2);
  STAGE_ATT(0, 0);
  __syncthreads();
  if (wid >= 2) {
    #pragma unroll
    for (int mt = 0; mt < 4; ++mt)
      #pragma unroll
      for (int ks = 0; ks < 3; ++ks)
        af[mt][ks] = *(const u32x4*)(xu2 + ((wid - 2) * 64 + mt * 16 + m16) * 104 +
                                     ks * 32 + kg * 8);
  }
  __syncthreads();   // FENCE: all xu2 reads drained; uB becomes xsl2+wol2
  // zero junk rows (tv 100..111) of BOTH xsl buffers (never rewritten)
  for (int i = tid; i < 2 * 12 * 64; i += 256) {
    const int b = i / (12 * 64), r = i % (12 * 64);
    *(unsigned short*)(XSLB(b) + (100 + (r >> 6)) * 128 + ((r & 63) * 2)) = 0;
  }
  // NOTE: zeroing completes before bar(h=0), which precedes first xsl read.

  const int wd_d = tid >> 1, wd_c0 = (tid & 1) * 32;
  const float so_ = g_o[wd_d] * rsqrtf(v_o[wd_d] + 1e-5f);
  const float sd_ = g_d[wd_d] * rsqrtf(v_d[wd_d] + 1e-5f);

  f32x4 acc2[2][7];
  #pragma unroll
  for (int mt = 0; mt < 2; ++mt)
    #pragma unroll
    for (int nt = 0; nt < 7; ++nt) acc2[mt][nt] = (f32x4)0.f;

  for (int h = 0; h <= HH; ++h) {
    const int pb = h & 1;
    char* xs = XSLB(pb);
    char* wo = WOLB(pb);
    float4 wb[8];
    {
      const float* wsrc = (h < HH) ? (Wo + wd_d * 512 + h * 64 + wd_c0)
                                   : (Wd + wd_d * 64 + wd_c0);
      #pragma unroll
      for (int q = 0; q < 8; ++q) wb[q] = ((const float4*)wsrc)[q];
    }
    if (h + 1 < HH) { STAGE_ATT(h + 1, (h + 1) & 1); }
    f32x4 a1[4][2];
    if (h < HH) {
      u32x4 bfr[2][3];
      #pragma unroll
      for (int nt = 0; nt < 2; ++nt)
        #pragma unroll
        for (int ks = 0; ks < 3; ++ks)
          bfr[nt][ks] =
              *(const u32x4*)&attB[pb][nt * 16 + m16][ks * 32 + kg * 8];
      #pragma unroll
      for (int mt = 0; mt < 4; ++mt)
        #pragma unroll
        for (int nt = 0; nt < 2; ++nt) {
          a1[mt][nt] = (f32x4)0.f;
          #pragma unroll
          for (int ks = 0; ks < 3; ++ks)
            a1[mt][nt] = mfma_bf16(af[mt][ks], bfr[nt][ks], a1[mt][nt]);
        }
    }
    // write this h's operand buffers (parity pb; h-1 used 1-pb -> no hazard)
    if (h < HH) {
      #pragma unroll
      for (int mt = 0; mt < 4; ++mt)
        #pragma unroll
        for (int nt = 0; nt < 2; ++nt) {
          const int v = nt * 16 + m16;
          if (v < VV) {
            const int tv = wid * VV + v;
            const int c0 = mt * 16 + kg * 4;
            u32x2 pk;
            pk[0] = pack2(a1[mt][nt][0], a1[mt][nt][1]);
            pk[1] = pack2(a1[mt][nt][2], a1[mt][nt][3]);
            char* p = xs + tv * 128 + ((c0 * 2) ^ ((tv & 7) << 4));
            *(u32x2*)p = pk;
          }
        }
    } else {
      for (int i = tid; i < 6400; i += 256) {
        const int c = i / 100, j = i % 100;
        const float f = x[((size_t)(n * 64 + c) * TT + t0) * VV + j];
        *(unsigned short*)(xs + j * 128 + ((c * 2) ^ ((j & 7) << 4))) =
            f2bu(f);
      }
    }
    {
      const float sc = (h < HH) ? so_ : sd_;
      #pragma unroll
      for (int q = 0; q < 4; ++q) {
        const float4 p0 = wb[q * 2], p1 = wb[q * 2 + 1];
        u32x4 wv;
        wv[0] = pack2(p0.x * sc, p0.y * sc); wv[1] = pack2(p0.z * sc, p0.w * sc);
        wv[2] = pack2(p1.x * sc, p1.y * sc); wv[3] = pack2(p1.z * sc, p1.w * sc);
        char* p = wo + wd_d * 128 + ((wd_c0 * 2 + q * 16) ^ ((wd_d & 7) << 4));
        *(u32x4*)p = wv;
      }
    }
    __syncthreads();   // single barrier: writes(pb) -> reads(pb)
    u32x4 a2[2][2];
    #pragma unroll
    for (int mt = 0; mt < 2; ++mt)
      #pragma unroll
      for (int ks = 0; ks < 2; ++ks) {
        const int d = wid * 32 + mt * 16 + m16;
        a2[mt][ks] = *(const u32x4*)(wo + d * 128 +
                      (((ks * 32 + kg * 8) * 2) ^ ((d & 7) << 4)));
      }
    #pragma unroll
    for (int nt = 0; nt < 7; ++nt) {
      const int tv = nt * 16 + m16;
      const u32x4 b0 = *(const u32x4*)(xs + tv * 128 +
                        (((kg * 8) * 2) ^ ((tv & 7) << 4)));
      const u32x4 b1 = *(const u32x4*)(xs + tv * 128 +
                        (((32 + kg * 8) * 2) ^ ((tv & 7) << 4)));
      #pragma unroll
      for (int mt = 0; mt < 2; ++mt) {
        acc2[mt][nt] = mfma_bf16(a2[mt][0], b0, acc2[mt][nt]);
        acc2[mt][nt] = mfma_bf16(a2[mt][1], b1, acc2[mt][nt]);
      }
    }
  }

  #pragma unroll
  for (int mt = 0; mt < 2; ++mt) {
    float cc[4];
    #pragma unroll
    for (int i = 0; i < 4; ++i) {
      const int d = wid * 32 + mt * 16 + kg * 4 + i;
      const float so2 = g_o[d] * rsqrtf(v_o[d] + 1e-5f);
      const float sd2 = g_d[d] * rsqrtf(v_d[d] + 1e-5f);
      cc[i] = b_o[d] * so2 + be_o[d] - m_o[d] * so2
            + b_d[d] * sd2 + be_d[d] - m_d[d] * sd2;
    }
    #pragma unroll
    for (int nt = 0; nt < 7; ++nt) {
      const int tv = nt * 16 + m16;
      if (tv < 100) {
        const int t = t0 + tv / VV, v = tv % VV;
        #pragma unroll
        for (int i = 0; i < 4; ++i) {
          const int d = wid * 32 + mt * 16 + kg * 4 + i;
          const float z = acc2[mt][nt][i] + cc[i];
          out[((n * DIMD + d) * TT + t) * VV + v] = (z >= 0.f) ? z : 0.1f * z;
        }
      }
    }
  }
  #undef STAGE_XU
  #undef STAGE_ATT
  #undef XSLB
  #undef WOLB
}

// ---------------------------------------------------------------------------
extern "C" void kernel_launch(void* const* d_in, const int* in_sizes, int n_in,
                              void* d_out, int out_size, void* d_ws, size_t ws_size,
                              hipStream_t stream)
{
  (void)in_sizes; (void)n_in; (void)out_size; (void)ws_size;
  const float* x     = (const float*)d_in[0];
  const float* Wq    = (const float*)d_in[1];
  const float* bq    = (const float*)d_in[2];
  const float* Wk    = (const float*)d_in[3];
  const float* bk    = (const float*)d_in[4];
  const float* We    = (const float*)d_in[5];
  const float* be    = (const float*)d_in[6];
  const float* G     = (const float*)d_in[7];
  const float* sepe  = (const float*)d_in[8];
  const float* att0  = (const float*)d_in[9];
  const float* alpha = (const float*)d_in[10];
  const float* beta  = (const float*)d_in[11];
  const float* Wo    = (const float*)d_in[12];
  const float* b_o   = (const float*)d_in[13];
  const float* g_o   = (const float*)d_in[14];
  const float* be_o  = (const float*)d_in[15];
  const float* m_o   = (const float*)d_in[16];
  const float* v_o   = (const float*)d_in[17];
  const float* Wd    = (const float*)d_in[18];
  const float* b_d   = (const float*)d_in[19];
  const float* g_d   = (const float*)d_in[20];
  const float* be_d  = (const float*)d_in[21];
  const float* m_d   = (const float*)d_in[22];
  const float* v_d   = (const float*)d_in[23];
  const int*   dism  = (const int*)d_in[24];
  const float* disg  = (const float*)d_in[25];

  // Workspace: qy @0 (49.152 MB), kk @49,152,000, attP @98,304,000 (3.41 MB,
  // padded [n][h][32][104] bf16)
  char* ws = (char*)d_ws;
  bf16* qy   = (bf16*)(ws);
  bf16* kkp  = (bf16*)(ws + 49152000);
  unsigned short* attP = (unsigned short*)(ws + 98304000);

  k_qke_mfma5<<<NB * 30, 256, 0, stream>>>(x, Wq, bq, Wk, bk, We, be, G, beta,
                                           sepe, dism, qy, kkp);
  k_att<<<NB * HH, 256, 0, stream>>>(qy, kkp, bq, disg, att0, alpha, attP);
  k_out_mfma4<<<NB * 30, 256, 0, stream>>>(x, attP, Wo, b_o, g_o, be_o, m_o, v_o,
                                           Wd, b_d, g_d, be_d, m_d, v_d, (float*)d_out);
}